// Round 8
// baseline (1579.220 us; speedup 1.0000x reference)
//
#include <hip/hip_runtime.h>
#include <hip/hip_bf16.h>

typedef __attribute__((ext_vector_type(8))) short bf16x8;
typedef __attribute__((ext_vector_type(4))) float f32x4;

__device__ __forceinline__ float sigf(float x){ return 1.0f/(1.0f+expf(-x)); }
__device__ __forceinline__ int clampi(int v, int lo, int hi){ return v<lo?lo:(v>hi?hi:v); }
__device__ __forceinline__ unsigned short f2b(float f){
    __hip_bfloat16 h = __float2bfloat16(f);
    return *reinterpret_cast<unsigned short*>(&h);
}
__device__ __forceinline__ float us2f(unsigned short u){ return __uint_as_float(((unsigned)u)<<16); }

// ---- int64/int32 tolerant index conversion ----
__global__ void k_cvt(const int* __restrict__ src, int* __restrict__ dst, int n,
                      const int* __restrict__ det)
{
    int i = blockIdx.x*blockDim.x + threadIdx.x;
    if (i >= n) return;
    int stride = (det[1] == 0) ? 2 : 1;
    dst[i] = src[(size_t)i*stride];
}

// ---- weight transpose+convert: Wt[n][k] (bf16) <- W[k][n] (f32) ----
__global__ void k_wt(const float* __restrict__ W, unsigned short* __restrict__ Wt,
                     int N, int kshift, int kmask, int total)
{
    int idx = blockIdx.x*blockDim.x + threadIdx.x;
    if (idx >= total) return;
    int n = idx >> kshift, k = idx & kmask;
    Wt[idx] = f2b(W[(size_t)k*N + n]);
}

// ---- split transpose+convert: Whi/Wlo[n][k] <- W[k][n], lo = residual ----
__global__ void k_wt2(const float* __restrict__ W, unsigned short* __restrict__ Whi,
                      unsigned short* __restrict__ Wlo, int N, int kshift, int kmask, int total)
{
    int idx = blockIdx.x*blockDim.x + threadIdx.x;
    if (idx >= total) return;
    int n = idx >> kshift, k = idx & kmask;
    float v = W[(size_t)k*N + n];
    unsigned short hi = f2b(v);
    Whi[idx] = hi;
    Wlo[idx] = f2b(v - us2f(hi));
}

// ---- concat-head W_src layout: Wc[c][h*256+k] <- W_src[k][h*256+c] ----
__global__ void k_wtc(const float* __restrict__ W, unsigned short* __restrict__ Wt, int total)
{
    int idx = blockIdx.x*blockDim.x + threadIdx.x;
    if (idx >= total) return;
    int c = idx >> 10, r = idx & 1023;
    int h = r >> 8, k = r & 255;
    Wt[idx] = f2b(W[(size_t)k*1024 + h*256 + c]);
}

// ---------------- init projections ----------------
__global__ void k_proj5(const float* __restrict__ X, const float* __restrict__ W,
                        const float* __restrict__ bias,
                        const int* __restrict__ gidx, const int* __restrict__ sidx,
                        float* __restrict__ out, float* __restrict__ out2, int M, int nrows, int nodes)
{
    int t = blockIdx.x*blockDim.x + threadIdx.x;
    int i = t >> 7, j = t & 127;
    if (i >= M) return;
    int src = gidx ? clampi(gidx[i]-1, 0, nrows-1) : i;
    const float* xp = X + (size_t)src*5;
    float acc = bias[j];
#pragma unroll
    for (int k=0;k<5;k++) acc += xp[k] * W[k*128+j];
    int dr = sidx ? clampi(sidx[i], 0, nodes-1) : i;
    out[(size_t)dr*128 + j] = acc;
    if (out2) out2[(size_t)i*128 + j] = acc;
}

// ---------------- f32 tiled GEMM (readout heads only) ----------------
__launch_bounds__(256)
__global__ void k_mm(const float* __restrict__ A0, int lda,
                     const float* __restrict__ B, int ldb,
                     const float* __restrict__ bias, float* __restrict__ C,
                     int M, int N, int K, int relu, float scale, int accum)
{
    __shared__ float As[16][132];
    __shared__ float Bs[16][132];
    int tid = threadIdx.x;
    int tx = tid & 15, ty = tid >> 4;
    int row0 = blockIdx.y * 128, col0 = blockIdx.x * 128;
    float acc[8][8] = {};
    for (int k0 = 0; k0 < K; k0 += 16){
#pragma unroll
        for (int q = 0; q < 2; ++q){
            int idx = tid + q*256;
            int r = idx >> 2, k4 = (idx & 3) * 4;
            const float* src = A0 + (size_t)(row0+r)*lda + k0 + k4;
            float4 v = *reinterpret_cast<const float4*>(src);
            As[k4+0][r]=v.x; As[k4+1][r]=v.y; As[k4+2][r]=v.z; As[k4+3][r]=v.w;
        }
#pragma unroll
        for (int q = 0; q < 2; ++q){
            int idx = tid + q*256;
            int kb = idx >> 5, n4 = (idx & 31) * 4;
            float4 v = *reinterpret_cast<const float4*>(B + (size_t)(k0+kb)*ldb + col0 + n4);
            *reinterpret_cast<float4*>(&Bs[kb][n4]) = v;
        }
        __syncthreads();
#pragma unroll
        for (int k = 0; k < 16; ++k){
            float a[8], b[8];
            *(float4*)&a[0] = *(const float4*)&As[k][ty*8];
            *(float4*)&a[4] = *(const float4*)&As[k][ty*8+4];
            *(float4*)&b[0] = *(const float4*)&Bs[k][tx*8];
            *(float4*)&b[4] = *(const float4*)&Bs[k][tx*8+4];
#pragma unroll
            for (int i=0;i<8;i++)
#pragma unroll
                for (int j=0;j<8;j++) acc[i][j] += a[i]*b[j];
        }
        __syncthreads();
    }
    float bb[8];
#pragma unroll
    for (int j=0;j<8;j++) bb[j] = bias ? bias[col0+tx*8+j] : 0.f;
#pragma unroll
    for (int i=0;i<8;i++){
        float* cp = C + (size_t)(row0+ty*8+i)*N + col0 + tx*8;
#pragma unroll
        for (int jq=0;jq<2;jq++){
            float4 prev = accum ? *(const float4*)(cp+jq*4) : make_float4(0,0,0,0);
            float o[4];
#pragma unroll
            for (int c=0;c<4;c++){
                float u = acc[i][jq*4+c] + bb[jq*4+c];
                if (relu) u = fmaxf(u,0.f);
                o[c] = (&prev.x)[c] + scale*u;
            }
            *(float4*)(cp+jq*4) = make_float4(o[0],o[1],o[2],o[3]);
        }
    }
}

// ---------------- bf16 MFMA GEMM: C[M,N] = scale*(A(f32->bf16) @ Wt^T) + bias ----------------
// epi==1: GAT alpha epilogue; rows are PERMUTED by i0 (sorted by device):
//   fid = i0[r]; dr = rowIdx[r] (sorted device id); atomicAdd(alpha[fid*4+h]).
__launch_bounds__(256)
__global__ void mm_bf(const float* __restrict__ A0, const float* __restrict__ A1,
                      const int* __restrict__ i0, const int* __restrict__ i1, int lda,
                      const unsigned short* __restrict__ Wt,
                      const float* __restrict__ bias, float* __restrict__ C,
                      int M, int N, int K, int epi, float scale,
                      const float* __restrict__ tgtP, const int* __restrict__ rowIdx,
                      const float* __restrict__ attP, const float* __restrict__ bsrcP,
                      float* __restrict__ alphaP)
{
    __shared__ alignas(16) unsigned short As[128*64];
    __shared__ alignas(16) unsigned short Bs[128*64];
    int tid = threadIdx.x;
    int l = tid & 63, w = tid >> 6;
    int wr = w >> 1, wc = w & 1;
    int row0 = blockIdx.y * 128, col0 = blockIdx.x * 128;
    f32x4 acc[4][4];
#pragma unroll
    for (int m=0;m<4;m++)
#pragma unroll
        for (int n=0;n<4;n++) acc[m][n] = (f32x4){0.f,0.f,0.f,0.f};

    for (int k0 = 0; k0 < K; k0 += 64){
#pragma unroll
        for (int q = 0; q < 8; ++q){
            int idx = tid + q*256;
            int r = idx >> 4, c4 = (idx & 15) * 4;
            int kk = k0 + c4;
            const float* src;
            if (A1){
                if (kk < 128){ int ri = i0 ? i0[row0+r] : (row0+r); src = A0 + (size_t)ri*128 + kk; }
                else         { int ri = i1 ? i1[row0+r] : (row0+r); src = A1 + (size_t)ri*128 + (kk-128); }
            } else {
                src = A0 + (size_t)(row0+r)*lda + kk;
            }
            float4 v = *reinterpret_cast<const float4*>(src);
            ushort4 o; o.x=f2b(v.x); o.y=f2b(v.y); o.z=f2b(v.z); o.w=f2b(v.w);
            int csw = c4 ^ ((r & 7) << 3);
            *reinterpret_cast<ushort4*>(&As[r*64 + csw]) = o;
        }
#pragma unroll
        for (int q = 0; q < 4; ++q){
            int idx = tid + q*256;
            int n = idx >> 3, k8 = (idx & 7) * 8;
            uint4 v = *reinterpret_cast<const uint4*>(Wt + (size_t)(col0+n)*K + k0 + k8);
            int ksw = k8 ^ ((n & 7) << 3);
            *reinterpret_cast<uint4*>(&Bs[n*64 + ksw]) = v;
        }
        __syncthreads();
#pragma unroll
        for (int kk = 0; kk < 2; ++kk){
            int ek = kk*32 + (l >> 4) * 8;
            bf16x8 af[4], bf[4];
#pragma unroll
            for (int m=0;m<4;m++){
                int r = wr*64 + m*16 + (l & 15);
                af[m] = *reinterpret_cast<const bf16x8*>(&As[r*64 + (ek ^ ((r & 7) << 3))]);
            }
#pragma unroll
            for (int n=0;n<4;n++){
                int c = wc*64 + n*16 + (l & 15);
                bf[n] = *reinterpret_cast<const bf16x8*>(&Bs[c*64 + (ek ^ ((c & 7) << 3))]);
            }
#pragma unroll
            for (int m=0;m<4;m++)
#pragma unroll
                for (int n=0;n<4;n++)
                    acc[m][n] = __builtin_amdgcn_mfma_f32_16x16x32_bf16(af[m], bf[n], acc[m][n], 0, 0, 0);
        }
        __syncthreads();
    }

    if (epi == 0){
#pragma unroll
        for (int m=0;m<4;m++){
#pragma unroll
            for (int v=0;v<4;v++){
                int row = row0 + wr*64 + m*16 + (l >> 4)*4 + v;
                float* cp = C + (size_t)row*N + col0 + wc*64 + (l & 15);
#pragma unroll
                for (int n=0;n<4;n++){
                    int col = col0 + wc*64 + n*16 + (l & 15);
                    float u = scale*acc[m][n][v] + (bias ? bias[col] : 0.f);
                    cp[n*16] = u;
                }
            }
        }
    } else {
        int h = col0 >> 8;
#pragma unroll
        for (int m=0;m<4;m++){
#pragma unroll
            for (int v=0;v<4;v++){
                int rglob = row0 + wr*64 + m*16 + (l >> 4)*4 + v;
                int fid = i0 ? i0[rglob] : rglob;
                int dr = rowIdx[rglob];
                const float* tp = tgtP + (size_t)dr*1024 + col0 + wc*64;
                float s = 0.f;
#pragma unroll
                for (int n=0;n<4;n++){
                    int cl = n*16 + (l & 15);
                    int c = col0 + wc*64 + cl;
                    float e = acc[m][n][v] + bsrcP[c] + tp[cl];
                    e = e > 0.f ? e : 0.2f*e;
                    s += e * attP[c];
                }
#pragma unroll
                for (int msk=1; msk<16; msk<<=1) s += __shfl_xor(s, msk);
                if ((l & 15) == 0) atomicAdd(&alphaP[(size_t)fid*4 + h], s);
            }
        }
    }
}

// ---------------- fused phiC recurrence: MFMA gh, Whh stationary in registers ----------------
__launch_bounds__(512)
__global__ void k_recur(float* __restrict__ h_srv, const float* __restrict__ giF,
                        const unsigned short* __restrict__ Whi,
                        const unsigned short* __restrict__ Wlo,
                        const float* __restrict__ bhh,
                        const int* __restrict__ inv, float* __restrict__ out_f,
                        int S, int L, int F)
{
    __shared__ float hs[16][132];
    __shared__ float ghs[16][388];
    __shared__ int fLoc[16];
    int tid = threadIdx.x;
    int l = tid & 63, w = tid >> 6;
    int lane15 = l & 15, lhi = l >> 4;
    int s0 = blockIdx.x * 16;
    for (int u = tid; u < 2048; u += 512){ int s=u>>7,k=u&127; hs[s][k] = h_srv[(size_t)(s0+s)*128+k]; }
    bf16x8 wHi[3][4], wLo[3][4];
#pragma unroll
    for (int ct=0; ct<3; ++ct){
        int col = w*48 + ct*16 + lane15;
#pragma unroll
        for (int ks=0; ks<4; ++ks){
            size_t off = (size_t)col*128 + ks*32 + lhi*8;
            wHi[ct][ks] = *reinterpret_cast<const bf16x8*>(Whi + off);
            wLo[ct][ks] = *reinterpret_cast<const bf16x8*>(Wlo + off);
        }
    }
    __syncthreads();
    for (int t=0;t<L;++t){
        if (tid < 16) fLoc[tid] = inv[(size_t)(s0+tid)*L + t];
        __syncthreads();
        bf16x8 hHi[4], hLo[4];
#pragma unroll
        for (int ks=0; ks<4; ++ks){
            const float* hp = &hs[lane15][ks*32 + lhi*8];
#pragma unroll
            for (int j=0;j<8;j++){
                float v = hp[j];
                unsigned short hi = f2b(v);
                hHi[ks][j] = (short)hi;
                hLo[ks][j] = (short)f2b(v - us2f(hi));
            }
        }
#pragma unroll
        for (int ct=0; ct<3; ++ct){
            f32x4 acc = (f32x4){0.f,0.f,0.f,0.f};
#pragma unroll
            for (int ks=0; ks<4; ++ks){
                acc = __builtin_amdgcn_mfma_f32_16x16x32_bf16(hHi[ks], wHi[ct][ks], acc, 0,0,0);
                acc = __builtin_amdgcn_mfma_f32_16x16x32_bf16(hLo[ks], wHi[ct][ks], acc, 0,0,0);
                acc = __builtin_amdgcn_mfma_f32_16x16x32_bf16(hHi[ks], wLo[ct][ks], acc, 0,0,0);
            }
            int col = w*48 + ct*16 + lane15;
            float bb = bhh[col];
#pragma unroll
            for (int v=0; v<4; ++v){
                ghs[lhi*4 + v][col] = acc[v] + bb;
            }
        }
        __syncthreads();
        for (int u = tid; u < 2048; u += 512){
            int s=u>>7, k=u&127; int f = fLoc[s];
            if (f >= 0 && f < F){
                const float* gp = giF + (size_t)f*384;
                float r  = sigf(gp[k]     + ghs[s][k]);
                float zz = sigf(gp[128+k] + ghs[s][128+k]);
                float n  = tanhf(gp[256+k] + r*ghs[s][256+k]);
                float hn = (1.f-zz)*n + zz*hs[s][k];
                hs[s][k] = hn;
                out_f[(size_t)f*128+k] = hn;
            }
        }
        __syncthreads();
    }
    for (int u = tid; u < 2048; u += 512){ int s=u>>7,k=u&127; h_srv[(size_t)(s0+s)*128+k] = hs[s][k]; }
}

// ---------------- GRU pointwise with state write-through ----------------
__global__ void k_gru(const float* __restrict__ gi, const float* __restrict__ gh,
                      const float* __restrict__ hin, float* __restrict__ hout,
                      float* __restrict__ state, const int* __restrict__ sidx,
                      int M, int nodes)
{
    int idx = blockIdx.x*blockDim.x + threadIdx.x;
    int i = idx >> 7, j = idx & 127;
    if (i >= M) return;
    size_t g = (size_t)i*384;
    float r = sigf(gi[g+j]     + gh[g+j]);
    float z = sigf(gi[g+128+j] + gh[g+128+j]);
    float n = tanhf(gi[g+256+j] + r*gh[g+256+j]);
    float hv = hin[(size_t)i*128+j];
    float hn = (1.f-z)*n + z*hv;
    hout[(size_t)i*128+j] = hn;
    if (state) state[(size_t)clampi(sidx[i],0,nodes-1)*128 + j] = hn;
}

// ---------------- per-device softmax + weighted [out_f|fragOld] sum ----------------
__global__ void k_attn_z(const float* __restrict__ out_f, const float* __restrict__ fragOld,
                         const float* __restrict__ alpha,
                         const int* __restrict__ list, const int* __restrict__ offs,
                         float* __restrict__ z, float* __restrict__ sa, int Dn, int F)
{
    int d = blockIdx.x;
    int tid = threadIdx.x;
    int h = tid >> 6, lane = tid & 63;
    int beg = offs[d], end = offs[d+1];
    if (beg < 0) beg = 0; if (end > F) end = F; if (end < beg) end = beg;
    float amax = -3.4e38f;
    for (int i=beg;i<end;i++) amax = fmaxf(amax, alpha[(size_t)list[i]*4+h]);
    float wsum = 0.f;
    for (int i=beg;i<end;i++) wsum += expf(alpha[(size_t)list[i]*4+h]-amax);
    float iws = 1.f/(wsum + 1e-16f);
    float acc[4] = {0,0,0,0};
    for (int i=beg;i<end;i++){
        int f = list[i];
        float a = expf(alpha[(size_t)f*4+h]-amax)*iws;
#pragma unroll
        for (int q=0;q<4;q++){
            int c = lane + q*64;
            float v = (c < 128) ? out_f[(size_t)f*128 + c] : fragOld[(size_t)f*128 + c - 128];
            acc[q] += a * v;
        }
    }
#pragma unroll
    for (int q=0;q<4;q++) z[(size_t)d*1024 + h*256 + lane + q*64] = acc[q];
    if (lane == 0) sa[d*4+h] = (end>beg) ? wsum*iws : 0.f;
}

__global__ void k_msgd_fix(float* __restrict__ msgD, const float* __restrict__ sa,
                           const float* __restrict__ bsrc, const float* __restrict__ batt, int Dn)
{
    int idx = blockIdx.x*blockDim.x + threadIdx.x;
    int d = idx >> 8, c = idx & 255;
    if (d >= Dn) return;
    float v = batt[c];
#pragma unroll
    for (int h=0;h<4;h++) v += 0.25f * sa[d*4+h] * bsrc[h*256+c];
    msgD[(size_t)d*256 + c] += v;
}

__global__ void k_count(const int* __restrict__ row, int* __restrict__ counts, int F, int Dn)
{ int f = blockIdx.x*blockDim.x + threadIdx.x; if (f < F) atomicAdd(&counts[clampi(row[f],0,Dn-1)], 1); }

__global__ void k_scan(const int* __restrict__ counts, int* __restrict__ offs, int D)
{
    __shared__ int part[257];
    int tid = threadIdx.x;
    int per = (D + 255) / 256;
    int s = 0;
    for (int i=0;i<per;i++){ int idx = tid*per+i; if (idx < D) s += counts[idx]; }
    part[tid] = s;
    __syncthreads();
    if (tid == 0){
        int acc = 0;
        for (int i=0;i<256;i++){ int v = part[i]; part[i] = acc; acc += v; }
        part[256] = acc;
    }
    __syncthreads();
    int acc = part[tid];
    for (int i=0;i<per;i++){ int idx = tid*per+i; if (idx < D){ offs[idx] = acc; acc += counts[idx]; } }
    if (tid == 0) offs[D] = part[256];
}

// fill device-sorted fragment list + per-position device id
__global__ void k_fill(const int* __restrict__ row, const int* __restrict__ offs,
                       int* __restrict__ cursor, int* __restrict__ list,
                       int* __restrict__ sortedDev, int F, int Dn)
{
    int f = blockIdx.x*blockDim.x + threadIdx.x;
    if (f >= F) return;
    int r = clampi(row[f],0,Dn-1);
    int p = atomicAdd(&cursor[r], 1);
    int pos = offs[r]+p;
    if (pos >= 0 && pos < F){ list[pos] = f; sortedDev[pos] = r; }
}

__global__ void k_build_inv(const int* __restrict__ fs, const int* __restrict__ fp,
                            int* __restrict__ inv, int F, int L, int S)
{
    int f = blockIdx.x*blockDim.x + threadIdx.x;
    if (f >= F) return;
    inv[clampi(fs[f],0,S-1)*L + clampi(fp[f],0,L-1)] = f;
}

__global__ void k_pool_add(const float* __restrict__ frag, const int* __restrict__ fs,
                           float* __restrict__ pooled, int F, int S)
{
    int t = blockIdx.x*blockDim.x + threadIdx.x;
    int i = t >> 7, j = t & 127;
    if (i >= F) return;
    atomicAdd(&pooled[(size_t)clampi(fs[i],0,S-1)*128 + j], frag[(size_t)i*128 + j]);
}

__global__ void k_pool_div(float* __restrict__ pooled, const int* __restrict__ lengths, int S)
{
    int t = blockIdx.x*blockDim.x + threadIdx.x;
    int i = t >> 7, j = t & 127;
    if (i >= S) return;
    int l = lengths[i]; if (l < 1) l = 1;
    pooled[(size_t)i*128 + j] /= (float)l;
}

__global__ void k_dot_out(const float* __restrict__ H, const float* __restrict__ W3,
                          const float* __restrict__ b3, float* __restrict__ outv, int off)
{
    __shared__ float red[256];
    int s = blockIdx.x, tid = threadIdx.x;
    red[tid] = H[(size_t)s*256 + tid] * W3[tid];
    __syncthreads();
    for (int st=128; st; st>>=1){ if (tid < st) red[tid] += red[tid+st]; __syncthreads(); }
    if (tid == 0) outv[off + s] = red[0] + b3[0];
}

// =====================================================================================
extern "C" void kernel_launch(void* const* d_in, const int* in_sizes, int n_in,
                              void* d_out, int out_size, void* d_ws, size_t ws_size,
                              hipStream_t stream)
{
    (void)n_in; (void)out_size; (void)ws_size;
    const float* realnode = (const float*)d_in[0];
    const float* arr      = (const float*)d_in[1];
    const int* r_exe   = (const int*)d_in[2];
    const int* r_idev  = (const int*)d_in[3];
    const int* r_ifrag = (const int*)d_in[4];
    const int* r_fdn   = (const int*)d_in[5];
    const int* r_fdr   = (const int*)d_in[6];
    const int* r_len   = (const int*)d_in[7];
    const int* r_fsvc  = (const int*)d_in[8];
    const int* r_fpos  = (const int*)d_in[9];
    const float *W_dev=(const float*)d_in[10], *b_dev=(const float*)d_in[11];
    const float *W_frg=(const float*)d_in[12], *b_frg=(const float*)d_in[13];
    const float *W_srv=(const float*)d_in[14], *b_srv=(const float*)d_in[15];
    const float *C_Wih=(const float*)d_in[16], *C_Whh=(const float*)d_in[17], *C_bih=(const float*)d_in[18], *C_bhh=(const float*)d_in[19];
    const float *F_Wih=(const float*)d_in[20], *F_Whh=(const float*)d_in[21], *F_bih=(const float*)d_in[22], *F_bhh=(const float*)d_in[23];
    const float *D_Wih=(const float*)d_in[24], *D_Whh=(const float*)d_in[25], *D_bih=(const float*)d_in[26], *D_bhh=(const float*)d_in[27];
    const float *W_src=(const float*)d_in[28], *b_src=(const float*)d_in[29];
    const float *W_tgt=(const float*)d_in[30], *b_tgt=(const float*)d_in[31];
    const float *att=(const float*)d_in[32], *bias_att=(const float*)d_in[33];
    const float *Wt1=(const float*)d_in[34], *bt1=(const float*)d_in[35], *Wt2=(const float*)d_in[36], *bt2=(const float*)d_in[37], *Wt3=(const float*)d_in[38], *bt3=(const float*)d_in[39];
    const float *Wl1=(const float*)d_in[40], *bl1=(const float*)d_in[41], *Wl2=(const float*)d_in[42], *bl2=(const float*)d_in[43], *Wl3=(const float*)d_in[44], *bl3=(const float*)d_in[45];
    float* outp = (float*)d_out;

    const int S  = in_sizes[7];
    const int Dn = in_sizes[3];
    const int F  = in_sizes[4];
    const int L  = in_sizes[2] / (2*S);
    const int nreal = in_sizes[0]/5;
    const int nodes = nreal + 1;
    const int NIT = 3;
    const int FH = F/2;

    char* wp = (char*)d_ws;
    auto alloc = [&](size_t nelem)->float*{
        float* p = (float*)wp;
        wp += ((nelem*4 + 255)/256)*256;
        return p;
    };
    float* state  = alloc((size_t)nodes*128);
    float* h_srv  = alloc((size_t)S*128);
    float* out_f  = alloc((size_t)F*128);
    float* fragA  = alloc((size_t)F*128);
    float* devA   = alloc((size_t)Dn*128);
    float* alphaB = alloc((size_t)F*4);
    float* msgDm  = alloc((size_t)Dn*256);
    float* saB    = alloc((size_t)Dn*4);
    float* giF    = alloc((size_t)F*384);
    float* TGT    = alloc((size_t)Dn*1024);
    float* Z      = alloc((size_t)Dn*1024);
    float* pooled = alloc((size_t)S*128);
    unsigned short* tCWih   = (unsigned short*)alloc(384*256/2);
    unsigned short* tCWhhHi = (unsigned short*)alloc(384*128/2);
    unsigned short* tCWhhLo = (unsigned short*)alloc(384*128/2);
    unsigned short* tFWih   = (unsigned short*)alloc(384*256/2);
    unsigned short* tFWhh   = (unsigned short*)alloc(384*128/2);
    unsigned short* tDWih   = (unsigned short*)alloc(384*256/2);
    unsigned short* tDWhh   = (unsigned short*)alloc(384*128/2);
    unsigned short* tWtgt   = (unsigned short*)alloc(1024*128/2);
    unsigned short* tWsrc   = (unsigned short*)alloc(1024*256/2);
    unsigned short* tWsrcC  = (unsigned short*)alloc(256*1024/2);
    int* cExe   = (int*)alloc((size_t)S*2*L);
    int* cIdev  = (int*)alloc((size_t)Dn);
    int* cIfrag = (int*)alloc((size_t)F);
    int* cFdn   = (int*)alloc((size_t)F);
    int* cFdr   = (int*)alloc((size_t)F);
    int* cLen   = (int*)alloc((size_t)S);
    int* cFsvc  = (int*)alloc((size_t)F);
    int* cFpos  = (int*)alloc((size_t)F);
    int* inv    = (int*)alloc((size_t)S*L);
    int* counts = (int*)alloc((size_t)Dn);
    int* offs   = (int*)alloc((size_t)Dn+1);
    int* cursor = (int*)alloc((size_t)Dn);
    int* list   = (int*)alloc((size_t)F);
    int* sortedDev = (int*)alloc((size_t)F);

    const int* det = r_idev;
    auto cvt = [&](const int* src, int* dst, int n){
        k_cvt<<<dim3((n+255)/256),256,0,stream>>>(src, dst, n, det);
    };
    cvt(r_exe,  cExe,  S*2*L);
    cvt(r_idev, cIdev, Dn);
    cvt(r_ifrag,cIfrag,F);
    cvt(r_fdn,  cFdn,  F);
    cvt(r_fdr,  cFdr,  F);
    cvt(r_len,  cLen,  S);
    cvt(r_fsvc, cFsvc, F);
    cvt(r_fpos, cFpos, F);

    k_wt<<<dim3((98304+255)/256),256,0,stream>>>(C_Wih, tCWih, 384, 8, 255, 98304);
    k_wt2<<<dim3((49152+255)/256),256,0,stream>>>(C_Whh, tCWhhHi, tCWhhLo, 384, 7, 127, 49152);
    k_wt<<<dim3((98304+255)/256),256,0,stream>>>(F_Wih, tFWih, 384, 8, 255, 98304);
    k_wt<<<dim3((49152+255)/256),256,0,stream>>>(F_Whh, tFWhh, 384, 7, 127, 49152);
    k_wt<<<dim3((98304+255)/256),256,0,stream>>>(D_Wih, tDWih, 384, 8, 255, 98304);
    k_wt<<<dim3((49152+255)/256),256,0,stream>>>(D_Whh, tDWhh, 384, 7, 127, 49152);
    k_wt<<<dim3((131072+255)/256),256,0,stream>>>(W_tgt, tWtgt, 1024, 7, 127, 131072);
    k_wt<<<dim3((262144+255)/256),256,0,stream>>>(W_src, tWsrc, 1024, 8, 255, 262144);
    k_wtc<<<dim3((262144+255)/256),256,0,stream>>>(W_src, tWsrcC, 262144);

    hipMemsetAsync(state, 0, (size_t)nodes*128*4, stream);
    hipMemsetAsync(inv, 0xFF, (size_t)S*L*4, stream);
    hipMemsetAsync(counts, 0, (size_t)Dn*4, stream);
    hipMemsetAsync(cursor, 0, (size_t)Dn*4, stream);

    k_proj5<<<dim3((Dn*128+255)/256),256,0,stream>>>(realnode, W_dev, b_dev, cIdev, cIdev, state, devA, Dn, nreal, nodes);
    k_proj5<<<dim3(((size_t)F*128+255)/256),256,0,stream>>>(realnode, W_frg, b_frg, cIfrag, cIfrag, state, fragA, F, nreal, nodes);
    k_proj5<<<dim3((S*128+255)/256),256,0,stream>>>(arr, W_srv, b_srv, nullptr, nullptr, h_srv, nullptr, S, S, nodes);
    k_build_inv<<<dim3((F+255)/256),256,0,stream>>>(cFsvc, cFpos, inv, F, L, S);
    k_count<<<dim3((F+255)/256),256,0,stream>>>(cFdr, counts, F, Dn);
    k_scan<<<1,256,0,stream>>>(counts, offs, Dn);
    k_fill<<<dim3((F+255)/256),256,0,stream>>>(cFdr, offs, cursor, list, sortedDev, F, Dn);

    for (int it=0; it<NIT; ++it){
        // phiC: batched gi (MFMA) + fused MFMA recurrence
        mm_bf<<<dim3(3, F/128),256,0,stream>>>(state, state, cIfrag, cFdn, 0,
            tCWih, C_bih, giF, F, 384, 256, 0, 1.f, nullptr, nullptr, nullptr, nullptr, nullptr);
        k_recur<<<dim3(S/16),512,0,stream>>>(h_srv, giF, tCWhhHi, tCWhhLo, C_bhh, inv, out_f, S, L, F);
        // attention
        mm_bf<<<dim3(8, Dn/128),256,0,stream>>>(devA, nullptr, nullptr, nullptr, 128,
            tWtgt, b_tgt, TGT, Dn, 1024, 128, 0, 1.f, nullptr, nullptr, nullptr, nullptr, nullptr);
        hipMemsetAsync(alphaB, 0, (size_t)F*4*4, stream);
        // alpha GEMM in device-sorted row order: tgt rows L1/L2-resident within tiles
        mm_bf<<<dim3(8, F/128),256,0,stream>>>(out_f, fragA, list, list, 0,
            tWsrc, nullptr, nullptr, F, 1024, 256, 1, 1.f, TGT, sortedDev, att, b_src, alphaB);
        k_attn_z<<<dim3(Dn),256,0,stream>>>(out_f, fragA, alphaB, list, offs, Z, saB, Dn, F);
        mm_bf<<<dim3(2, Dn/128),256,0,stream>>>(Z, nullptr, nullptr, nullptr, 1024,
            tWsrcC, nullptr, msgDm, Dn, 256, 1024, 0, 0.25f, nullptr, nullptr, nullptr, nullptr, nullptr);
        k_msgd_fix<<<dim3((Dn*256+255)/256),256,0,stream>>>(msgDm, saB, b_src, bias_att, Dn);
        // F-GRU chunked 2x (in-place, write-through to state)
        for (int c=0;c<2;c++){
            size_t off = (size_t)c*FH;
            mm_bf<<<dim3(3, FH/128),256,0,stream>>>(out_f + off*128, state, nullptr, cFdn + off, 0,
                tFWih, F_bih, TGT, FH, 384, 256, 0, 1.f, nullptr, nullptr, nullptr, nullptr, nullptr);
            mm_bf<<<dim3(3, FH/128),256,0,stream>>>(fragA + off*128, nullptr, nullptr, nullptr, 128,
                tFWhh, F_bhh, Z, FH, 384, 128, 0, 1.f, nullptr, nullptr, nullptr, nullptr, nullptr);
            k_gru<<<dim3(((size_t)FH*128+255)/256),256,0,stream>>>(TGT, Z, fragA + off*128, fragA + off*128,
                state, cIfrag + off, FH, nodes);
        }
        // D-GRU (in-place, write-through to state)
        mm_bf<<<dim3(3, Dn/128),256,0,stream>>>(msgDm, nullptr, nullptr, nullptr, 256,
            tDWih, D_bih, TGT, Dn, 384, 256, 0, 1.f, nullptr, nullptr, nullptr, nullptr, nullptr);
        mm_bf<<<dim3(3, Dn/128),256,0,stream>>>(devA, nullptr, nullptr, nullptr, 128,
            tDWhh, D_bhh, Z, Dn, 384, 128, 0, 1.f, nullptr, nullptr, nullptr, nullptr, nullptr);
        k_gru<<<dim3((Dn*128+255)/256),256,0,stream>>>(TGT, Z, devA, devA, state, cIdev, Dn, nodes);
    }

    // readout
    hipMemsetAsync(pooled, 0, (size_t)S*128*4, stream);
    k_pool_add<<<dim3(((size_t)F*128+255)/256),256,0,stream>>>(fragA, cFsvc, pooled, F, S);
    k_pool_div<<<dim3((S*128+255)/256),256,0,stream>>>(pooled, cLen, S);
    k_mm<<<dim3(256/128, S/128),256,0,stream>>>(pooled, 128, Wl1, 256, bl1, TGT, S, 256, 128, 1, 1.f, 0);
    k_mm<<<dim3(256/128, S/128),256,0,stream>>>(TGT, 256, Wl2, 256, bl2, Z, S, 256, 256, 1, 1.f, 0);
    k_dot_out<<<dim3(S),256,0,stream>>>(Z, Wl3, bl3, outp, 0);
    k_mm<<<dim3(256/128, S/128),256,0,stream>>>(h_srv, 128, Wt1, 256, bt1, TGT, S, 256, 128, 1, 1.f, 0);
    k_mm<<<dim3(256/128, S/128),256,0,stream>>>(TGT, 256, Wt2, 256, bt2, Z, S, 256, 256, 1, 1.f, 0);
    k_dot_out<<<dim3(S),256,0,stream>>>(Z, Wt3, bt3, outp, S);
}

// Round 9
// 1339.562 us; speedup vs baseline: 1.1789x; 1.1789x over previous
//
#include <hip/hip_runtime.h>
#include <hip/hip_bf16.h>

typedef __attribute__((ext_vector_type(8))) short bf16x8;
typedef __attribute__((ext_vector_type(4))) float f32x4;

__device__ __forceinline__ float sigf(float x){ return 1.0f/(1.0f+expf(-x)); }
__device__ __forceinline__ int clampi(int v, int lo, int hi){ return v<lo?lo:(v>hi?hi:v); }
__device__ __forceinline__ unsigned short f2b(float f){
    __hip_bfloat16 h = __float2bfloat16(f);
    return *reinterpret_cast<unsigned short*>(&h);
}
__device__ __forceinline__ float us2f(unsigned short u){ return __uint_as_float(((unsigned)u)<<16); }

// ---- int64/int32 tolerant index conversion ----
__global__ void k_cvt(const int* __restrict__ src, int* __restrict__ dst, int n,
                      const int* __restrict__ det)
{
    int i = blockIdx.x*blockDim.x + threadIdx.x;
    if (i >= n) return;
    int stride = (det[1] == 0) ? 2 : 1;
    dst[i] = src[(size_t)i*stride];
}

// ---- weight transpose+convert: Wt[n][k] (bf16) <- W[k][n] (f32) ----
__global__ void k_wt(const float* __restrict__ W, unsigned short* __restrict__ Wt,
                     int N, int kshift, int kmask, int total)
{
    int idx = blockIdx.x*blockDim.x + threadIdx.x;
    if (idx >= total) return;
    int n = idx >> kshift, k = idx & kmask;
    Wt[idx] = f2b(W[(size_t)k*N + n]);
}

// ---- split transpose+convert: Whi/Wlo[n][k] <- W[k][n], lo = residual ----
__global__ void k_wt2(const float* __restrict__ W, unsigned short* __restrict__ Whi,
                      unsigned short* __restrict__ Wlo, int N, int kshift, int kmask, int total)
{
    int idx = blockIdx.x*blockDim.x + threadIdx.x;
    if (idx >= total) return;
    int n = idx >> kshift, k = idx & kmask;
    float v = W[(size_t)k*N + n];
    unsigned short hi = f2b(v);
    Whi[idx] = hi;
    Wlo[idx] = f2b(v - us2f(hi));
}

// ---------------- init projections ----------------
__global__ void k_proj5(const float* __restrict__ X, const float* __restrict__ W,
                        const float* __restrict__ bias,
                        const int* __restrict__ gidx, const int* __restrict__ sidx,
                        float* __restrict__ out, float* __restrict__ out2, int M, int nrows, int nodes)
{
    int t = blockIdx.x*blockDim.x + threadIdx.x;
    int i = t >> 7, j = t & 127;
    if (i >= M) return;
    int src = gidx ? clampi(gidx[i]-1, 0, nrows-1) : i;
    const float* xp = X + (size_t)src*5;
    float acc = bias[j];
#pragma unroll
    for (int k=0;k<5;k++) acc += xp[k] * W[k*128+j];
    int dr = sidx ? clampi(sidx[i], 0, nodes-1) : i;
    out[(size_t)dr*128 + j] = acc;
    if (out2) out2[(size_t)i*128 + j] = acc;
}

// ---------------- f32 tiled GEMM (readout heads only) ----------------
__launch_bounds__(256)
__global__ void k_mm(const float* __restrict__ A0, int lda,
                     const float* __restrict__ B, int ldb,
                     const float* __restrict__ bias, float* __restrict__ C,
                     int M, int N, int K, int relu, float scale, int accum)
{
    __shared__ float As[16][132];
    __shared__ float Bs[16][132];
    int tid = threadIdx.x;
    int tx = tid & 15, ty = tid >> 4;
    int row0 = blockIdx.y * 128, col0 = blockIdx.x * 128;
    float acc[8][8] = {};
    for (int k0 = 0; k0 < K; k0 += 16){
#pragma unroll
        for (int q = 0; q < 2; ++q){
            int idx = tid + q*256;
            int r = idx >> 2, k4 = (idx & 3) * 4;
            const float* src = A0 + (size_t)(row0+r)*lda + k0 + k4;
            float4 v = *reinterpret_cast<const float4*>(src);
            As[k4+0][r]=v.x; As[k4+1][r]=v.y; As[k4+2][r]=v.z; As[k4+3][r]=v.w;
        }
#pragma unroll
        for (int q = 0; q < 2; ++q){
            int idx = tid + q*256;
            int kb = idx >> 5, n4 = (idx & 31) * 4;
            float4 v = *reinterpret_cast<const float4*>(B + (size_t)(k0+kb)*ldb + col0 + n4);
            *reinterpret_cast<float4*>(&Bs[kb][n4]) = v;
        }
        __syncthreads();
#pragma unroll
        for (int k = 0; k < 16; ++k){
            float a[8], b[8];
            *(float4*)&a[0] = *(const float4*)&As[k][ty*8];
            *(float4*)&a[4] = *(const float4*)&As[k][ty*8+4];
            *(float4*)&b[0] = *(const float4*)&Bs[k][tx*8];
            *(float4*)&b[4] = *(const float4*)&Bs[k][tx*8+4];
#pragma unroll
            for (int i=0;i<8;i++)
#pragma unroll
                for (int j=0;j<8;j++) acc[i][j] += a[i]*b[j];
        }
        __syncthreads();
    }
    float bb[8];
#pragma unroll
    for (int j=0;j<8;j++) bb[j] = bias ? bias[col0+tx*8+j] : 0.f;
#pragma unroll
    for (int i=0;i<8;i++){
        float* cp = C + (size_t)(row0+ty*8+i)*N + col0 + tx*8;
#pragma unroll
        for (int jq=0;jq<2;jq++){
            float4 prev = accum ? *(const float4*)(cp+jq*4) : make_float4(0,0,0,0);
            float o[4];
#pragma unroll
            for (int c=0;c<4;c++){
                float u = acc[i][jq*4+c] + bb[jq*4+c];
                if (relu) u = fmaxf(u,0.f);
                o[c] = (&prev.x)[c] + scale*u;
            }
            *(float4*)(cp+jq*4) = make_float4(o[0],o[1],o[2],o[3]);
        }
    }
}

// ---------------- bf16 MFMA GEMM: C = scale*(A(f32->bf16) @ Wt^T) + bias ----------------
// epi==0: f32 C.  epi==2: bf16 C (SRC materialization).
__launch_bounds__(256)
__global__ void mm_bf(const float* __restrict__ A0, const float* __restrict__ A1,
                      const int* __restrict__ i0, const int* __restrict__ i1, int lda,
                      const unsigned short* __restrict__ Wt,
                      const float* __restrict__ bias, void* __restrict__ C,
                      int M, int N, int K, int epi, float scale)
{
    __shared__ alignas(16) unsigned short As[128*64];
    __shared__ alignas(16) unsigned short Bs[128*64];
    int tid = threadIdx.x;
    int l = tid & 63, w = tid >> 6;
    int wr = w >> 1, wc = w & 1;
    int row0 = blockIdx.y * 128, col0 = blockIdx.x * 128;
    f32x4 acc[4][4];
#pragma unroll
    for (int m=0;m<4;m++)
#pragma unroll
        for (int n=0;n<4;n++) acc[m][n] = (f32x4){0.f,0.f,0.f,0.f};

    for (int k0 = 0; k0 < K; k0 += 64){
#pragma unroll
        for (int q = 0; q < 8; ++q){
            int idx = tid + q*256;
            int r = idx >> 4, c4 = (idx & 15) * 4;
            int kk = k0 + c4;
            const float* src;
            if (A1){
                if (kk < 128){ int ri = i0 ? i0[row0+r] : (row0+r); src = A0 + (size_t)ri*128 + kk; }
                else         { int ri = i1 ? i1[row0+r] : (row0+r); src = A1 + (size_t)ri*128 + (kk-128); }
            } else {
                src = A0 + (size_t)(row0+r)*lda + kk;
            }
            float4 v = *reinterpret_cast<const float4*>(src);
            ushort4 o; o.x=f2b(v.x); o.y=f2b(v.y); o.z=f2b(v.z); o.w=f2b(v.w);
            int csw = c4 ^ ((r & 7) << 3);
            *reinterpret_cast<ushort4*>(&As[r*64 + csw]) = o;
        }
#pragma unroll
        for (int q = 0; q < 4; ++q){
            int idx = tid + q*256;
            int n = idx >> 3, k8 = (idx & 7) * 8;
            uint4 v = *reinterpret_cast<const uint4*>(Wt + (size_t)(col0+n)*K + k0 + k8);
            int ksw = k8 ^ ((n & 7) << 3);
            *reinterpret_cast<uint4*>(&Bs[n*64 + ksw]) = v;
        }
        __syncthreads();
#pragma unroll
        for (int kk = 0; kk < 2; ++kk){
            int ek = kk*32 + (l >> 4) * 8;
            bf16x8 af[4], bf[4];
#pragma unroll
            for (int m=0;m<4;m++){
                int r = wr*64 + m*16 + (l & 15);
                af[m] = *reinterpret_cast<const bf16x8*>(&As[r*64 + (ek ^ ((r & 7) << 3))]);
            }
#pragma unroll
            for (int n=0;n<4;n++){
                int c = wc*64 + n*16 + (l & 15);
                bf[n] = *reinterpret_cast<const bf16x8*>(&Bs[c*64 + (ek ^ ((c & 7) << 3))]);
            }
#pragma unroll
            for (int m=0;m<4;m++)
#pragma unroll
                for (int n=0;n<4;n++)
                    acc[m][n] = __builtin_amdgcn_mfma_f32_16x16x32_bf16(af[m], bf[n], acc[m][n], 0, 0, 0);
        }
        __syncthreads();
    }

#pragma unroll
    for (int m=0;m<4;m++){
#pragma unroll
        for (int v=0;v<4;v++){
            int row = row0 + wr*64 + m*16 + (l >> 4)*4 + v;
            size_t base = (size_t)row*N + col0 + wc*64 + (l & 15);
#pragma unroll
            for (int n=0;n<4;n++){
                int col = col0 + wc*64 + n*16 + (l & 15);
                float u = scale*acc[m][n][v] + (bias ? bias[col] : 0.f);
                if (epi == 0) ((float*)C)[base + n*16] = u;
                else          ((unsigned short*)C)[base + n*16] = f2b(u);
            }
        }
    }
}

// ---------------- fused GAT attention: per-device alpha+softmax+msgD ----------------
// SRC[F][1024] bf16 (b_src folded). One block per device, 4 waves = 4 heads.
__launch_bounds__(256)
__global__ void k_attn(const unsigned short* __restrict__ SRC, const float* __restrict__ tgt,
                       const float* __restrict__ att, const int* __restrict__ list,
                       const int* __restrict__ offs, const float* __restrict__ batt,
                       float* __restrict__ msgD, float* __restrict__ alphaG, int Dn, int F)
{
    __shared__ float tg[1024];
    __shared__ float alds[128*4];
    __shared__ float accs[4][256];
    int d = blockIdx.x;
    int tid = threadIdx.x;
    int w = tid >> 6, lane = tid & 63;
    for (int u = tid; u < 1024; u += 256) tg[u] = tgt[(size_t)d*1024 + u];
    __syncthreads();
    int beg = offs[d], end = offs[d+1];
    if (beg < 0) beg = 0; if (end > F) end = F; if (end < beg) end = beg;
    int c0 = w*256 + lane*4;
    float t0 = tg[c0], t1 = tg[c0+1], t2 = tg[c0+2], t3 = tg[c0+3];
    float a0 = att[c0], a1 = att[c0+1], a2 = att[c0+2], a3 = att[c0+3];
    float amax = -3.4e38f;
    for (int i=beg;i<end;i++){
        int f = list[i];
        ushort4 sv = *reinterpret_cast<const ushort4*>(SRC + (size_t)f*1024 + c0);
        float e0 = us2f(sv.x)+t0, e1 = us2f(sv.y)+t1, e2 = us2f(sv.z)+t2, e3 = us2f(sv.w)+t3;
        e0 = e0>0.f?e0:0.2f*e0; e1 = e1>0.f?e1:0.2f*e1;
        e2 = e2>0.f?e2:0.2f*e2; e3 = e3>0.f?e3:0.2f*e3;
        float s = e0*a0 + e1*a1 + e2*a2 + e3*a3;
#pragma unroll
        for (int msk=1; msk<64; msk<<=1) s += __shfl_xor(s, msk);
        int li = i - beg;
        if (li < 128){ if (lane == 0) alds[li*4+w] = s; }
        else         { if (lane == 0) alphaG[(size_t)f*4+w] = s; }
        amax = fmaxf(amax, s);
    }
    __syncthreads();
    float wsum = 0.f;
    for (int i=beg;i<end;i++){
        int li = i - beg;
        float a = (li < 128) ? alds[li*4+w] : alphaG[(size_t)list[i]*4+w];
        wsum += expf(a - amax);
    }
    float iws = 1.f/(wsum + 1e-16f);
    float acc[4] = {0,0,0,0};
    for (int i=beg;i<end;i++){
        int f = list[i];
        int li = i - beg;
        float a = (li < 128) ? alds[li*4+w] : alphaG[(size_t)f*4+w];
        float p = expf(a - amax)*iws;
        ushort4 sv = *reinterpret_cast<const ushort4*>(SRC + (size_t)f*1024 + c0);
        acc[0] += p*us2f(sv.x); acc[1] += p*us2f(sv.y);
        acc[2] += p*us2f(sv.z); acc[3] += p*us2f(sv.w);
    }
#pragma unroll
    for (int j=0;j<4;j++) accs[w][lane*4+j] = acc[j];
    __syncthreads();
    if (tid < 256){
        float m = (accs[0][tid]+accs[1][tid]+accs[2][tid]+accs[3][tid])*0.25f + batt[tid];
        msgD[(size_t)d*256 + tid] = m;
    }
}

// ---------------- fused phiC recurrence: MFMA gh, Whh stationary in registers ----------------
__launch_bounds__(512)
__global__ void k_recur(float* __restrict__ h_srv, const float* __restrict__ giF,
                        const unsigned short* __restrict__ Whi,
                        const unsigned short* __restrict__ Wlo,
                        const float* __restrict__ bhh,
                        const int* __restrict__ inv, float* __restrict__ out_f,
                        int S, int L, int F)
{
    __shared__ float hs[16][132];
    __shared__ float ghs[16][388];
    __shared__ int fLoc[16];
    int tid = threadIdx.x;
    int l = tid & 63, w = tid >> 6;
    int lane15 = l & 15, lhi = l >> 4;
    int s0 = blockIdx.x * 16;
    for (int u = tid; u < 2048; u += 512){ int s=u>>7,k=u&127; hs[s][k] = h_srv[(size_t)(s0+s)*128+k]; }
    bf16x8 wHi[3][4], wLo[3][4];
#pragma unroll
    for (int ct=0; ct<3; ++ct){
        int col = w*48 + ct*16 + lane15;
#pragma unroll
        for (int ks=0; ks<4; ++ks){
            size_t off = (size_t)col*128 + ks*32 + lhi*8;
            wHi[ct][ks] = *reinterpret_cast<const bf16x8*>(Whi + off);
            wLo[ct][ks] = *reinterpret_cast<const bf16x8*>(Wlo + off);
        }
    }
    __syncthreads();
    for (int t=0;t<L;++t){
        if (tid < 16) fLoc[tid] = inv[(size_t)(s0+tid)*L + t];
        __syncthreads();
        bf16x8 hHi[4], hLo[4];
#pragma unroll
        for (int ks=0; ks<4; ++ks){
            const float* hp = &hs[lane15][ks*32 + lhi*8];
#pragma unroll
            for (int j=0;j<8;j++){
                float v = hp[j];
                unsigned short hi = f2b(v);
                hHi[ks][j] = (short)hi;
                hLo[ks][j] = (short)f2b(v - us2f(hi));
            }
        }
#pragma unroll
        for (int ct=0; ct<3; ++ct){
            f32x4 acc = (f32x4){0.f,0.f,0.f,0.f};
#pragma unroll
            for (int ks=0; ks<4; ++ks){
                acc = __builtin_amdgcn_mfma_f32_16x16x32_bf16(hHi[ks], wHi[ct][ks], acc, 0,0,0);
                acc = __builtin_amdgcn_mfma_f32_16x16x32_bf16(hLo[ks], wHi[ct][ks], acc, 0,0,0);
                acc = __builtin_amdgcn_mfma_f32_16x16x32_bf16(hHi[ks], wLo[ct][ks], acc, 0,0,0);
            }
            int col = w*48 + ct*16 + lane15;
            float bb = bhh[col];
#pragma unroll
            for (int v=0; v<4; ++v){
                ghs[lhi*4 + v][col] = acc[v] + bb;
            }
        }
        __syncthreads();
        for (int u = tid; u < 2048; u += 512){
            int s=u>>7, k=u&127; int f = fLoc[s];
            if (f >= 0 && f < F){
                const float* gp = giF + (size_t)f*384;
                float r  = sigf(gp[k]     + ghs[s][k]);
                float zz = sigf(gp[128+k] + ghs[s][128+k]);
                float n  = tanhf(gp[256+k] + r*ghs[s][256+k]);
                float hn = (1.f-zz)*n + zz*hs[s][k];
                hs[s][k] = hn;
                out_f[(size_t)f*128+k] = hn;
            }
        }
        __syncthreads();
    }
    for (int u = tid; u < 2048; u += 512){ int s=u>>7,k=u&127; h_srv[(size_t)(s0+s)*128+k] = hs[s][k]; }
}

// ---------------- GRU pointwise with state write-through ----------------
__global__ void k_gru(const float* __restrict__ gi, const float* __restrict__ gh,
                      const float* __restrict__ hin, float* __restrict__ hout,
                      float* __restrict__ state, const int* __restrict__ sidx,
                      int M, int nodes)
{
    int idx = blockIdx.x*blockDim.x + threadIdx.x;
    int i = idx >> 7, j = idx & 127;
    if (i >= M) return;
    size_t g = (size_t)i*384;
    float r = sigf(gi[g+j]     + gh[g+j]);
    float z = sigf(gi[g+128+j] + gh[g+128+j]);
    float n = tanhf(gi[g+256+j] + r*gh[g+256+j]);
    float hv = hin[(size_t)i*128+j];
    float hn = (1.f-z)*n + z*hv;
    hout[(size_t)i*128+j] = hn;
    if (state) state[(size_t)clampi(sidx[i],0,nodes-1)*128 + j] = hn;
}

__global__ void k_count(const int* __restrict__ row, int* __restrict__ counts, int F, int Dn)
{ int f = blockIdx.x*blockDim.x + threadIdx.x; if (f < F) atomicAdd(&counts[clampi(row[f],0,Dn-1)], 1); }

__global__ void k_scan(const int* __restrict__ counts, int* __restrict__ offs, int D)
{
    __shared__ int part[257];
    int tid = threadIdx.x;
    int per = (D + 255) / 256;
    int s = 0;
    for (int i=0;i<per;i++){ int idx = tid*per+i; if (idx < D) s += counts[idx]; }
    part[tid] = s;
    __syncthreads();
    if (tid == 0){
        int acc = 0;
        for (int i=0;i<256;i++){ int v = part[i]; part[i] = acc; acc += v; }
        part[256] = acc;
    }
    __syncthreads();
    int acc = part[tid];
    for (int i=0;i<per;i++){ int idx = tid*per+i; if (idx < D){ offs[idx] = acc; acc += counts[idx]; } }
    if (tid == 0) offs[D] = part[256];
}

__global__ void k_fill(const int* __restrict__ row, const int* __restrict__ offs,
                       int* __restrict__ cursor, int* __restrict__ list, int F, int Dn)
{
    int f = blockIdx.x*blockDim.x + threadIdx.x;
    if (f >= F) return;
    int r = clampi(row[f],0,Dn-1);
    int p = atomicAdd(&cursor[r], 1);
    int pos = offs[r]+p;
    if (pos >= 0 && pos < F) list[pos] = f;
}

__global__ void k_build_inv(const int* __restrict__ fs, const int* __restrict__ fp,
                            int* __restrict__ inv, int F, int L, int S)
{
    int f = blockIdx.x*blockDim.x + threadIdx.x;
    if (f >= F) return;
    inv[clampi(fs[f],0,S-1)*L + clampi(fp[f],0,L-1)] = f;
}

__global__ void k_pool_add(const float* __restrict__ frag, const int* __restrict__ fs,
                           float* __restrict__ pooled, int F, int S)
{
    int t = blockIdx.x*blockDim.x + threadIdx.x;
    int i = t >> 7, j = t & 127;
    if (i >= F) return;
    atomicAdd(&pooled[(size_t)clampi(fs[i],0,S-1)*128 + j], frag[(size_t)i*128 + j]);
}

__global__ void k_pool_div(float* __restrict__ pooled, const int* __restrict__ lengths, int S)
{
    int t = blockIdx.x*blockDim.x + threadIdx.x;
    int i = t >> 7, j = t & 127;
    if (i >= S) return;
    int l = lengths[i]; if (l < 1) l = 1;
    pooled[(size_t)i*128 + j] /= (float)l;
}

__global__ void k_dot_out(const float* __restrict__ H, const float* __restrict__ W3,
                          const float* __restrict__ b3, float* __restrict__ outv, int off)
{
    __shared__ float red[256];
    int s = blockIdx.x, tid = threadIdx.x;
    red[tid] = H[(size_t)s*256 + tid] * W3[tid];
    __syncthreads();
    for (int st=128; st; st>>=1){ if (tid < st) red[tid] += red[tid+st]; __syncthreads(); }
    if (tid == 0) outv[off + s] = red[0] + b3[0];
}

// =====================================================================================
extern "C" void kernel_launch(void* const* d_in, const int* in_sizes, int n_in,
                              void* d_out, int out_size, void* d_ws, size_t ws_size,
                              hipStream_t stream)
{
    (void)n_in; (void)out_size; (void)ws_size;
    const float* realnode = (const float*)d_in[0];
    const float* arr      = (const float*)d_in[1];
    const int* r_exe   = (const int*)d_in[2];
    const int* r_idev  = (const int*)d_in[3];
    const int* r_ifrag = (const int*)d_in[4];
    const int* r_fdn   = (const int*)d_in[5];
    const int* r_fdr   = (const int*)d_in[6];
    const int* r_len   = (const int*)d_in[7];
    const int* r_fsvc  = (const int*)d_in[8];
    const int* r_fpos  = (const int*)d_in[9];
    const float *W_dev=(const float*)d_in[10], *b_dev=(const float*)d_in[11];
    const float *W_frg=(const float*)d_in[12], *b_frg=(const float*)d_in[13];
    const float *W_srv=(const float*)d_in[14], *b_srv=(const float*)d_in[15];
    const float *C_Wih=(const float*)d_in[16], *C_Whh=(const float*)d_in[17], *C_bih=(const float*)d_in[18], *C_bhh=(const float*)d_in[19];
    const float *F_Wih=(const float*)d_in[20], *F_Whh=(const float*)d_in[21], *F_bih=(const float*)d_in[22], *F_bhh=(const float*)d_in[23];
    const float *D_Wih=(const float*)d_in[24], *D_Whh=(const float*)d_in[25], *D_bih=(const float*)d_in[26], *D_bhh=(const float*)d_in[27];
    const float *W_src=(const float*)d_in[28], *b_src=(const float*)d_in[29];
    const float *W_tgt=(const float*)d_in[30], *b_tgt=(const float*)d_in[31];
    const float *att=(const float*)d_in[32], *bias_att=(const float*)d_in[33];
    const float *Wt1=(const float*)d_in[34], *bt1=(const float*)d_in[35], *Wt2=(const float*)d_in[36], *bt2=(const float*)d_in[37], *Wt3=(const float*)d_in[38], *bt3=(const float*)d_in[39];
    const float *Wl1=(const float*)d_in[40], *bl1=(const float*)d_in[41], *Wl2=(const float*)d_in[42], *bl2=(const float*)d_in[43], *Wl3=(const float*)d_in[44], *bl3=(const float*)d_in[45];
    float* outp = (float*)d_out;

    const int S  = in_sizes[7];
    const int Dn = in_sizes[3];
    const int F  = in_sizes[4];
    const int L  = in_sizes[2] / (2*S);
    const int nreal = in_sizes[0]/5;
    const int nodes = nreal + 1;
    const int NIT = 3;
    const int FH = F/2;

    char* wp = (char*)d_ws;
    auto alloc = [&](size_t nelem)->float*{
        float* p = (float*)wp;
        wp += ((nelem*4 + 255)/256)*256;
        return p;
    };
    float* state  = alloc((size_t)nodes*128);
    float* h_srv  = alloc((size_t)S*128);
    float* out_f  = alloc((size_t)F*128);
    float* fragA  = alloc((size_t)F*128);
    float* devA   = alloc((size_t)Dn*128);
    float* alphaB = alloc((size_t)F*4);
    float* msgDm  = alloc((size_t)Dn*256);
    // union region: giF (F*384 f32, live in phiC) / SRC (F*1024 bf16 = F*512 f32, live in attention)
    float* UNION  = alloc((size_t)F*512);
    float* giF    = UNION;
    unsigned short* SRC = (unsigned short*)UNION;
    float* TGT    = alloc((size_t)Dn*1024);
    float* Z      = alloc((size_t)Dn*1024);
    float* pooled = alloc((size_t)S*128);
    unsigned short* tCWih   = (unsigned short*)alloc(384*256/2);
    unsigned short* tCWhhHi = (unsigned short*)alloc(384*128/2);
    unsigned short* tCWhhLo = (unsigned short*)alloc(384*128/2);
    unsigned short* tFWih   = (unsigned short*)alloc(384*256/2);
    unsigned short* tFWhh   = (unsigned short*)alloc(384*128/2);
    unsigned short* tDWih   = (unsigned short*)alloc(384*256/2);
    unsigned short* tDWhh   = (unsigned short*)alloc(384*128/2);
    unsigned short* tWtgt   = (unsigned short*)alloc(1024*128/2);
    unsigned short* tWsrc   = (unsigned short*)alloc(1024*256/2);
    int* cExe   = (int*)alloc((size_t)S*2*L);
    int* cIdev  = (int*)alloc((size_t)Dn);
    int* cIfrag = (int*)alloc((size_t)F);
    int* cFdn   = (int*)alloc((size_t)F);
    int* cFdr   = (int*)alloc((size_t)F);
    int* cLen   = (int*)alloc((size_t)S);
    int* cFsvc  = (int*)alloc((size_t)F);
    int* cFpos  = (int*)alloc((size_t)F);
    int* inv    = (int*)alloc((size_t)S*L);
    int* counts = (int*)alloc((size_t)Dn);
    int* offs   = (int*)alloc((size_t)Dn+1);
    int* cursor = (int*)alloc((size_t)Dn);
    int* list   = (int*)alloc((size_t)F);

    const int* det = r_idev;
    auto cvt = [&](const int* src, int* dst, int n){
        k_cvt<<<dim3((n+255)/256),256,0,stream>>>(src, dst, n, det);
    };
    cvt(r_exe,  cExe,  S*2*L);
    cvt(r_idev, cIdev, Dn);
    cvt(r_ifrag,cIfrag,F);
    cvt(r_fdn,  cFdn,  F);
    cvt(r_fdr,  cFdr,  F);
    cvt(r_len,  cLen,  S);
    cvt(r_fsvc, cFsvc, F);
    cvt(r_fpos, cFpos, F);

    k_wt<<<dim3((98304+255)/256),256,0,stream>>>(C_Wih, tCWih, 384, 8, 255, 98304);
    k_wt2<<<dim3((49152+255)/256),256,0,stream>>>(C_Whh, tCWhhHi, tCWhhLo, 384, 7, 127, 49152);
    k_wt<<<dim3((98304+255)/256),256,0,stream>>>(F_Wih, tFWih, 384, 8, 255, 98304);
    k_wt<<<dim3((49152+255)/256),256,0,stream>>>(F_Whh, tFWhh, 384, 7, 127, 49152);
    k_wt<<<dim3((98304+255)/256),256,0,stream>>>(D_Wih, tDWih, 384, 8, 255, 98304);
    k_wt<<<dim3((49152+255)/256),256,0,stream>>>(D_Whh, tDWhh, 384, 7, 127, 49152);
    k_wt<<<dim3((131072+255)/256),256,0,stream>>>(W_tgt, tWtgt, 1024, 7, 127, 131072);
    k_wt<<<dim3((262144+255)/256),256,0,stream>>>(W_src, tWsrc, 1024, 8, 255, 262144);

    hipMemsetAsync(state, 0, (size_t)nodes*128*4, stream);
    hipMemsetAsync(inv, 0xFF, (size_t)S*L*4, stream);
    hipMemsetAsync(counts, 0, (size_t)Dn*4, stream);
    hipMemsetAsync(cursor, 0, (size_t)Dn*4, stream);

    k_proj5<<<dim3((Dn*128+255)/256),256,0,stream>>>(realnode, W_dev, b_dev, cIdev, cIdev, state, devA, Dn, nreal, nodes);
    k_proj5<<<dim3(((size_t)F*128+255)/256),256,0,stream>>>(realnode, W_frg, b_frg, cIfrag, cIfrag, state, fragA, F, nreal, nodes);
    k_proj5<<<dim3((S*128+255)/256),256,0,stream>>>(arr, W_srv, b_srv, nullptr, nullptr, h_srv, nullptr, S, S, nodes);
    k_build_inv<<<dim3((F+255)/256),256,0,stream>>>(cFsvc, cFpos, inv, F, L, S);
    k_count<<<dim3((F+255)/256),256,0,stream>>>(cFdr, counts, F, Dn);
    k_scan<<<1,256,0,stream>>>(counts, offs, Dn);
    k_fill<<<dim3((F+255)/256),256,0,stream>>>(cFdr, offs, cursor, list, F, Dn);

    for (int it=0; it<NIT; ++it){
        // phiC: batched gi (MFMA) + fused MFMA recurrence
        mm_bf<<<dim3(3, F/128),256,0,stream>>>(state, state, cIfrag, cFdn, 0,
            tCWih, C_bih, giF, F, 384, 256, 0, 1.f);
        k_recur<<<dim3(S/16),512,0,stream>>>(h_srv, giF, tCWhhHi, tCWhhLo, C_bhh, inv, out_f, S, L, F);
        // attention: tgt GEMM, SRC materialization (bf16, b_src folded), fused per-device GAT
        mm_bf<<<dim3(8, Dn/128),256,0,stream>>>(devA, nullptr, nullptr, nullptr, 128,
            tWtgt, b_tgt, TGT, Dn, 1024, 128, 0, 1.f);
        mm_bf<<<dim3(8, F/128),256,0,stream>>>(out_f, fragA, nullptr, nullptr, 0,
            tWsrc, b_src, SRC, F, 1024, 256, 2, 1.f);
        k_attn<<<dim3(Dn),256,0,stream>>>(SRC, TGT, att, list, offs, bias_att, msgDm, alphaB, Dn, F);
        // F-GRU chunked 2x (in-place, write-through to state)
        for (int c=0;c<2;c++){
            size_t off = (size_t)c*FH;
            mm_bf<<<dim3(3, FH/128),256,0,stream>>>(out_f + off*128, state, nullptr, cFdn + off, 0,
                tFWih, F_bih, TGT, FH, 384, 256, 0, 1.f);
            mm_bf<<<dim3(3, FH/128),256,0,stream>>>(fragA + off*128, nullptr, nullptr, nullptr, 128,
                tFWhh, F_bhh, Z, FH, 384, 128, 0, 1.f);
            k_gru<<<dim3(((size_t)FH*128+255)/256),256,0,stream>>>(TGT, Z, fragA + off*128, fragA + off*128,
                state, cIfrag + off, FH, nodes);
        }
        // D-GRU (in-place, write-through to state)
        mm_bf<<<dim3(3, Dn/128),256,0,stream>>>(msgDm, nullptr, nullptr, nullptr, 256,
            tDWih, D_bih, TGT, Dn, 384, 256, 0, 1.f);
        mm_bf<<<dim3(3, Dn/128),256,0,stream>>>(devA, nullptr, nullptr, nullptr, 128,
            tDWhh, D_bhh, Z, Dn, 384, 128, 0, 1.f);
        k_gru<<<dim3((Dn*128+255)/256),256,0,stream>>>(TGT, Z, devA, devA, state, cIdev, Dn, nodes);
    }

    // readout
    hipMemsetAsync(pooled, 0, (size_t)S*128*4, stream);
    k_pool_add<<<dim3(((size_t)F*128+255)/256),256,0,stream>>>(fragA, cFsvc, pooled, F, S);
    k_pool_div<<<dim3((S*128+255)/256),256,0,stream>>>(pooled, cLen, S);
    k_mm<<<dim3(256/128, S/128),256,0,stream>>>(pooled, 128, Wl1, 256, bl1, TGT, S, 256, 128, 1, 1.f, 0);
    k_mm<<<dim3(256/128, S/128),256,0,stream>>>(TGT, 256, Wl2, 256, bl2, Z, S, 256, 256, 1, 1.f, 0);
    k_dot_out<<<dim3(S),256,0,stream>>>(Z, Wl3, bl3, outp, 0);
    k_mm<<<dim3(256/128, S/128),256,0,stream>>>(h_srv, 128, Wt1, 256, bt1, TGT, S, 256, 128, 1, 1.f, 0);
    k_mm<<<dim3(256/128, S/128),256,0,stream>>>(TGT, 256, Wt2, 256, bt2, Z, S, 256, 256, 1, 1.f, 0);
    k_dot_out<<<dim3(S),256,0,stream>>>(Z, Wt3, bt3, outp, S);
}

// Round 10
// 1040.415 us; speedup vs baseline: 1.5179x; 1.2875x over previous
//
#include <hip/hip_runtime.h>
#include <hip/hip_bf16.h>

typedef __attribute__((ext_vector_type(8))) short bf16x8;
typedef __attribute__((ext_vector_type(4))) float f32x4;

__device__ __forceinline__ float sigf(float x){ return 1.0f/(1.0f+expf(-x)); }
__device__ __forceinline__ int clampi(int v, int lo, int hi){ return v<lo?lo:(v>hi?hi:v); }
__device__ __forceinline__ unsigned short f2b(float f){
    __hip_bfloat16 h = __float2bfloat16(f);
    return *reinterpret_cast<unsigned short*>(&h);
}
__device__ __forceinline__ float us2f(unsigned short u){ return __uint_as_float(((unsigned)u)<<16); }

// ---- int64/int32 tolerant index conversion ----
__global__ void k_cvt(const int* __restrict__ src, int* __restrict__ dst, int n,
                      const int* __restrict__ det)
{
    int i = blockIdx.x*blockDim.x + threadIdx.x;
    if (i >= n) return;
    int stride = (det[1] == 0) ? 2 : 1;
    dst[i] = src[(size_t)i*stride];
}

// ---- weight transpose+convert: Wt[n][k] (bf16) <- W[k][n] (f32) ----
__global__ void k_wt(const float* __restrict__ W, unsigned short* __restrict__ Wt,
                     int N, int kshift, int kmask, int total)
{
    int idx = blockIdx.x*blockDim.x + threadIdx.x;
    if (idx >= total) return;
    int n = idx >> kshift, k = idx & kmask;
    Wt[idx] = f2b(W[(size_t)k*N + n]);
}

// ---- split transpose+convert: Whi/Wlo[n][k] <- W[k][n], lo = residual ----
__global__ void k_wt2(const float* __restrict__ W, unsigned short* __restrict__ Whi,
                      unsigned short* __restrict__ Wlo, int N, int kshift, int kmask, int total)
{
    int idx = blockIdx.x*blockDim.x + threadIdx.x;
    if (idx >= total) return;
    int n = idx >> kshift, k = idx & kmask;
    float v = W[(size_t)k*N + n];
    unsigned short hi = f2b(v);
    Whi[idx] = hi;
    Wlo[idx] = f2b(v - us2f(hi));
}

// ---------------- init projections ----------------
__global__ void k_proj5(const float* __restrict__ X, const float* __restrict__ W,
                        const float* __restrict__ bias,
                        const int* __restrict__ gidx, const int* __restrict__ sidx,
                        float* __restrict__ out, float* __restrict__ out2, int M, int nrows, int nodes)
{
    int t = blockIdx.x*blockDim.x + threadIdx.x;
    int i = t >> 7, j = t & 127;
    if (i >= M) return;
    int src = gidx ? clampi(gidx[i]-1, 0, nrows-1) : i;
    const float* xp = X + (size_t)src*5;
    float acc = bias[j];
#pragma unroll
    for (int k=0;k<5;k++) acc += xp[k] * W[k*128+j];
    int dr = sidx ? clampi(sidx[i], 0, nodes-1) : i;
    out[(size_t)dr*128 + j] = acc;
    if (out2) out2[(size_t)i*128 + j] = acc;
}

// ---------------- f32 tiled GEMM (readout heads only) ----------------
__launch_bounds__(256)
__global__ void k_mm(const float* __restrict__ A0, int lda,
                     const float* __restrict__ B, int ldb,
                     const float* __restrict__ bias, float* __restrict__ C,
                     int M, int N, int K, int relu, float scale, int accum)
{
    __shared__ float As[16][132];
    __shared__ float Bs[16][132];
    int tid = threadIdx.x;
    int tx = tid & 15, ty = tid >> 4;
    int row0 = blockIdx.y * 128, col0 = blockIdx.x * 128;
    float acc[8][8] = {};
    for (int k0 = 0; k0 < K; k0 += 16){
#pragma unroll
        for (int q = 0; q < 2; ++q){
            int idx = tid + q*256;
            int r = idx >> 2, k4 = (idx & 3) * 4;
            const float* src = A0 + (size_t)(row0+r)*lda + k0 + k4;
            float4 v = *reinterpret_cast<const float4*>(src);
            As[k4+0][r]=v.x; As[k4+1][r]=v.y; As[k4+2][r]=v.z; As[k4+3][r]=v.w;
        }
#pragma unroll
        for (int q = 0; q < 2; ++q){
            int idx = tid + q*256;
            int kb = idx >> 5, n4 = (idx & 31) * 4;
            float4 v = *reinterpret_cast<const float4*>(B + (size_t)(k0+kb)*ldb + col0 + n4);
            *reinterpret_cast<float4*>(&Bs[kb][n4]) = v;
        }
        __syncthreads();
#pragma unroll
        for (int k = 0; k < 16; ++k){
            float a[8], b[8];
            *(float4*)&a[0] = *(const float4*)&As[k][ty*8];
            *(float4*)&a[4] = *(const float4*)&As[k][ty*8+4];
            *(float4*)&b[0] = *(const float4*)&Bs[k][tx*8];
            *(float4*)&b[4] = *(const float4*)&Bs[k][tx*8+4];
#pragma unroll
            for (int i=0;i<8;i++)
#pragma unroll
                for (int j=0;j<8;j++) acc[i][j] += a[i]*b[j];
        }
        __syncthreads();
    }
    float bb[8];
#pragma unroll
    for (int j=0;j<8;j++) bb[j] = bias ? bias[col0+tx*8+j] : 0.f;
#pragma unroll
    for (int i=0;i<8;i++){
        float* cp = C + (size_t)(row0+ty*8+i)*N + col0 + tx*8;
#pragma unroll
        for (int jq=0;jq<2;jq++){
            float4 prev = accum ? *(const float4*)(cp+jq*4) : make_float4(0,0,0,0);
            float o[4];
#pragma unroll
            for (int c=0;c<4;c++){
                float u = acc[i][jq*4+c] + bb[jq*4+c];
                if (relu) u = fmaxf(u,0.f);
                o[c] = (&prev.x)[c] + scale*u;
            }
            *(float4*)(cp+jq*4) = make_float4(o[0],o[1],o[2],o[3]);
        }
    }
}

// ---------------- bf16 MFMA GEMM: C = scale*(A(f32->bf16) @ Wt^T) + bias ----------------
// 1D grid, XCD-friendly order: by = bid % nrow (col-tiles of a row share an XCD's L2).
// epi==0: f32 C.  epi==2: bf16 C.
__launch_bounds__(256)
__global__ void mm_bf(const float* __restrict__ A0, const float* __restrict__ A1,
                      const int* __restrict__ i0, const int* __restrict__ i1, int lda,
                      const unsigned short* __restrict__ Wt,
                      const float* __restrict__ bias, void* __restrict__ C,
                      int M, int N, int K, int epi, float scale, int nrow)
{
    __shared__ alignas(16) unsigned short As[128*64];
    __shared__ alignas(16) unsigned short Bs[128*64];
    int tid = threadIdx.x;
    int l = tid & 63, w = tid >> 6;
    int wr = w >> 1, wc = w & 1;
    int bid = blockIdx.x;
    int row0 = (bid % nrow) * 128, col0 = (bid / nrow) * 128;
    f32x4 acc[4][4];
#pragma unroll
    for (int m=0;m<4;m++)
#pragma unroll
        for (int n=0;n<4;n++) acc[m][n] = (f32x4){0.f,0.f,0.f,0.f};

    for (int k0 = 0; k0 < K; k0 += 64){
#pragma unroll
        for (int q = 0; q < 8; ++q){
            int idx = tid + q*256;
            int r = idx >> 4, c4 = (idx & 15) * 4;
            int kk = k0 + c4;
            const float* src;
            if (A1){
                if (kk < 128){ int ri = i0 ? i0[row0+r] : (row0+r); src = A0 + (size_t)ri*128 + kk; }
                else         { int ri = i1 ? i1[row0+r] : (row0+r); src = A1 + (size_t)ri*128 + (kk-128); }
            } else {
                src = A0 + (size_t)(row0+r)*lda + kk;
            }
            float4 v = *reinterpret_cast<const float4*>(src);
            ushort4 o; o.x=f2b(v.x); o.y=f2b(v.y); o.z=f2b(v.z); o.w=f2b(v.w);
            int csw = c4 ^ ((r & 7) << 3);
            *reinterpret_cast<ushort4*>(&As[r*64 + csw]) = o;
        }
#pragma unroll
        for (int q = 0; q < 4; ++q){
            int idx = tid + q*256;
            int n = idx >> 3, k8 = (idx & 7) * 8;
            uint4 v = *reinterpret_cast<const uint4*>(Wt + (size_t)(col0+n)*K + k0 + k8);
            int ksw = k8 ^ ((n & 7) << 3);
            *reinterpret_cast<uint4*>(&Bs[n*64 + ksw]) = v;
        }
        __syncthreads();
#pragma unroll
        for (int kk = 0; kk < 2; ++kk){
            int ek = kk*32 + (l >> 4) * 8;
            bf16x8 af[4], bf[4];
#pragma unroll
            for (int m=0;m<4;m++){
                int r = wr*64 + m*16 + (l & 15);
                af[m] = *reinterpret_cast<const bf16x8*>(&As[r*64 + (ek ^ ((r & 7) << 3))]);
            }
#pragma unroll
            for (int n=0;n<4;n++){
                int c = wc*64 + n*16 + (l & 15);
                bf[n] = *reinterpret_cast<const bf16x8*>(&Bs[c*64 + (ek ^ ((c & 7) << 3))]);
            }
#pragma unroll
            for (int m=0;m<4;m++)
#pragma unroll
                for (int n=0;n<4;n++)
                    acc[m][n] = __builtin_amdgcn_mfma_f32_16x16x32_bf16(af[m], bf[n], acc[m][n], 0, 0, 0);
        }
        __syncthreads();
    }

#pragma unroll
    for (int m=0;m<4;m++){
#pragma unroll
        for (int v=0;v<4;v++){
            int row = row0 + wr*64 + m*16 + (l >> 4)*4 + v;
            size_t base = (size_t)row*N + col0 + wc*64 + (l & 15);
#pragma unroll
            for (int n=0;n<4;n++){
                int col = col0 + wc*64 + n*16 + (l & 15);
                float u = scale*acc[m][n][v] + (bias ? bias[col] : 0.f);
                if (epi == 0) ((float*)C)[base + n*16] = u;
                else          ((unsigned short*)C)[base + n*16] = f2b(u);
            }
        }
    }
}

// ---------------- fully fused GRU: h' = GRU(x@Wih+bih, h@Whh+bhh, h) ----------------
// 512 threads = 8 waves; wave w owns rows [w*16, w*16+16) of a 128-row panel.
// gi: K=256 (two-half indexed A like mm_bf). gh: K=128 from H. n-gate gh kept separate (accN).
__launch_bounds__(512)
__global__ void k_grufuse(const float* __restrict__ A0, const float* __restrict__ A1,
                          const int* __restrict__ i0, const int* __restrict__ i1, int lda,
                          const unsigned short* __restrict__ Wih,   // [384][256] bf16
                          const unsigned short* __restrict__ Whh,   // [384][128] bf16
                          const float* __restrict__ bih, const float* __restrict__ bhh,
                          float* __restrict__ H, float* __restrict__ state,
                          const int* __restrict__ sidx, int M, int nodes)
{
    __shared__ alignas(16) unsigned short As[128*64];   // 16 KB
    __shared__ alignas(16) unsigned short Bs[384*64];   // 48 KB
    int tid = threadIdx.x;
    int l = tid & 63, w = tid >> 6;
    int row0 = blockIdx.x * 128;
    f32x4 acc[24], accN[8];
#pragma unroll
    for (int n=0;n<24;n++) acc[n] = (f32x4){0.f,0.f,0.f,0.f};
#pragma unroll
    for (int n=0;n<8;n++) accN[n] = (f32x4){0.f,0.f,0.f,0.f};

    // ---- gi: K=256 over Wih ----
    for (int k0 = 0; k0 < 256; k0 += 64){
#pragma unroll
        for (int q = 0; q < 4; ++q){
            int idx = tid + q*512;
            int r = idx >> 4, c4 = (idx & 15) * 4;
            int kk = k0 + c4;
            const float* src;
            if (A1){
                if (kk < 128){ int ri = i0 ? i0[row0+r] : (row0+r); src = A0 + (size_t)ri*128 + kk; }
                else         { int ri = i1 ? i1[row0+r] : (row0+r); src = A1 + (size_t)ri*128 + (kk-128); }
            } else {
                src = A0 + (size_t)(row0+r)*lda + kk;
            }
            float4 v = *reinterpret_cast<const float4*>(src);
            ushort4 o; o.x=f2b(v.x); o.y=f2b(v.y); o.z=f2b(v.z); o.w=f2b(v.w);
            int csw = c4 ^ ((r & 7) << 3);
            *reinterpret_cast<ushort4*>(&As[r*64 + csw]) = o;
        }
#pragma unroll
        for (int q = 0; q < 6; ++q){
            int idx = tid + q*512;
            int n = idx >> 3, k8 = (idx & 7) * 8;
            uint4 v = *reinterpret_cast<const uint4*>(Wih + (size_t)n*256 + k0 + k8);
            int ksw = k8 ^ ((n & 7) << 3);
            *reinterpret_cast<uint4*>(&Bs[n*64 + ksw]) = v;
        }
        __syncthreads();
#pragma unroll
        for (int kk = 0; kk < 2; ++kk){
            int ek = kk*32 + (l >> 4) * 8;
            int r = w*16 + (l & 15);
            bf16x8 af = *reinterpret_cast<const bf16x8*>(&As[r*64 + (ek ^ ((r & 7) << 3))]);
#pragma unroll
            for (int n=0;n<24;n++){
                int c = n*16 + (l & 15);
                bf16x8 bf = *reinterpret_cast<const bf16x8*>(&Bs[c*64 + (ek ^ ((c & 7) << 3))]);
                acc[n] = __builtin_amdgcn_mfma_f32_16x16x32_bf16(af, bf, acc[n], 0, 0, 0);
            }
        }
        __syncthreads();
    }
    // ---- gh: K=128 over Whh, A = H (h_old) ----
    for (int k0 = 0; k0 < 128; k0 += 64){
#pragma unroll
        for (int q = 0; q < 4; ++q){
            int idx = tid + q*512;
            int r = idx >> 4, c4 = (idx & 15) * 4;
            const float* src = H + (size_t)(row0+r)*128 + k0 + c4;
            float4 v = *reinterpret_cast<const float4*>(src);
            ushort4 o; o.x=f2b(v.x); o.y=f2b(v.y); o.z=f2b(v.z); o.w=f2b(v.w);
            int csw = c4 ^ ((r & 7) << 3);
            *reinterpret_cast<ushort4*>(&As[r*64 + csw]) = o;
        }
#pragma unroll
        for (int q = 0; q < 6; ++q){
            int idx = tid + q*512;
            int n = idx >> 3, k8 = (idx & 7) * 8;
            uint4 v = *reinterpret_cast<const uint4*>(Whh + (size_t)n*128 + k0 + k8);
            int ksw = k8 ^ ((n & 7) << 3);
            *reinterpret_cast<uint4*>(&Bs[n*64 + ksw]) = v;
        }
        __syncthreads();
#pragma unroll
        for (int kk = 0; kk < 2; ++kk){
            int ek = kk*32 + (l >> 4) * 8;
            int r = w*16 + (l & 15);
            bf16x8 af = *reinterpret_cast<const bf16x8*>(&As[r*64 + (ek ^ ((r & 7) << 3))]);
#pragma unroll
            for (int n=0;n<24;n++){
                int c = n*16 + (l & 15);
                bf16x8 bf = *reinterpret_cast<const bf16x8*>(&Bs[c*64 + (ek ^ ((c & 7) << 3))]);
                if (n < 16) acc[n]     = __builtin_amdgcn_mfma_f32_16x16x32_bf16(af, bf, acc[n], 0, 0, 0);
                else        accN[n-16] = __builtin_amdgcn_mfma_f32_16x16x32_bf16(af, bf, accN[n-16], 0, 0, 0);
            }
        }
        __syncthreads();
    }
    // ---- epilogue: pointwise GRU, lane-local (r,z,n frags share (row,col) per lane) ----
#pragma unroll
    for (int v=0;v<4;v++){
        int row = row0 + w*16 + (l >> 4)*4 + v;
        int st = (state && row < M) ? clampi(sidx[row],0,nodes-1) : 0;
#pragma unroll
        for (int c=0;c<8;c++){
            int col = c*16 + (l & 15);
            float rr = sigf(acc[c][v]    + bih[col]     + bhh[col]);
            float zz = sigf(acc[c+8][v]  + bih[col+128] + bhh[col+128]);
            float nn = tanhf(acc[c+16][v] + bih[col+256] + rr*(accN[c][v] + bhh[col+256]));
            float hv = H[(size_t)row*128 + col];
            float hn = (1.f-zz)*nn + zz*hv;
            H[(size_t)row*128 + col] = hn;
            if (state) state[(size_t)st*128 + col] = hn;
        }
    }
}

// ---------------- fused GAT attention: per-device alpha+softmax+msgD ----------------
__launch_bounds__(256)
__global__ void k_attn(const unsigned short* __restrict__ SRC, const float* __restrict__ tgt,
                       const float* __restrict__ att, const int* __restrict__ list,
                       const int* __restrict__ offs, const float* __restrict__ batt,
                       float* __restrict__ msgD, float* __restrict__ alphaG, int Dn, int F)
{
    __shared__ float tg[1024];
    __shared__ float alds[128*4];
    __shared__ float accs[4][256];
    int d = blockIdx.x;
    int tid = threadIdx.x;
    int w = tid >> 6, lane = tid & 63;
    for (int u = tid; u < 1024; u += 256) tg[u] = tgt[(size_t)d*1024 + u];
    __syncthreads();
    int beg = offs[d], end = offs[d+1];
    if (beg < 0) beg = 0; if (end > F) end = F; if (end < beg) end = beg;
    int c0 = w*256 + lane*4;
    float t0 = tg[c0], t1 = tg[c0+1], t2 = tg[c0+2], t3 = tg[c0+3];
    float a0 = att[c0], a1 = att[c0+1], a2 = att[c0+2], a3 = att[c0+3];
    float amax = -3.4e38f;
    for (int i=beg;i<end;i++){
        int f = list[i];
        ushort4 sv = *reinterpret_cast<const ushort4*>(SRC + (size_t)f*1024 + c0);
        float e0 = us2f(sv.x)+t0, e1 = us2f(sv.y)+t1, e2 = us2f(sv.z)+t2, e3 = us2f(sv.w)+t3;
        e0 = e0>0.f?e0:0.2f*e0; e1 = e1>0.f?e1:0.2f*e1;
        e2 = e2>0.f?e2:0.2f*e2; e3 = e3>0.f?e3:0.2f*e3;
        float s = e0*a0 + e1*a1 + e2*a2 + e3*a3;
#pragma unroll
        for (int msk=1; msk<64; msk<<=1) s += __shfl_xor(s, msk);
        int li = i - beg;
        if (li < 128){ if (lane == 0) alds[li*4+w] = s; }
        else         { if (lane == 0) alphaG[(size_t)f*4+w] = s; }
        amax = fmaxf(amax, s);
    }
    __syncthreads();
    float wsum = 0.f;
    for (int i=beg;i<end;i++){
        int li = i - beg;
        float a = (li < 128) ? alds[li*4+w] : alphaG[(size_t)list[i]*4+w];
        wsum += expf(a - amax);
    }
    float iws = 1.f/(wsum + 1e-16f);
    float acc[4] = {0,0,0,0};
    for (int i=beg;i<end;i++){
        int f = list[i];
        int li = i - beg;
        float a = (li < 128) ? alds[li*4+w] : alphaG[(size_t)f*4+w];
        float p = expf(a - amax)*iws;
        ushort4 sv = *reinterpret_cast<const ushort4*>(SRC + (size_t)f*1024 + c0);
        acc[0] += p*us2f(sv.x); acc[1] += p*us2f(sv.y);
        acc[2] += p*us2f(sv.z); acc[3] += p*us2f(sv.w);
    }
#pragma unroll
    for (int j=0;j<4;j++) accs[w][lane*4+j] = acc[j];
    __syncthreads();
    if (tid < 256){
        float m = (accs[0][tid]+accs[1][tid]+accs[2][tid]+accs[3][tid])*0.25f + batt[tid];
        msgD[(size_t)d*256 + tid] = m;
    }
}

// ---------------- fused phiC recurrence: MFMA gh, Whh stationary in registers ----------------
__launch_bounds__(512)
__global__ void k_recur(float* __restrict__ h_srv, const float* __restrict__ giF,
                        const unsigned short* __restrict__ Whi,
                        const unsigned short* __restrict__ Wlo,
                        const float* __restrict__ bhh,
                        const int* __restrict__ inv, float* __restrict__ out_f,
                        int S, int L, int F)
{
    __shared__ float hs[16][132];
    __shared__ float ghs[16][388];
    __shared__ int fLoc[16];
    int tid = threadIdx.x;
    int l = tid & 63, w = tid >> 6;
    int lane15 = l & 15, lhi = l >> 4;
    int s0 = blockIdx.x * 16;
    for (int u = tid; u < 2048; u += 512){ int s=u>>7,k=u&127; hs[s][k] = h_srv[(size_t)(s0+s)*128+k]; }
    bf16x8 wHi[3][4], wLo[3][4];
#pragma unroll
    for (int ct=0; ct<3; ++ct){
        int col = w*48 + ct*16 + lane15;
#pragma unroll
        for (int ks=0; ks<4; ++ks){
            size_t off = (size_t)col*128 + ks*32 + lhi*8;
            wHi[ct][ks] = *reinterpret_cast<const bf16x8*>(Whi + off);
            wLo[ct][ks] = *reinterpret_cast<const bf16x8*>(Wlo + off);
        }
    }
    __syncthreads();
    for (int t=0;t<L;++t){
        if (tid < 16) fLoc[tid] = inv[(size_t)(s0+tid)*L + t];
        __syncthreads();
        bf16x8 hHi[4], hLo[4];
#pragma unroll
        for (int ks=0; ks<4; ++ks){
            const float* hp = &hs[lane15][ks*32 + lhi*8];
#pragma unroll
            for (int j=0;j<8;j++){
                float v = hp[j];
                unsigned short hi = f2b(v);
                hHi[ks][j] = (short)hi;
                hLo[ks][j] = (short)f2b(v - us2f(hi));
            }
        }
#pragma unroll
        for (int ct=0; ct<3; ++ct){
            f32x4 acc = (f32x4){0.f,0.f,0.f,0.f};
#pragma unroll
            for (int ks=0; ks<4; ++ks){
                acc = __builtin_amdgcn_mfma_f32_16x16x32_bf16(hHi[ks], wHi[ct][ks], acc, 0,0,0);
                acc = __builtin_amdgcn_mfma_f32_16x16x32_bf16(hLo[ks], wHi[ct][ks], acc, 0,0,0);
                acc = __builtin_amdgcn_mfma_f32_16x16x32_bf16(hHi[ks], wLo[ct][ks], acc, 0,0,0);
            }
            int col = w*48 + ct*16 + lane15;
            float bb = bhh[col];
#pragma unroll
            for (int v=0; v<4; ++v){
                ghs[lhi*4 + v][col] = acc[v] + bb;
            }
        }
        __syncthreads();
        for (int u = tid; u < 2048; u += 512){
            int s=u>>7, k=u&127; int f = fLoc[s];
            if (f >= 0 && f < F){
                const float* gp = giF + (size_t)f*384;
                float r  = sigf(gp[k]     + ghs[s][k]);
                float zz = sigf(gp[128+k] + ghs[s][128+k]);
                float n  = tanhf(gp[256+k] + r*ghs[s][256+k]);
                float hn = (1.f-zz)*n + zz*hs[s][k];
                hs[s][k] = hn;
                out_f[(size_t)f*128+k] = hn;
            }
        }
        __syncthreads();
    }
    for (int u = tid; u < 2048; u += 512){ int s=u>>7,k=u&127; h_srv[(size_t)(s0+s)*128+k] = hs[s][k]; }
}

__global__ void k_count(const int* __restrict__ row, int* __restrict__ counts, int F, int Dn)
{ int f = blockIdx.x*blockDim.x + threadIdx.x; if (f < F) atomicAdd(&counts[clampi(row[f],0,Dn-1)], 1); }

__global__ void k_scan(const int* __restrict__ counts, int* __restrict__ offs, int D)
{
    __shared__ int part[257];
    int tid = threadIdx.x;
    int per = (D + 255) / 256;
    int s = 0;
    for (int i=0;i<per;i++){ int idx = tid*per+i; if (idx < D) s += counts[idx]; }
    part[tid] = s;
    __syncthreads();
    if (tid == 0){
        int acc = 0;
        for (int i=0;i<256;i++){ int v = part[i]; part[i] = acc; acc += v; }
        part[256] = acc;
    }
    __syncthreads();
    int acc = part[tid];
    for (int i=0;i<per;i++){ int idx = tid*per+i; if (idx < D){ offs[idx] = acc; acc += counts[idx]; } }
    if (tid == 0) offs[D] = part[256];
}

__global__ void k_fill(const int* __restrict__ row, const int* __restrict__ offs,
                       int* __restrict__ cursor, int* __restrict__ list, int F, int Dn)
{
    int f = blockIdx.x*blockDim.x + threadIdx.x;
    if (f >= F) return;
    int r = clampi(row[f],0,Dn-1);
    int p = atomicAdd(&cursor[r], 1);
    int pos = offs[r]+p;
    if (pos >= 0 && pos < F) list[pos] = f;
}

__global__ void k_build_inv(const int* __restrict__ fs, const int* __restrict__ fp,
                            int* __restrict__ inv, int F, int L, int S)
{
    int f = blockIdx.x*blockDim.x + threadIdx.x;
    if (f >= F) return;
    inv[clampi(fs[f],0,S-1)*L + clampi(fp[f],0,L-1)] = f;
}

__global__ void k_pool_add(const float* __restrict__ frag, const int* __restrict__ fs,
                           float* __restrict__ pooled, int F, int S)
{
    int t = blockIdx.x*blockDim.x + threadIdx.x;
    int i = t >> 7, j = t & 127;
    if (i >= F) return;
    atomicAdd(&pooled[(size_t)clampi(fs[i],0,S-1)*128 + j], frag[(size_t)i*128 + j]);
}

__global__ void k_pool_div(float* __restrict__ pooled, const int* __restrict__ lengths, int S)
{
    int t = blockIdx.x*blockDim.x + threadIdx.x;
    int i = t >> 7, j = t & 127;
    if (i >= S) return;
    int l = lengths[i]; if (l < 1) l = 1;
    pooled[(size_t)i*128 + j] /= (float)l;
}

__global__ void k_dot_out(const float* __restrict__ H, const float* __restrict__ W3,
                          const float* __restrict__ b3, float* __restrict__ outv, int off)
{
    __shared__ float red[256];
    int s = blockIdx.x, tid = threadIdx.x;
    red[tid] = H[(size_t)s*256 + tid] * W3[tid];
    __syncthreads();
    for (int st=128; st; st>>=1){ if (tid < st) red[tid] += red[tid+st]; __syncthreads(); }
    if (tid == 0) outv[off + s] = red[0] + b3[0];
}

// =====================================================================================
extern "C" void kernel_launch(void* const* d_in, const int* in_sizes, int n_in,
                              void* d_out, int out_size, void* d_ws, size_t ws_size,
                              hipStream_t stream)
{
    (void)n_in; (void)out_size; (void)ws_size;
    const float* realnode = (const float*)d_in[0];
    const float* arr      = (const float*)d_in[1];
    const int* r_exe   = (const int*)d_in[2];
    const int* r_idev  = (const int*)d_in[3];
    const int* r_ifrag = (const int*)d_in[4];
    const int* r_fdn   = (const int*)d_in[5];
    const int* r_fdr   = (const int*)d_in[6];
    const int* r_len   = (const int*)d_in[7];
    const int* r_fsvc  = (const int*)d_in[8];
    const int* r_fpos  = (const int*)d_in[9];
    const float *W_dev=(const float*)d_in[10], *b_dev=(const float*)d_in[11];
    const float *W_frg=(const float*)d_in[12], *b_frg=(const float*)d_in[13];
    const float *W_srv=(const float*)d_in[14], *b_srv=(const float*)d_in[15];
    const float *C_Wih=(const float*)d_in[16], *C_Whh=(const float*)d_in[17], *C_bih=(const float*)d_in[18], *C_bhh=(const float*)d_in[19];
    const float *F_Wih=(const float*)d_in[20], *F_Whh=(const float*)d_in[21], *F_bih=(const float*)d_in[22], *F_bhh=(const float*)d_in[23];
    const float *D_Wih=(const float*)d_in[24], *D_Whh=(const float*)d_in[25], *D_bih=(const float*)d_in[26], *D_bhh=(const float*)d_in[27];
    const float *W_src=(const float*)d_in[28], *b_src=(const float*)d_in[29];
    const float *W_tgt=(const float*)d_in[30], *b_tgt=(const float*)d_in[31];
    const float *att=(const float*)d_in[32], *bias_att=(const float*)d_in[33];
    const float *Wt1=(const float*)d_in[34], *bt1=(const float*)d_in[35], *Wt2=(const float*)d_in[36], *bt2=(const float*)d_in[37], *Wt3=(const float*)d_in[38], *bt3=(const float*)d_in[39];
    const float *Wl1=(const float*)d_in[40], *bl1=(const float*)d_in[41], *Wl2=(const float*)d_in[42], *bl2=(const float*)d_in[43], *Wl3=(const float*)d_in[44], *bl3=(const float*)d_in[45];
    float* outp = (float*)d_out;

    const int S  = in_sizes[7];
    const int Dn = in_sizes[3];
    const int F  = in_sizes[4];
    const int L  = in_sizes[2] / (2*S);
    const int nreal = in_sizes[0]/5;
    const int nodes = nreal + 1;
    const int NIT = 3;

    char* wp = (char*)d_ws;
    auto alloc = [&](size_t nelem)->float*{
        float* p = (float*)wp;
        wp += ((nelem*4 + 255)/256)*256;
        return p;
    };
    float* state  = alloc((size_t)nodes*128);
    float* h_srv  = alloc((size_t)S*128);
    float* out_f  = alloc((size_t)F*128);
    float* fragA  = alloc((size_t)F*128);
    float* devA   = alloc((size_t)Dn*128);
    float* alphaB = alloc((size_t)F*4);
    float* msgDm  = alloc((size_t)Dn*256);
    // union region: giF (F*384 f32, live in phiC) / SRC (F*1024 bf16, live in attention)
    float* UNION  = alloc((size_t)F*512);
    float* giF    = UNION;
    unsigned short* SRC = (unsigned short*)UNION;
    float* TGT    = alloc((size_t)Dn*1024);
    float* Z      = alloc((size_t)Dn*1024);
    float* pooled = alloc((size_t)S*128);
    unsigned short* tCWih   = (unsigned short*)alloc(384*256/2);
    unsigned short* tCWhhHi = (unsigned short*)alloc(384*128/2);
    unsigned short* tCWhhLo = (unsigned short*)alloc(384*128/2);
    unsigned short* tFWih   = (unsigned short*)alloc(384*256/2);
    unsigned short* tFWhh   = (unsigned short*)alloc(384*128/2);
    unsigned short* tDWih   = (unsigned short*)alloc(384*256/2);
    unsigned short* tDWhh   = (unsigned short*)alloc(384*128/2);
    unsigned short* tWtgt   = (unsigned short*)alloc(1024*128/2);
    unsigned short* tWsrc   = (unsigned short*)alloc(1024*256/2);
    int* cExe   = (int*)alloc((size_t)S*2*L);
    int* cIdev  = (int*)alloc((size_t)Dn);
    int* cIfrag = (int*)alloc((size_t)F);
    int* cFdn   = (int*)alloc((size_t)F);
    int* cFdr   = (int*)alloc((size_t)F);
    int* cLen   = (int*)alloc((size_t)S);
    int* cFsvc  = (int*)alloc((size_t)F);
    int* cFpos  = (int*)alloc((size_t)F);
    int* inv    = (int*)alloc((size_t)S*L);
    int* counts = (int*)alloc((size_t)Dn);
    int* offs   = (int*)alloc((size_t)Dn+1);
    int* cursor = (int*)alloc((size_t)Dn);
    int* list   = (int*)alloc((size_t)F);

    const int* det = r_idev;
    auto cvt = [&](const int* src, int* dst, int n){
        k_cvt<<<dim3((n+255)/256),256,0,stream>>>(src, dst, n, det);
    };
    cvt(r_exe,  cExe,  S*2*L);
    cvt(r_idev, cIdev, Dn);
    cvt(r_ifrag,cIfrag,F);
    cvt(r_fdn,  cFdn,  F);
    cvt(r_fdr,  cFdr,  F);
    cvt(r_len,  cLen,  S);
    cvt(r_fsvc, cFsvc, F);
    cvt(r_fpos, cFpos, F);

    k_wt<<<dim3((98304+255)/256),256,0,stream>>>(C_Wih, tCWih, 384, 8, 255, 98304);
    k_wt2<<<dim3((49152+255)/256),256,0,stream>>>(C_Whh, tCWhhHi, tCWhhLo, 384, 7, 127, 49152);
    k_wt<<<dim3((98304+255)/256),256,0,stream>>>(F_Wih, tFWih, 384, 8, 255, 98304);
    k_wt<<<dim3((49152+255)/256),256,0,stream>>>(F_Whh, tFWhh, 384, 7, 127, 49152);
    k_wt<<<dim3((98304+255)/256),256,0,stream>>>(D_Wih, tDWih, 384, 8, 255, 98304);
    k_wt<<<dim3((49152+255)/256),256,0,stream>>>(D_Whh, tDWhh, 384, 7, 127, 49152);
    k_wt<<<dim3((131072+255)/256),256,0,stream>>>(W_tgt, tWtgt, 1024, 7, 127, 131072);
    k_wt<<<dim3((262144+255)/256),256,0,stream>>>(W_src, tWsrc, 1024, 8, 255, 262144);

    hipMemsetAsync(state, 0, (size_t)nodes*128*4, stream);
    hipMemsetAsync(inv, 0xFF, (size_t)S*L*4, stream);
    hipMemsetAsync(counts, 0, (size_t)Dn*4, stream);
    hipMemsetAsync(cursor, 0, (size_t)Dn*4, stream);

    k_proj5<<<dim3((Dn*128+255)/256),256,0,stream>>>(realnode, W_dev, b_dev, cIdev, cIdev, state, devA, Dn, nreal, nodes);
    k_proj5<<<dim3(((size_t)F*128+255)/256),256,0,stream>>>(realnode, W_frg, b_frg, cIfrag, cIfrag, state, fragA, F, nreal, nodes);
    k_proj5<<<dim3((S*128+255)/256),256,0,stream>>>(arr, W_srv, b_srv, nullptr, nullptr, h_srv, nullptr, S, S, nodes);
    k_build_inv<<<dim3((F+255)/256),256,0,stream>>>(cFsvc, cFpos, inv, F, L, S);
    k_count<<<dim3((F+255)/256),256,0,stream>>>(cFdr, counts, F, Dn);
    k_scan<<<1,256,0,stream>>>(counts, offs, Dn);
    k_fill<<<dim3((F+255)/256),256,0,stream>>>(cFdr, offs, cursor, list, F, Dn);

    const int nrF = F/128, nrD = Dn/128;
    for (int it=0; it<NIT; ++it){
        // phiC: batched gi (MFMA) + fused MFMA recurrence
        mm_bf<<<dim3(3*nrF),256,0,stream>>>(state, state, cIfrag, cFdn, 0,
            tCWih, C_bih, giF, F, 384, 256, 0, 1.f, nrF);
        k_recur<<<dim3(S/16),512,0,stream>>>(h_srv, giF, tCWhhHi, tCWhhLo, C_bhh, inv, out_f, S, L, F);
        // attention: tgt GEMM, SRC materialization (bf16, b_src folded), fused per-device GAT
        mm_bf<<<dim3(8*nrD),256,0,stream>>>(devA, nullptr, nullptr, nullptr, 128,
            tWtgt, b_tgt, TGT, Dn, 1024, 128, 0, 1.f, nrD);
        mm_bf<<<dim3(8*nrF),256,0,stream>>>(out_f, fragA, nullptr, nullptr, 0,
            tWsrc, b_src, SRC, F, 1024, 256, 2, 1.f, nrF);
        k_attn<<<dim3(Dn),256,0,stream>>>(SRC, TGT, att, list, offs, bias_att, msgDm, alphaB, Dn, F);
        // F-GRU fully fused (in-place on fragA, write-through to state)
        k_grufuse<<<dim3(nrF),512,0,stream>>>(out_f, state, nullptr, cFdn, 0,
            tFWih, tFWhh, F_bih, F_bhh, fragA, state, cIfrag, F, nodes);
        // D-GRU fully fused (in-place on devA, write-through to state)
        k_grufuse<<<dim3(nrD),512,0,stream>>>(msgDm, nullptr, nullptr, nullptr, 256,
            tDWih, tDWhh, D_bih, D_bhh, devA, state, cIdev, Dn, nodes);
    }

    // readout
    hipMemsetAsync(pooled, 0, (size_t)S*128*4, stream);
    k_pool_add<<<dim3(((size_t)F*128+255)/256),256,0,stream>>>(fragA, cFsvc, pooled, F, S);
    k_pool_div<<<dim3((S*128+255)/256),256,0,stream>>>(pooled, cLen, S);
    k_mm<<<dim3(256/128, S/128),256,0,stream>>>(pooled, 128, Wl1, 256, bl1, TGT, S, 256, 128, 1, 1.f, 0);
    k_mm<<<dim3(256/128, S/128),256,0,stream>>>(TGT, 256, Wl2, 256, bl2, Z, S, 256, 256, 1, 1.f, 0);
    k_dot_out<<<dim3(S),256,0,stream>>>(Z, Wl3, bl3, outp, 0);
    k_mm<<<dim3(256/128, S/128),256,0,stream>>>(h_srv, 128, Wt1, 256, bt1, TGT, S, 256, 128, 1, 1.f, 0);
    k_mm<<<dim3(256/128, S/128),256,0,stream>>>(TGT, 256, Wt2, 256, bt2, Z, S, 256, 256, 1, 1.f, 0);
    k_dot_out<<<dim3(S),256,0,stream>>>(Z, Wt3, bt3, outp, S);
}

// Round 11
// 1007.192 us; speedup vs baseline: 1.5679x; 1.0330x over previous
//
#include <hip/hip_runtime.h>
#include <hip/hip_bf16.h>

typedef __attribute__((ext_vector_type(8))) short bf16x8;
typedef __attribute__((ext_vector_type(4))) float f32x4;

__device__ __forceinline__ float sigf(float x){ return 1.0f/(1.0f+expf(-x)); }
__device__ __forceinline__ int clampi(int v, int lo, int hi){ return v<lo?lo:(v>hi?hi:v); }
__device__ __forceinline__ unsigned short f2b(float f){
    __hip_bfloat16 h = __float2bfloat16(f);
    return *reinterpret_cast<unsigned short*>(&h);
}
__device__ __forceinline__ float us2f(unsigned short u){ return __uint_as_float(((unsigned)u)<<16); }

__device__ __forceinline__ void gload16(const void* g, void* l){
    __builtin_amdgcn_global_load_lds((const __attribute__((address_space(1))) void*)g,
                                     (__attribute__((address_space(3))) void*)l, 16, 0, 0);
}

// ---- int64/int32 tolerant index conversion ----
__global__ void k_cvt(const int* __restrict__ src, int* __restrict__ dst, int n,
                      const int* __restrict__ det)
{
    int i = blockIdx.x*blockDim.x + threadIdx.x;
    if (i >= n) return;
    int stride = (det[1] == 0) ? 2 : 1;
    dst[i] = src[(size_t)i*stride];
}

// ---- weight transpose+convert: Wt[n][k] (bf16) <- W[k][n] (f32) ----
__global__ void k_wt(const float* __restrict__ W, unsigned short* __restrict__ Wt,
                     int N, int kshift, int kmask, int total)
{
    int idx = blockIdx.x*blockDim.x + threadIdx.x;
    if (idx >= total) return;
    int n = idx >> kshift, k = idx & kmask;
    Wt[idx] = f2b(W[(size_t)k*N + n]);
}

// ---- split transpose+convert: Whi/Wlo[n][k] <- W[k][n], lo = residual ----
__global__ void k_wt2(const float* __restrict__ W, unsigned short* __restrict__ Whi,
                      unsigned short* __restrict__ Wlo, int N, int kshift, int kmask, int total)
{
    int idx = blockIdx.x*blockDim.x + threadIdx.x;
    if (idx >= total) return;
    int n = idx >> kshift, k = idx & kmask;
    float v = W[(size_t)k*N + n];
    unsigned short hi = f2b(v);
    Whi[idx] = hi;
    Wlo[idx] = f2b(v - us2f(hi));
}

// ---------------- init projections (+ bf16 mirrors) ----------------
__global__ void k_proj5(const float* __restrict__ X, const float* __restrict__ W,
                        const float* __restrict__ bias,
                        const int* __restrict__ gidx, const int* __restrict__ sidx,
                        float* __restrict__ out, unsigned short* __restrict__ outBf,
                        float* __restrict__ out2, unsigned short* __restrict__ out2Bf,
                        int M, int nrows, int nodes)
{
    int t = blockIdx.x*blockDim.x + threadIdx.x;
    int i = t >> 7, j = t & 127;
    if (i >= M) return;
    int src = gidx ? clampi(gidx[i]-1, 0, nrows-1) : i;
    const float* xp = X + (size_t)src*5;
    float acc = bias[j];
#pragma unroll
    for (int k=0;k<5;k++) acc += xp[k] * W[k*128+j];
    int dr = sidx ? clampi(sidx[i], 0, nodes-1) : i;
    out[(size_t)dr*128 + j] = acc;
    if (outBf) outBf[(size_t)dr*128 + j] = f2b(acc);
    if (out2){ out2[(size_t)i*128 + j] = acc; out2Bf[(size_t)i*128 + j] = f2b(acc); }
}

// ---------------- f32 tiled GEMM (readout heads only) ----------------
__launch_bounds__(256)
__global__ void k_mm(const float* __restrict__ A0, int lda,
                     const float* __restrict__ B, int ldb,
                     const float* __restrict__ bias, float* __restrict__ C,
                     int M, int N, int K, int relu, float scale, int accum)
{
    __shared__ float As[16][132];
    __shared__ float Bs[16][132];
    int tid = threadIdx.x;
    int tx = tid & 15, ty = tid >> 4;
    int row0 = blockIdx.y * 128, col0 = blockIdx.x * 128;
    float acc[8][8] = {};
    for (int k0 = 0; k0 < K; k0 += 16){
#pragma unroll
        for (int q = 0; q < 2; ++q){
            int idx = tid + q*256;
            int r = idx >> 2, k4 = (idx & 3) * 4;
            const float* src = A0 + (size_t)(row0+r)*lda + k0 + k4;
            float4 v = *reinterpret_cast<const float4*>(src);
            As[k4+0][r]=v.x; As[k4+1][r]=v.y; As[k4+2][r]=v.z; As[k4+3][r]=v.w;
        }
#pragma unroll
        for (int q = 0; q < 2; ++q){
            int idx = tid + q*256;
            int kb = idx >> 5, n4 = (idx & 31) * 4;
            float4 v = *reinterpret_cast<const float4*>(B + (size_t)(k0+kb)*ldb + col0 + n4);
            *reinterpret_cast<float4*>(&Bs[kb][n4]) = v;
        }
        __syncthreads();
#pragma unroll
        for (int k = 0; k < 16; ++k){
            float a[8], b[8];
            *(float4*)&a[0] = *(const float4*)&As[k][ty*8];
            *(float4*)&a[4] = *(const float4*)&As[k][ty*8+4];
            *(float4*)&b[0] = *(const float4*)&Bs[k][tx*8];
            *(float4*)&b[4] = *(const float4*)&Bs[k][tx*8+4];
#pragma unroll
            for (int i=0;i<8;i++)
#pragma unroll
                for (int j=0;j<8;j++) acc[i][j] += a[i]*b[j];
        }
        __syncthreads();
    }
    float bb[8];
#pragma unroll
    for (int j=0;j<8;j++) bb[j] = bias ? bias[col0+tx*8+j] : 0.f;
#pragma unroll
    for (int i=0;i<8;i++){
        float* cp = C + (size_t)(row0+ty*8+i)*N + col0 + tx*8;
#pragma unroll
        for (int jq=0;jq<2;jq++){
            float4 prev = accum ? *(const float4*)(cp+jq*4) : make_float4(0,0,0,0);
            float o[4];
#pragma unroll
            for (int c=0;c<4;c++){
                float u = acc[i][jq*4+c] + bb[jq*4+c];
                if (relu) u = fmaxf(u,0.f);
                o[c] = (&prev.x)[c] + scale*u;
            }
            *(float4*)(cp+jq*4) = make_float4(o[0],o[1],o[2],o[3]);
        }
    }
}

// ---------------- pipelined bf16 MFMA GEMM (global_load_lds + double buffer) ----------------
// A is bf16, row stride 128. Two-half mode: k<128 -> A0[i0(r)], k>=128 -> A1[i1(r)].
// Swizzle baked into per-lane global address; LDS written linearly by gload_lds.
// epi==0: f32 C.  epi==2: bf16 C.  1D grid, XCD order: row = bid % nrow.
__launch_bounds__(256)
__global__ void mm2(const unsigned short* __restrict__ A0, const unsigned short* __restrict__ A1,
                    const int* __restrict__ i0, const int* __restrict__ i1,
                    const unsigned short* __restrict__ Wt,
                    const float* __restrict__ bias, void* __restrict__ C,
                    int M, int N, int K, int epi, float scale, int nrow)
{
    __shared__ alignas(16) unsigned short As[2][128*64];
    __shared__ alignas(16) unsigned short Bs[2][128*64];
    int tid = threadIdx.x;
    int l = tid & 63, w = tid >> 6;
    int wr = w >> 1, wc = w & 1;
    int bid = blockIdx.x;
    int row0 = (bid % nrow) * 128, col0 = (bid / nrow) * 128;
    int nK = K >> 6;

    f32x4 acc[4][4];
#pragma unroll
    for (int m=0;m<4;m++)
#pragma unroll
        for (int n=0;n<4;n++) acc[m][n] = (f32x4){0.f,0.f,0.f,0.f};

    auto stage = [&](int buf, int k0){
#pragma unroll
        for (int q=0;q<4;q++){
            int slot = q*256 + w*64 + l;
            int r = slot >> 3, c8 = slot & 7;
            int g8 = c8 ^ (r & 7);
            int row; const unsigned short* base; int kl;
            if (k0 < 128){ row = i0 ? i0[row0+r] : (row0+r); base = A0; kl = k0; }
            else         { row = i1 ? i1[row0+r] : (row0+r); base = A1; kl = k0-128; }
            const char* g = (const char*)(base + (size_t)row*128 + kl) + g8*16;
            gload16(g, (void*)&As[buf][(size_t)(q*256 + w*64)*8]);
        }
#pragma unroll
        for (int q=0;q<4;q++){
            int slot = q*256 + w*64 + l;
            int n = slot >> 3, kc = slot & 7;
            int g8 = kc ^ (n & 7);
            const char* g = (const char*)(Wt + (size_t)(col0+n)*K + k0) + g8*16;
            gload16(g, (void*)&Bs[buf][(size_t)(q*256 + w*64)*8]);
        }
    };

    stage(0, 0);
    __syncthreads();
    for (int ks=0; ks<nK; ++ks){
        int cur = ks & 1;
        if (ks+1 < nK) stage(cur^1, (ks+1)*64);
#pragma unroll
        for (int kk = 0; kk < 2; ++kk){
            int ek = kk*32 + (l >> 4) * 8;
            bf16x8 af[4], bf[4];
#pragma unroll
            for (int m=0;m<4;m++){
                int r = wr*64 + m*16 + (l & 15);
                af[m] = *reinterpret_cast<const bf16x8*>(&As[cur][r*64 + (ek ^ ((r & 7) << 3))]);
            }
#pragma unroll
            for (int n=0;n<4;n++){
                int c = wc*64 + n*16 + (l & 15);
                bf[n] = *reinterpret_cast<const bf16x8*>(&Bs[cur][c*64 + (ek ^ ((c & 7) << 3))]);
            }
#pragma unroll
            for (int m=0;m<4;m++)
#pragma unroll
                for (int n=0;n<4;n++)
                    acc[m][n] = __builtin_amdgcn_mfma_f32_16x16x32_bf16(af[m], bf[n], acc[m][n], 0, 0, 0);
        }
        __syncthreads();
    }

#pragma unroll
    for (int m=0;m<4;m++){
#pragma unroll
        for (int v=0;v<4;v++){
            int row = row0 + wr*64 + m*16 + (l >> 4)*4 + v;
            size_t base = (size_t)row*N + col0 + wc*64 + (l & 15);
#pragma unroll
            for (int n=0;n<4;n++){
                int col = col0 + wc*64 + n*16 + (l & 15);
                float u = scale*acc[m][n][v] + (bias ? bias[col] : 0.f);
                if (epi == 0) ((float*)C)[base + n*16] = u;
                else          ((unsigned short*)C)[base + n*16] = f2b(u);
            }
        }
    }
}

// ---------------- fully fused GRU (unchanged staging; adds bf16 mirror writes) ----------------
__launch_bounds__(512)
__global__ void k_grufuse(const float* __restrict__ A0, const float* __restrict__ A1,
                          const int* __restrict__ i0, const int* __restrict__ i1, int lda,
                          const unsigned short* __restrict__ Wih,
                          const unsigned short* __restrict__ Whh,
                          const float* __restrict__ bih, const float* __restrict__ bhh,
                          float* __restrict__ H, unsigned short* __restrict__ Hbf,
                          float* __restrict__ state, unsigned short* __restrict__ stateBf,
                          const int* __restrict__ sidx, int M, int nodes)
{
    __shared__ alignas(16) unsigned short As[128*64];
    __shared__ alignas(16) unsigned short Bs[384*64];
    int tid = threadIdx.x;
    int l = tid & 63, w = tid >> 6;
    int row0 = blockIdx.x * 128;
    f32x4 acc[24], accN[8];
#pragma unroll
    for (int n=0;n<24;n++) acc[n] = (f32x4){0.f,0.f,0.f,0.f};
#pragma unroll
    for (int n=0;n<8;n++) accN[n] = (f32x4){0.f,0.f,0.f,0.f};

    for (int k0 = 0; k0 < 256; k0 += 64){
#pragma unroll
        for (int q = 0; q < 4; ++q){
            int idx = tid + q*512;
            int r = idx >> 4, c4 = (idx & 15) * 4;
            int kk = k0 + c4;
            const float* src;
            if (A1){
                if (kk < 128){ int ri = i0 ? i0[row0+r] : (row0+r); src = A0 + (size_t)ri*128 + kk; }
                else         { int ri = i1 ? i1[row0+r] : (row0+r); src = A1 + (size_t)ri*128 + (kk-128); }
            } else {
                src = A0 + (size_t)(row0+r)*lda + kk;
            }
            float4 v = *reinterpret_cast<const float4*>(src);
            ushort4 o; o.x=f2b(v.x); o.y=f2b(v.y); o.z=f2b(v.z); o.w=f2b(v.w);
            int csw = c4 ^ ((r & 7) << 3);
            *reinterpret_cast<ushort4*>(&As[r*64 + csw]) = o;
        }
#pragma unroll
        for (int q = 0; q < 6; ++q){
            int idx = tid + q*512;
            int n = idx >> 3, k8 = (idx & 7) * 8;
            uint4 v = *reinterpret_cast<const uint4*>(Wih + (size_t)n*256 + k0 + k8);
            int ksw = k8 ^ ((n & 7) << 3);
            *reinterpret_cast<uint4*>(&Bs[n*64 + ksw]) = v;
        }
        __syncthreads();
#pragma unroll
        for (int kk = 0; kk < 2; ++kk){
            int ek = kk*32 + (l >> 4) * 8;
            int r = w*16 + (l & 15);
            bf16x8 af = *reinterpret_cast<const bf16x8*>(&As[r*64 + (ek ^ ((r & 7) << 3))]);
#pragma unroll
            for (int n=0;n<24;n++){
                int c = n*16 + (l & 15);
                bf16x8 bf = *reinterpret_cast<const bf16x8*>(&Bs[c*64 + (ek ^ ((c & 7) << 3))]);
                acc[n] = __builtin_amdgcn_mfma_f32_16x16x32_bf16(af, bf, acc[n], 0, 0, 0);
            }
        }
        __syncthreads();
    }
    for (int k0 = 0; k0 < 128; k0 += 64){
#pragma unroll
        for (int q = 0; q < 4; ++q){
            int idx = tid + q*512;
            int r = idx >> 4, c4 = (idx & 15) * 4;
            const float* src = H + (size_t)(row0+r)*128 + k0 + c4;
            float4 v = *reinterpret_cast<const float4*>(src);
            ushort4 o; o.x=f2b(v.x); o.y=f2b(v.y); o.z=f2b(v.z); o.w=f2b(v.w);
            int csw = c4 ^ ((r & 7) << 3);
            *reinterpret_cast<ushort4*>(&As[r*64 + csw]) = o;
        }
#pragma unroll
        for (int q = 0; q < 6; ++q){
            int idx = tid + q*512;
            int n = idx >> 3, k8 = (idx & 7) * 8;
            uint4 v = *reinterpret_cast<const uint4*>(Whh + (size_t)n*128 + k0 + k8);
            int ksw = k8 ^ ((n & 7) << 3);
            *reinterpret_cast<uint4*>(&Bs[n*64 + ksw]) = v;
        }
        __syncthreads();
#pragma unroll
        for (int kk = 0; kk < 2; ++kk){
            int ek = kk*32 + (l >> 4) * 8;
            int r = w*16 + (l & 15);
            bf16x8 af = *reinterpret_cast<const bf16x8*>(&As[r*64 + (ek ^ ((r & 7) << 3))]);
#pragma unroll
            for (int n=0;n<24;n++){
                int c = n*16 + (l & 15);
                bf16x8 bf = *reinterpret_cast<const bf16x8*>(&Bs[c*64 + (ek ^ ((c & 7) << 3))]);
                if (n < 16) acc[n]     = __builtin_amdgcn_mfma_f32_16x16x32_bf16(af, bf, acc[n], 0, 0, 0);
                else        accN[n-16] = __builtin_amdgcn_mfma_f32_16x16x32_bf16(af, bf, accN[n-16], 0, 0, 0);
            }
        }
        __syncthreads();
    }
#pragma unroll
    for (int v=0;v<4;v++){
        int row = row0 + w*16 + (l >> 4)*4 + v;
        int st = (state && row < M) ? clampi(sidx[row],0,nodes-1) : 0;
#pragma unroll
        for (int c=0;c<8;c++){
            int col = c*16 + (l & 15);
            float rr = sigf(acc[c][v]    + bih[col]     + bhh[col]);
            float zz = sigf(acc[c+8][v]  + bih[col+128] + bhh[col+128]);
            float nn = tanhf(acc[c+16][v] + bih[col+256] + rr*(accN[c][v] + bhh[col+256]));
            float hv = H[(size_t)row*128 + col];
            float hn = (1.f-zz)*nn + zz*hv;
            unsigned short hb = f2b(hn);
            H[(size_t)row*128 + col] = hn;
            Hbf[(size_t)row*128 + col] = hb;
            if (state){
                state[(size_t)st*128 + col] = hn;
                stateBf[(size_t)st*128 + col] = hb;
            }
        }
    }
}

// ---------------- fused GAT attention ----------------
__launch_bounds__(256)
__global__ void k_attn(const unsigned short* __restrict__ SRC, const float* __restrict__ tgt,
                       const float* __restrict__ att, const int* __restrict__ list,
                       const int* __restrict__ offs, const float* __restrict__ batt,
                       float* __restrict__ msgD, float* __restrict__ alphaG, int Dn, int F)
{
    __shared__ float tg[1024];
    __shared__ float alds[128*4];
    __shared__ float accs[4][256];
    int d = blockIdx.x;
    int tid = threadIdx.x;
    int w = tid >> 6, lane = tid & 63;
    for (int u = tid; u < 1024; u += 256) tg[u] = tgt[(size_t)d*1024 + u];
    __syncthreads();
    int beg = offs[d], end = offs[d+1];
    if (beg < 0) beg = 0; if (end > F) end = F; if (end < beg) end = beg;
    int c0 = w*256 + lane*4;
    float t0 = tg[c0], t1 = tg[c0+1], t2 = tg[c0+2], t3 = tg[c0+3];
    float a0 = att[c0], a1 = att[c0+1], a2 = att[c0+2], a3 = att[c0+3];
    float amax = -3.4e38f;
    for (int i=beg;i<end;i++){
        int f = list[i];
        ushort4 sv = *reinterpret_cast<const ushort4*>(SRC + (size_t)f*1024 + c0);
        float e0 = us2f(sv.x)+t0, e1 = us2f(sv.y)+t1, e2 = us2f(sv.z)+t2, e3 = us2f(sv.w)+t3;
        e0 = e0>0.f?e0:0.2f*e0; e1 = e1>0.f?e1:0.2f*e1;
        e2 = e2>0.f?e2:0.2f*e2; e3 = e3>0.f?e3:0.2f*e3;
        float s = e0*a0 + e1*a1 + e2*a2 + e3*a3;
#pragma unroll
        for (int msk=1; msk<64; msk<<=1) s += __shfl_xor(s, msk);
        int li = i - beg;
        if (li < 128){ if (lane == 0) alds[li*4+w] = s; }
        else         { if (lane == 0) alphaG[(size_t)f*4+w] = s; }
        amax = fmaxf(amax, s);
    }
    __syncthreads();
    float wsum = 0.f;
    for (int i=beg;i<end;i++){
        int li = i - beg;
        float a = (li < 128) ? alds[li*4+w] : alphaG[(size_t)list[i]*4+w];
        wsum += expf(a - amax);
    }
    float iws = 1.f/(wsum + 1e-16f);
    float acc[4] = {0,0,0,0};
    for (int i=beg;i<end;i++){
        int f = list[i];
        int li = i - beg;
        float a = (li < 128) ? alds[li*4+w] : alphaG[(size_t)f*4+w];
        float p = expf(a - amax)*iws;
        ushort4 sv = *reinterpret_cast<const ushort4*>(SRC + (size_t)f*1024 + c0);
        acc[0] += p*us2f(sv.x); acc[1] += p*us2f(sv.y);
        acc[2] += p*us2f(sv.z); acc[3] += p*us2f(sv.w);
    }
#pragma unroll
    for (int j=0;j<4;j++) accs[w][lane*4+j] = acc[j];
    __syncthreads();
    if (tid < 256){
        float m = (accs[0][tid]+accs[1][tid]+accs[2][tid]+accs[3][tid])*0.25f + batt[tid];
        msgD[(size_t)d*256 + tid] = m;
    }
}

// ---------------- fused phiC recurrence ----------------
__launch_bounds__(512)
__global__ void k_recur(float* __restrict__ h_srv, const float* __restrict__ giF,
                        const unsigned short* __restrict__ Whi,
                        const unsigned short* __restrict__ Wlo,
                        const float* __restrict__ bhh,
                        const int* __restrict__ inv, float* __restrict__ out_f,
                        unsigned short* __restrict__ out_f_bf,
                        int S, int L, int F)
{
    __shared__ float hs[16][132];
    __shared__ float ghs[16][388];
    __shared__ int fLoc[16];
    int tid = threadIdx.x;
    int l = tid & 63, w = tid >> 6;
    int lane15 = l & 15, lhi = l >> 4;
    int s0 = blockIdx.x * 16;
    for (int u = tid; u < 2048; u += 512){ int s=u>>7,k=u&127; hs[s][k] = h_srv[(size_t)(s0+s)*128+k]; }
    bf16x8 wHi[3][4], wLo[3][4];
#pragma unroll
    for (int ct=0; ct<3; ++ct){
        int col = w*48 + ct*16 + lane15;
#pragma unroll
        for (int ks=0; ks<4; ++ks){
            size_t off = (size_t)col*128 + ks*32 + lhi*8;
            wHi[ct][ks] = *reinterpret_cast<const bf16x8*>(Whi + off);
            wLo[ct][ks] = *reinterpret_cast<const bf16x8*>(Wlo + off);
        }
    }
    __syncthreads();
    for (int t=0;t<L;++t){
        if (tid < 16) fLoc[tid] = inv[(size_t)(s0+tid)*L + t];
        __syncthreads();
        bf16x8 hHi[4], hLo[4];
#pragma unroll
        for (int ks=0; ks<4; ++ks){
            const float* hp = &hs[lane15][ks*32 + lhi*8];
#pragma unroll
            for (int j=0;j<8;j++){
                float v = hp[j];
                unsigned short hi = f2b(v);
                hHi[ks][j] = (short)hi;
                hLo[ks][j] = (short)f2b(v - us2f(hi));
            }
        }
#pragma unroll
        for (int ct=0; ct<3; ++ct){
            f32x4 acc = (f32x4){0.f,0.f,0.f,0.f};
#pragma unroll
            for (int ks=0; ks<4; ++ks){
                acc = __builtin_amdgcn_mfma_f32_16x16x32_bf16(hHi[ks], wHi[ct][ks], acc, 0,0,0);
                acc = __builtin_amdgcn_mfma_f32_16x16x32_bf16(hLo[ks], wHi[ct][ks], acc, 0,0,0);
                acc = __builtin_amdgcn_mfma_f32_16x16x32_bf16(hHi[ks], wLo[ct][ks], acc, 0,0,0);
            }
            int col = w*48 + ct*16 + lane15;
            float bb = bhh[col];
#pragma unroll
            for (int v=0; v<4; ++v){
                ghs[lhi*4 + v][col] = acc[v] + bb;
            }
        }
        __syncthreads();
        for (int u = tid; u < 2048; u += 512){
            int s=u>>7, k=u&127; int f = fLoc[s];
            if (f >= 0 && f < F){
                const float* gp = giF + (size_t)f*384;
                float r  = sigf(gp[k]     + ghs[s][k]);
                float zz = sigf(gp[128+k] + ghs[s][128+k]);
                float n  = tanhf(gp[256+k] + r*ghs[s][256+k]);
                float hn = (1.f-zz)*n + zz*hs[s][k];
                hs[s][k] = hn;
                out_f[(size_t)f*128+k] = hn;
                out_f_bf[(size_t)f*128+k] = f2b(hn);
            }
        }
        __syncthreads();
    }
    for (int u = tid; u < 2048; u += 512){ int s=u>>7,k=u&127; h_srv[(size_t)(s0+s)*128+k] = hs[s][k]; }
}

__global__ void k_count(const int* __restrict__ row, int* __restrict__ counts, int F, int Dn)
{ int f = blockIdx.x*blockDim.x + threadIdx.x; if (f < F) atomicAdd(&counts[clampi(row[f],0,Dn-1)], 1); }

__global__ void k_scan(const int* __restrict__ counts, int* __restrict__ offs, int D)
{
    __shared__ int part[257];
    int tid = threadIdx.x;
    int per = (D + 255) / 256;
    int s = 0;
    for (int i=0;i<per;i++){ int idx = tid*per+i; if (idx < D) s += counts[idx]; }
    part[tid] = s;
    __syncthreads();
    if (tid == 0){
        int acc = 0;
        for (int i=0;i<256;i++){ int v = part[i]; part[i] = acc; acc += v; }
        part[256] = acc;
    }
    __syncthreads();
    int acc = part[tid];
    for (int i=0;i<per;i++){ int idx = tid*per+i; if (idx < D){ offs[idx] = acc; acc += counts[idx]; } }
    if (tid == 0) offs[D] = part[256];
}

__global__ void k_fill(const int* __restrict__ row, const int* __restrict__ offs,
                       int* __restrict__ cursor, int* __restrict__ list, int F, int Dn)
{
    int f = blockIdx.x*blockDim.x + threadIdx.x;
    if (f >= F) return;
    int r = clampi(row[f],0,Dn-1);
    int p = atomicAdd(&cursor[r], 1);
    int pos = offs[r]+p;
    if (pos >= 0 && pos < F) list[pos] = f;
}

__global__ void k_build_inv(const int* __restrict__ fs, const int* __restrict__ fp,
                            int* __restrict__ inv, int F, int L, int S)
{
    int f = blockIdx.x*blockDim.x + threadIdx.x;
    if (f >= F) return;
    inv[clampi(fs[f],0,S-1)*L + clampi(fp[f],0,L-1)] = f;
}

__global__ void k_pool_add(const float* __restrict__ frag, const int* __restrict__ fs,
                           float* __restrict__ pooled, int F, int S)
{
    int t = blockIdx.x*blockDim.x + threadIdx.x;
    int i = t >> 7, j = t & 127;
    if (i >= F) return;
    atomicAdd(&pooled[(size_t)clampi(fs[i],0,S-1)*128 + j], frag[(size_t)i*128 + j]);
}

__global__ void k_pool_div(float* __restrict__ pooled, const int* __restrict__ lengths, int S)
{
    int t = blockIdx.x*blockDim.x + threadIdx.x;
    int i = t >> 7, j = t & 127;
    if (i >= S) return;
    int l = lengths[i]; if (l < 1) l = 1;
    pooled[(size_t)i*128 + j] /= (float)l;
}

__global__ void k_dot_out(const float* __restrict__ H, const float* __restrict__ W3,
                          const float* __restrict__ b3, float* __restrict__ outv, int off)
{
    __shared__ float red[256];
    int s = blockIdx.x, tid = threadIdx.x;
    red[tid] = H[(size_t)s*256 + tid] * W3[tid];
    __syncthreads();
    for (int st=128; st; st>>=1){ if (tid < st) red[tid] += red[tid+st]; __syncthreads(); }
    if (tid == 0) outv[off + s] = red[0] + b3[0];
}

// =====================================================================================
extern "C" void kernel_launch(void* const* d_in, const int* in_sizes, int n_in,
                              void* d_out, int out_size, void* d_ws, size_t ws_size,
                              hipStream_t stream)
{
    (void)n_in; (void)out_size; (void)ws_size;
    const float* realnode = (const float*)d_in[0];
    const float* arr      = (const float*)d_in[1];
    const int* r_exe   = (const int*)d_in[2];
    const int* r_idev  = (const int*)d_in[3];
    const int* r_ifrag = (const int*)d_in[4];
    const int* r_fdn   = (const int*)d_in[5];
    const int* r_fdr   = (const int*)d_in[6];
    const int* r_len   = (const int*)d_in[7];
    const int* r_fsvc  = (const int*)d_in[8];
    const int* r_fpos  = (const int*)d_in[9];
    const float *W_dev=(const float*)d_in[10], *b_dev=(const float*)d_in[11];
    const float *W_frg=(const float*)d_in[12], *b_frg=(const float*)d_in[13];
    const float *W_srv=(const float*)d_in[14], *b_srv=(const float*)d_in[15];
    const float *C_Wih=(const float*)d_in[16], *C_Whh=(const float*)d_in[17], *C_bih=(const float*)d_in[18], *C_bhh=(const float*)d_in[19];
    const float *F_Wih=(const float*)d_in[20], *F_Whh=(const float*)d_in[21], *F_bih=(const float*)d_in[22], *F_bhh=(const float*)d_in[23];
    const float *D_Wih=(const float*)d_in[24], *D_Whh=(const float*)d_in[25], *D_bih=(const float*)d_in[26], *D_bhh=(const float*)d_in[27];
    const float *W_src=(const float*)d_in[28], *b_src=(const float*)d_in[29];
    const float *W_tgt=(const float*)d_in[30], *b_tgt=(const float*)d_in[31];
    const float *att=(const float*)d_in[32], *bias_att=(const float*)d_in[33];
    const float *Wt1=(const float*)d_in[34], *bt1=(const float*)d_in[35], *Wt2=(const float*)d_in[36], *bt2=(const float*)d_in[37], *Wt3=(const float*)d_in[38], *bt3=(const float*)d_in[39];
    const float *Wl1=(const float*)d_in[40], *bl1=(const float*)d_in[41], *Wl2=(const float*)d_in[42], *bl2=(const float*)d_in[43], *Wl3=(const float*)d_in[44], *bl3=(const float*)d_in[45];
    float* outp = (float*)d_out;

    const int S  = in_sizes[7];
    const int Dn = in_sizes[3];
    const int F  = in_sizes[4];
    const int L  = in_sizes[2] / (2*S);
    const int nreal = in_sizes[0]/5;
    const int nodes = nreal + 1;
    const int NIT = 3;

    char* wp = (char*)d_ws;
    auto alloc = [&](size_t nelem)->float*{
        float* p = (float*)wp;
        wp += ((nelem*4 + 255)/256)*256;
        return p;
    };
    float* state  = alloc((size_t)nodes*128);
    float* h_srv  = alloc((size_t)S*128);
    float* out_f  = alloc((size_t)F*128);
    float* fragA  = alloc((size_t)F*128);
    float* devA   = alloc((size_t)Dn*128);
    float* alphaB = alloc((size_t)F*4);
    float* msgDm  = alloc((size_t)Dn*256);
    float* UNION  = alloc((size_t)F*512);
    float* giF    = UNION;
    unsigned short* SRC = (unsigned short*)UNION;
    float* TGT    = alloc((size_t)Dn*1024);
    float* Z      = alloc((size_t)Dn*1024);
    float* pooled = alloc((size_t)S*128);
    // bf16 activation mirrors
    unsigned short* state_bf = (unsigned short*)alloc((size_t)nodes*64);
    unsigned short* out_f_bf = (unsigned short*)alloc((size_t)F*64);
    unsigned short* fragA_bf = (unsigned short*)alloc((size_t)F*64);
    unsigned short* devA_bf  = (unsigned short*)alloc((size_t)Dn*64);
    unsigned short* tCWih   = (unsigned short*)alloc(384*256/2);
    unsigned short* tCWhhHi = (unsigned short*)alloc(384*128/2);
    unsigned short* tCWhhLo = (unsigned short*)alloc(384*128/2);
    unsigned short* tFWih   = (unsigned short*)alloc(384*256/2);
    unsigned short* tFWhh   = (unsigned short*)alloc(384*128/2);
    unsigned short* tDWih   = (unsigned short*)alloc(384*256/2);
    unsigned short* tDWhh   = (unsigned short*)alloc(384*128/2);
    unsigned short* tWtgt   = (unsigned short*)alloc(1024*128/2);
    unsigned short* tWsrc   = (unsigned short*)alloc(1024*256/2);
    int* cExe   = (int*)alloc((size_t)S*2*L);
    int* cIdev  = (int*)alloc((size_t)Dn);
    int* cIfrag = (int*)alloc((size_t)F);
    int* cFdn   = (int*)alloc((size_t)F);
    int* cFdr   = (int*)alloc((size_t)F);
    int* cLen   = (int*)alloc((size_t)S);
    int* cFsvc  = (int*)alloc((size_t)F);
    int* cFpos  = (int*)alloc((size_t)F);
    int* inv    = (int*)alloc((size_t)S*L);
    int* counts = (int*)alloc((size_t)Dn);
    int* offs   = (int*)alloc((size_t)Dn+1);
    int* cursor = (int*)alloc((size_t)Dn);
    int* list   = (int*)alloc((size_t)F);

    const int* det = r_idev;
    auto cvt = [&](const int* src, int* dst, int n){
        k_cvt<<<dim3((n+255)/256),256,0,stream>>>(src, dst, n, det);
    };
    cvt(r_exe,  cExe,  S*2*L);
    cvt(r_idev, cIdev, Dn);
    cvt(r_ifrag,cIfrag,F);
    cvt(r_fdn,  cFdn,  F);
    cvt(r_fdr,  cFdr,  F);
    cvt(r_len,  cLen,  S);
    cvt(r_fsvc, cFsvc, F);
    cvt(r_fpos, cFpos, F);

    k_wt<<<dim3((98304+255)/256),256,0,stream>>>(C_Wih, tCWih, 384, 8, 255, 98304);
    k_wt2<<<dim3((49152+255)/256),256,0,stream>>>(C_Whh, tCWhhHi, tCWhhLo, 384, 7, 127, 49152);
    k_wt<<<dim3((98304+255)/256),256,0,stream>>>(F_Wih, tFWih, 384, 8, 255, 98304);
    k_wt<<<dim3((49152+255)/256),256,0,stream>>>(F_Whh, tFWhh, 384, 7, 127, 49152);
    k_wt<<<dim3((98304+255)/256),256,0,stream>>>(D_Wih, tDWih, 384, 8, 255, 98304);
    k_wt<<<dim3((49152+255)/256),256,0,stream>>>(D_Whh, tDWhh, 384, 7, 127, 49152);
    k_wt<<<dim3((131072+255)/256),256,0,stream>>>(W_tgt, tWtgt, 1024, 7, 127, 131072);
    k_wt<<<dim3((262144+255)/256),256,0,stream>>>(W_src, tWsrc, 1024, 8, 255, 262144);

    hipMemsetAsync(state, 0, (size_t)nodes*128*4, stream);
    hipMemsetAsync(state_bf, 0, (size_t)nodes*128*2, stream);
    hipMemsetAsync(inv, 0xFF, (size_t)S*L*4, stream);
    hipMemsetAsync(counts, 0, (size_t)Dn*4, stream);
    hipMemsetAsync(cursor, 0, (size_t)Dn*4, stream);

    k_proj5<<<dim3((Dn*128+255)/256),256,0,stream>>>(realnode, W_dev, b_dev, cIdev, cIdev,
        state, state_bf, devA, devA_bf, Dn, nreal, nodes);
    k_proj5<<<dim3(((size_t)F*128+255)/256),256,0,stream>>>(realnode, W_frg, b_frg, cIfrag, cIfrag,
        state, state_bf, fragA, fragA_bf, F, nreal, nodes);
    k_proj5<<<dim3((S*128+255)/256),256,0,stream>>>(arr, W_srv, b_srv, nullptr, nullptr,
        h_srv, nullptr, nullptr, nullptr, S, S, nodes);
    k_build_inv<<<dim3((F+255)/256),256,0,stream>>>(cFsvc, cFpos, inv, F, L, S);
    k_count<<<dim3((F+255)/256),256,0,stream>>>(cFdr, counts, F, Dn);
    k_scan<<<1,256,0,stream>>>(counts, offs, Dn);
    k_fill<<<dim3((F+255)/256),256,0,stream>>>(cFdr, offs, cursor, list, F, Dn);

    const int nrF = F/128, nrD = Dn/128;
    for (int it=0; it<NIT; ++it){
        // phiC: batched gi (pipelined MFMA) + fused MFMA recurrence
        mm2<<<dim3(3*nrF),256,0,stream>>>(state_bf, state_bf, cIfrag, cFdn,
            tCWih, C_bih, giF, F, 384, 256, 0, 1.f, nrF);
        k_recur<<<dim3(S/16),512,0,stream>>>(h_srv, giF, tCWhhHi, tCWhhLo, C_bhh, inv,
            out_f, out_f_bf, S, L, F);
        // attention
        mm2<<<dim3(8*nrD),256,0,stream>>>(devA_bf, devA_bf, nullptr, nullptr,
            tWtgt, b_tgt, TGT, Dn, 1024, 128, 0, 1.f, nrD);
        mm2<<<dim3(8*nrF),256,0,stream>>>(out_f_bf, fragA_bf, nullptr, nullptr,
            tWsrc, b_src, SRC, F, 1024, 256, 2, 1.f, nrF);
        k_attn<<<dim3(Dn),256,0,stream>>>(SRC, TGT, att, list, offs, bias_att, msgDm, alphaB, Dn, F);
        // F-GRU fully fused (in-place on fragA, write-through to state + bf16 mirrors)
        k_grufuse<<<dim3(nrF),512,0,stream>>>(out_f, state, nullptr, cFdn, 0,
            tFWih, tFWhh, F_bih, F_bhh, fragA, fragA_bf, state, state_bf, cIfrag, F, nodes);
        // D-GRU fully fused
        k_grufuse<<<dim3(nrD),512,0,stream>>>(msgDm, nullptr, nullptr, nullptr, 256,
            tDWih, tDWhh, D_bih, D_bhh, devA, devA_bf, state, state_bf, cIdev, Dn, nodes);
    }

    // readout
    hipMemsetAsync(pooled, 0, (size_t)S*128*4, stream);
    k_pool_add<<<dim3(((size_t)F*128+255)/256),256,0,stream>>>(fragA, cFsvc, pooled, F, S);
    k_pool_div<<<dim3((S*128+255)/256),256,0,stream>>>(pooled, cLen, S);
    k_mm<<<dim3(256/128, S/128),256,0,stream>>>(pooled, 128, Wl1, 256, bl1, TGT, S, 256, 128, 1, 1.f, 0);
    k_mm<<<dim3(256/128, S/128),256,0,stream>>>(TGT, 256, Wl2, 256, bl2, Z, S, 256, 256, 1, 1.f, 0);
    k_dot_out<<<dim3(S),256,0,stream>>>(Z, Wl3, bl3, outp, 0);
    k_mm<<<dim3(256/128, S/128),256,0,stream>>>(h_srv, 128, Wt1, 256, bt1, TGT, S, 256, 128, 1, 1.f, 0);
    k_mm<<<dim3(256/128, S/128),256,0,stream>>>(TGT, 256, Wt2, 256, bt2, Z, S, 256, 256, 1, 1.f, 0);
    k_dot_out<<<dim3(S),256,0,stream>>>(Z, Wt3, bt3, outp, S);
}

// Round 12
// 968.199 us; speedup vs baseline: 1.6311x; 1.0403x over previous
//
#include <hip/hip_runtime.h>
#include <hip/hip_bf16.h>

typedef __attribute__((ext_vector_type(8))) short bf16x8;
typedef __attribute__((ext_vector_type(4))) float f32x4;

__device__ __forceinline__ float sigf(float x){ return 1.0f/(1.0f+expf(-x)); }
__device__ __forceinline__ int clampi(int v, int lo, int hi){ return v<lo?lo:(v>hi?hi:v); }
__device__ __forceinline__ unsigned short f2b(float f){
    __hip_bfloat16 h = __float2bfloat16(f);
    return *reinterpret_cast<unsigned short*>(&h);
}
__device__ __forceinline__ float us2f(unsigned short u){ return __uint_as_float(((unsigned)u)<<16); }

__device__ __forceinline__ void gload16(const void* g, void* l){
    __builtin_amdgcn_global_load_lds((const __attribute__((address_space(1))) void*)g,
                                     (__attribute__((address_space(3))) void*)l, 16, 0, 0);
}

// ---- int64/int32 tolerant index conversion ----
__global__ void k_cvt(const int* __restrict__ src, int* __restrict__ dst, int n,
                      const int* __restrict__ det)
{
    int i = blockIdx.x*blockDim.x + threadIdx.x;
    if (i >= n) return;
    int stride = (det[1] == 0) ? 2 : 1;
    dst[i] = src[(size_t)i*stride];
}

// ---- weight transpose+convert: Wt[n][k] (bf16) <- W[k][n] (f32) ----
__global__ void k_wt(const float* __restrict__ W, unsigned short* __restrict__ Wt,
                     int N, int kshift, int kmask, int total)
{
    int idx = blockIdx.x*blockDim.x + threadIdx.x;
    if (idx >= total) return;
    int n = idx >> kshift, k = idx & kmask;
    Wt[idx] = f2b(W[(size_t)k*N + n]);
}

// ---- split transpose+convert ----
__global__ void k_wt2(const float* __restrict__ W, unsigned short* __restrict__ Whi,
                      unsigned short* __restrict__ Wlo, int N, int kshift, int kmask, int total)
{
    int idx = blockIdx.x*blockDim.x + threadIdx.x;
    if (idx >= total) return;
    int n = idx >> kshift, k = idx & kmask;
    float v = W[(size_t)k*N + n];
    unsigned short hi = f2b(v);
    Whi[idx] = hi;
    Wlo[idx] = f2b(v - us2f(hi));
}

// ---------------- init projections (+ bf16 mirrors) ----------------
__global__ void k_proj5(const float* __restrict__ X, const float* __restrict__ W,
                        const float* __restrict__ bias,
                        const int* __restrict__ gidx, const int* __restrict__ sidx,
                        float* __restrict__ out, unsigned short* __restrict__ outBf,
                        float* __restrict__ out2, unsigned short* __restrict__ out2Bf,
                        int M, int nrows, int nodes)
{
    int t = blockIdx.x*blockDim.x + threadIdx.x;
    int i = t >> 7, j = t & 127;
    if (i >= M) return;
    int src = gidx ? clampi(gidx[i]-1, 0, nrows-1) : i;
    const float* xp = X + (size_t)src*5;
    float acc = bias[j];
#pragma unroll
    for (int k=0;k<5;k++) acc += xp[k] * W[k*128+j];
    int dr = sidx ? clampi(sidx[i], 0, nodes-1) : i;
    out[(size_t)dr*128 + j] = acc;
    if (outBf) outBf[(size_t)dr*128 + j] = f2b(acc);
    if (out2){ out2[(size_t)i*128 + j] = acc; out2Bf[(size_t)i*128 + j] = f2b(acc); }
}

// ---------------- f32 tiled GEMM (readout heads only) ----------------
__launch_bounds__(256)
__global__ void k_mm(const float* __restrict__ A0, int lda,
                     const float* __restrict__ B, int ldb,
                     const float* __restrict__ bias, float* __restrict__ C,
                     int M, int N, int K, int relu, float scale, int accum)
{
    __shared__ float As[16][132];
    __shared__ float Bs[16][132];
    int tid = threadIdx.x;
    int tx = tid & 15, ty = tid >> 4;
    int row0 = blockIdx.y * 128, col0 = blockIdx.x * 128;
    float acc[8][8] = {};
    for (int k0 = 0; k0 < K; k0 += 16){
#pragma unroll
        for (int q = 0; q < 2; ++q){
            int idx = tid + q*256;
            int r = idx >> 2, k4 = (idx & 3) * 4;
            const float* src = A0 + (size_t)(row0+r)*lda + k0 + k4;
            float4 v = *reinterpret_cast<const float4*>(src);
            As[k4+0][r]=v.x; As[k4+1][r]=v.y; As[k4+2][r]=v.z; As[k4+3][r]=v.w;
        }
#pragma unroll
        for (int q = 0; q < 2; ++q){
            int idx = tid + q*256;
            int kb = idx >> 5, n4 = (idx & 31) * 4;
            float4 v = *reinterpret_cast<const float4*>(B + (size_t)(k0+kb)*ldb + col0 + n4);
            *reinterpret_cast<float4*>(&Bs[kb][n4]) = v;
        }
        __syncthreads();
#pragma unroll
        for (int k = 0; k < 16; ++k){
            float a[8], b[8];
            *(float4*)&a[0] = *(const float4*)&As[k][ty*8];
            *(float4*)&a[4] = *(const float4*)&As[k][ty*8+4];
            *(float4*)&b[0] = *(const float4*)&Bs[k][tx*8];
            *(float4*)&b[4] = *(const float4*)&Bs[k][tx*8+4];
#pragma unroll
            for (int i=0;i<8;i++)
#pragma unroll
                for (int j=0;j<8;j++) acc[i][j] += a[i]*b[j];
        }
        __syncthreads();
    }
    float bb[8];
#pragma unroll
    for (int j=0;j<8;j++) bb[j] = bias ? bias[col0+tx*8+j] : 0.f;
#pragma unroll
    for (int i=0;i<8;i++){
        float* cp = C + (size_t)(row0+ty*8+i)*N + col0 + tx*8;
#pragma unroll
        for (int jq=0;jq<2;jq++){
            float4 prev = accum ? *(const float4*)(cp+jq*4) : make_float4(0,0,0,0);
            float o[4];
#pragma unroll
            for (int c=0;c<4;c++){
                float u = acc[i][jq*4+c] + bb[jq*4+c];
                if (relu) u = fmaxf(u,0.f);
                o[c] = (&prev.x)[c] + scale*u;
            }
            *(float4*)(cp+jq*4) = make_float4(o[0],o[1],o[2],o[3]);
        }
    }
}

// ---------------- pipelined bf16 MFMA GEMM (global_load_lds + double buffer) ----------------
__launch_bounds__(256)
__global__ void mm2(const unsigned short* __restrict__ A0, const unsigned short* __restrict__ A1,
                    const int* __restrict__ i0, const int* __restrict__ i1,
                    const unsigned short* __restrict__ Wt,
                    const float* __restrict__ bias, void* __restrict__ C,
                    int M, int N, int K, int epi, float scale, int nrow)
{
    __shared__ alignas(16) unsigned short As[2][128*64];
    __shared__ alignas(16) unsigned short Bs[2][128*64];
    int tid = threadIdx.x;
    int l = tid & 63, w = tid >> 6;
    int wr = w >> 1, wc = w & 1;
    int bid = blockIdx.x;
    int row0 = (bid % nrow) * 128, col0 = (bid / nrow) * 128;
    int nK = K >> 6;

    f32x4 acc[4][4];
#pragma unroll
    for (int m=0;m<4;m++)
#pragma unroll
        for (int n=0;n<4;n++) acc[m][n] = (f32x4){0.f,0.f,0.f,0.f};

    auto stage = [&](int buf, int k0){
#pragma unroll
        for (int q=0;q<4;q++){
            int slot = q*256 + w*64 + l;
            int r = slot >> 3, c8 = slot & 7;
            int g8 = c8 ^ (r & 7);
            int row; const unsigned short* base; int kl;
            if (k0 < 128){ row = i0 ? i0[row0+r] : (row0+r); base = A0; kl = k0; }
            else         { row = i1 ? i1[row0+r] : (row0+r); base = A1; kl = k0-128; }
            const char* g = (const char*)(base + (size_t)row*128 + kl) + g8*16;
            gload16(g, (void*)&As[buf][(size_t)(q*256 + w*64)*8]);
        }
#pragma unroll
        for (int q=0;q<4;q++){
            int slot = q*256 + w*64 + l;
            int n = slot >> 3, kc = slot & 7;
            int g8 = kc ^ (n & 7);
            const char* g = (const char*)(Wt + (size_t)(col0+n)*K + k0) + g8*16;
            gload16(g, (void*)&Bs[buf][(size_t)(q*256 + w*64)*8]);
        }
    };

    stage(0, 0);
    __syncthreads();
    for (int ks=0; ks<nK; ++ks){
        int cur = ks & 1;
        if (ks+1 < nK) stage(cur^1, (ks+1)*64);
#pragma unroll
        for (int kk = 0; kk < 2; ++kk){
            int ek = kk*32 + (l >> 4) * 8;
            bf16x8 af[4], bf[4];
#pragma unroll
            for (int m=0;m<4;m++){
                int r = wr*64 + m*16 + (l & 15);
                af[m] = *reinterpret_cast<const bf16x8*>(&As[cur][r*64 + (ek ^ ((r & 7) << 3))]);
            }
#pragma unroll
            for (int n=0;n<4;n++){
                int c = wc*64 + n*16 + (l & 15);
                bf[n] = *reinterpret_cast<const bf16x8*>(&Bs[cur][c*64 + (ek ^ ((c & 7) << 3))]);
            }
#pragma unroll
            for (int m=0;m<4;m++)
#pragma unroll
                for (int n=0;n<4;n++)
                    acc[m][n] = __builtin_amdgcn_mfma_f32_16x16x32_bf16(af[m], bf[n], acc[m][n], 0, 0, 0);
        }
        __syncthreads();
    }

#pragma unroll
    for (int m=0;m<4;m++){
#pragma unroll
        for (int v=0;v<4;v++){
            int row = row0 + wr*64 + m*16 + (l >> 4)*4 + v;
            size_t base = (size_t)row*N + col0 + wc*64 + (l & 15);
#pragma unroll
            for (int n=0;n<4;n++){
                int col = col0 + wc*64 + n*16 + (l & 15);
                float u = scale*acc[m][n][v] + (bias ? bias[col] : 0.f);
                if (epi == 0) ((float*)C)[base + n*16] = u;
                else          ((unsigned short*)C)[base + n*16] = f2b(u);
            }
        }
    }
}

// ---------------- fully fused GRU, pipelined bf16 staging ----------------
// 512 thr = 8 waves; wave w owns rows [w*16,w*16+16). gi: steps 0-3 (K=256, two-half
// indexed bf16 A). gh: steps 4-5 (K=128 from Hbf). n-gate gh separate (accN).
__launch_bounds__(512)
__global__ void k_grufuse(const unsigned short* __restrict__ A0, const unsigned short* __restrict__ A1,
                          const int* __restrict__ i0, const int* __restrict__ i1, int lda,
                          const unsigned short* __restrict__ Wih,   // [384][256] bf16
                          const unsigned short* __restrict__ Whh,   // [384][128] bf16
                          const float* __restrict__ bih, const float* __restrict__ bhh,
                          float* __restrict__ H, unsigned short* __restrict__ Hbf,
                          float* __restrict__ state, unsigned short* __restrict__ stateBf,
                          const int* __restrict__ sidx, int M, int nodes)
{
    __shared__ alignas(16) unsigned short As[2][128*64];   // 32 KB
    __shared__ alignas(16) unsigned short Bs[2][384*64];   // 96 KB
    int tid = threadIdx.x;
    int l = tid & 63, w = tid >> 6;
    int row0 = blockIdx.x * 128;
    f32x4 acc[24], accN[8];
#pragma unroll
    for (int n=0;n<24;n++) acc[n] = (f32x4){0.f,0.f,0.f,0.f};
#pragma unroll
    for (int n=0;n<8;n++) accN[n] = (f32x4){0.f,0.f,0.f,0.f};

    auto stage = [&](int buf, int st){
        int k0 = st*64;
#pragma unroll
        for (int q=0;q<2;q++){
            int slot = q*512 + w*64 + l;
            int r = slot >> 3, c8 = slot & 7;
            int g8 = c8 ^ (r & 7);
            const unsigned short* src;
            if (st < 4){
                if (i1){
                    if (k0 < 128){ int ri = i0 ? i0[row0+r] : (row0+r); src = A0 + (size_t)ri*128 + k0; }
                    else         { int ri = i1[row0+r]; src = A1 + (size_t)ri*128 + (k0-128); }
                } else {
                    src = A0 + (size_t)(row0+r)*lda + k0;
                }
            } else {
                src = Hbf + (size_t)(row0+r)*128 + (k0-256);
            }
            gload16((const char*)src + g8*16, (void*)&As[buf][(size_t)(q*512 + w*64)*8]);
        }
#pragma unroll
        for (int q=0;q<6;q++){
            int slot = q*512 + w*64 + l;
            int n = slot >> 3, kc = slot & 7;
            int g8 = kc ^ (n & 7);
            const unsigned short* src = (st < 4) ? (Wih + (size_t)n*256 + k0)
                                                 : (Whh + (size_t)n*128 + (k0-256));
            gload16((const char*)src + g8*16, (void*)&Bs[buf][(size_t)(q*512 + w*64)*8]);
        }
    };

    stage(0, 0);
    __syncthreads();
    // gi phase: steps 0..3
    for (int st=0; st<4; ++st){
        int cur = st & 1;
        stage(cur^1, st+1);
#pragma unroll
        for (int kk=0; kk<2; ++kk){
            int ek = kk*32 + (l >> 4)*8;
            int r = w*16 + (l & 15);
            bf16x8 af = *reinterpret_cast<const bf16x8*>(&As[cur][r*64 + (ek ^ ((r & 7) << 3))]);
#pragma unroll
            for (int n=0;n<24;n++){
                int c = n*16 + (l & 15);
                bf16x8 bf = *reinterpret_cast<const bf16x8*>(&Bs[cur][c*64 + (ek ^ ((c & 7) << 3))]);
                acc[n] = __builtin_amdgcn_mfma_f32_16x16x32_bf16(af, bf, acc[n], 0, 0, 0);
            }
        }
        __syncthreads();
    }
    // gh phase: steps 4..5
    for (int st=4; st<6; ++st){
        int cur = st & 1;
        if (st+1 < 6) stage(cur^1, st+1);
#pragma unroll
        for (int kk=0; kk<2; ++kk){
            int ek = kk*32 + (l >> 4)*8;
            int r = w*16 + (l & 15);
            bf16x8 af = *reinterpret_cast<const bf16x8*>(&As[cur][r*64 + (ek ^ ((r & 7) << 3))]);
#pragma unroll
            for (int n=0;n<24;n++){
                int c = n*16 + (l & 15);
                bf16x8 bf = *reinterpret_cast<const bf16x8*>(&Bs[cur][c*64 + (ek ^ ((c & 7) << 3))]);
                if (n < 16) acc[n]     = __builtin_amdgcn_mfma_f32_16x16x32_bf16(af, bf, acc[n], 0, 0, 0);
                else        accN[n-16] = __builtin_amdgcn_mfma_f32_16x16x32_bf16(af, bf, accN[n-16], 0, 0, 0);
            }
        }
        __syncthreads();
    }
    // epilogue
#pragma unroll
    for (int v=0;v<4;v++){
        int row = row0 + w*16 + (l >> 4)*4 + v;
        int st = (state && row < M) ? clampi(sidx[row],0,nodes-1) : 0;
#pragma unroll
        for (int c=0;c<8;c++){
            int col = c*16 + (l & 15);
            float rr = sigf(acc[c][v]    + bih[col]     + bhh[col]);
            float zz = sigf(acc[c+8][v]  + bih[col+128] + bhh[col+128]);
            float nn = tanhf(acc[c+16][v] + bih[col+256] + rr*(accN[c][v] + bhh[col+256]));
            float hv = H[(size_t)row*128 + col];
            float hn = (1.f-zz)*nn + zz*hv;
            unsigned short hb = f2b(hn);
            H[(size_t)row*128 + col] = hn;
            Hbf[(size_t)row*128 + col] = hb;
            if (state){
                state[(size_t)st*128 + col] = hn;
                stateBf[(size_t)st*128 + col] = hb;
            }
        }
    }
}

// ---------------- fused GAT attention (+ msgD bf16 mirror) ----------------
__launch_bounds__(256)
__global__ void k_attn(const unsigned short* __restrict__ SRC, const float* __restrict__ tgt,
                       const float* __restrict__ att, const int* __restrict__ list,
                       const int* __restrict__ offs, const float* __restrict__ batt,
                       float* __restrict__ msgD, unsigned short* __restrict__ msgDbf,
                       float* __restrict__ alphaG, int Dn, int F)
{
    __shared__ float tg[1024];
    __shared__ float alds[128*4];
    __shared__ float accs[4][256];
    int d = blockIdx.x;
    int tid = threadIdx.x;
    int w = tid >> 6, lane = tid & 63;
    for (int u = tid; u < 1024; u += 256) tg[u] = tgt[(size_t)d*1024 + u];
    __syncthreads();
    int beg = offs[d], end = offs[d+1];
    if (beg < 0) beg = 0; if (end > F) end = F; if (end < beg) end = beg;
    int c0 = w*256 + lane*4;
    float t0 = tg[c0], t1 = tg[c0+1], t2 = tg[c0+2], t3 = tg[c0+3];
    float a0 = att[c0], a1 = att[c0+1], a2 = att[c0+2], a3 = att[c0+3];
    float amax = -3.4e38f;
    for (int i=beg;i<end;i++){
        int f = list[i];
        ushort4 sv = *reinterpret_cast<const ushort4*>(SRC + (size_t)f*1024 + c0);
        float e0 = us2f(sv.x)+t0, e1 = us2f(sv.y)+t1, e2 = us2f(sv.z)+t2, e3 = us2f(sv.w)+t3;
        e0 = e0>0.f?e0:0.2f*e0; e1 = e1>0.f?e1:0.2f*e1;
        e2 = e2>0.f?e2:0.2f*e2; e3 = e3>0.f?e3:0.2f*e3;
        float s = e0*a0 + e1*a1 + e2*a2 + e3*a3;
#pragma unroll
        for (int msk=1; msk<64; msk<<=1) s += __shfl_xor(s, msk);
        int li = i - beg;
        if (li < 128){ if (lane == 0) alds[li*4+w] = s; }
        else         { if (lane == 0) alphaG[(size_t)f*4+w] = s; }
        amax = fmaxf(amax, s);
    }
    __syncthreads();
    float wsum = 0.f;
    for (int i=beg;i<end;i++){
        int li = i - beg;
        float a = (li < 128) ? alds[li*4+w] : alphaG[(size_t)list[i]*4+w];
        wsum += expf(a - amax);
    }
    float iws = 1.f/(wsum + 1e-16f);
    float acc[4] = {0,0,0,0};
    for (int i=beg;i<end;i++){
        int f = list[i];
        int li = i - beg;
        float a = (li < 128) ? alds[li*4+w] : alphaG[(size_t)f*4+w];
        float p = expf(a - amax)*iws;
        ushort4 sv = *reinterpret_cast<const ushort4*>(SRC + (size_t)f*1024 + c0);
        acc[0] += p*us2f(sv.x); acc[1] += p*us2f(sv.y);
        acc[2] += p*us2f(sv.z); acc[3] += p*us2f(sv.w);
    }
#pragma unroll
    for (int j=0;j<4;j++) accs[w][lane*4+j] = acc[j];
    __syncthreads();
    if (tid < 256){
        float m = (accs[0][tid]+accs[1][tid]+accs[2][tid]+accs[3][tid])*0.25f + batt[tid];
        msgD[(size_t)d*256 + tid] = m;
        msgDbf[(size_t)d*256 + tid] = f2b(m);
    }
}

// ---------------- fused phiC recurrence: bf16 h in swizzled LDS, no per-step f2b ----------------
__launch_bounds__(512)
__global__ void k_recur(float* __restrict__ h_srv, const float* __restrict__ giF,
                        const unsigned short* __restrict__ Whi,
                        const unsigned short* __restrict__ Wlo,
                        const float* __restrict__ bhh,
                        const int* __restrict__ inv, float* __restrict__ out_f,
                        unsigned short* __restrict__ out_f_bf,
                        int S, int L, int F)
{
    __shared__ float hs[16][129];
    __shared__ alignas(16) unsigned short hsHi[16*128];
    __shared__ alignas(16) unsigned short hsLo[16*128];
    __shared__ float ghs[16][385];
    __shared__ int fLoc[16][16];   // [t][s]
    int tid = threadIdx.x;
    int l = tid & 63, w = tid >> 6;
    int lane15 = l & 15, lhi = l >> 4;
    int s0 = blockIdx.x * 16;
    for (int u = tid; u < 2048; u += 512){
        int s=u>>7,k=u&127;
        float v = h_srv[(size_t)(s0+s)*128+k];
        hs[s][k] = v;
        unsigned short hb = f2b(v);
        int ksw = k ^ ((s & 7) << 3);
        hsHi[s*128 + ksw] = hb;
        hsLo[s*128 + ksw] = f2b(v - us2f(hb));
    }
    if (tid < 256) fLoc[tid>>4][tid&15] = inv[(size_t)(s0+(tid&15))*L + (tid>>4)];
    bf16x8 wHi[3][4], wLo[3][4];
#pragma unroll
    for (int ct=0; ct<3; ++ct){
        int col = w*48 + ct*16 + lane15;
#pragma unroll
        for (int ks=0; ks<4; ++ks){
            size_t off = (size_t)col*128 + ks*32 + lhi*8;
            wHi[ct][ks] = *reinterpret_cast<const bf16x8*>(Whi + off);
            wLo[ct][ks] = *reinterpret_cast<const bf16x8*>(Wlo + off);
        }
    }
    __syncthreads();
    for (int t=0;t<L;++t){
        bf16x8 hHi[4], hLo[4];
#pragma unroll
        for (int ks=0; ks<4; ++ks){
            int ek = ks*32 + lhi*8;
            int off = lane15*128 + (ek ^ ((lane15 & 7) << 3));
            hHi[ks] = *reinterpret_cast<const bf16x8*>(&hsHi[off]);
            hLo[ks] = *reinterpret_cast<const bf16x8*>(&hsLo[off]);
        }
#pragma unroll
        for (int ct=0; ct<3; ++ct){
            f32x4 acc = (f32x4){0.f,0.f,0.f,0.f};
#pragma unroll
            for (int ks=0; ks<4; ++ks){
                acc = __builtin_amdgcn_mfma_f32_16x16x32_bf16(hHi[ks], wHi[ct][ks], acc, 0,0,0);
                acc = __builtin_amdgcn_mfma_f32_16x16x32_bf16(hLo[ks], wHi[ct][ks], acc, 0,0,0);
                acc = __builtin_amdgcn_mfma_f32_16x16x32_bf16(hHi[ks], wLo[ct][ks], acc, 0,0,0);
            }
            int col = w*48 + ct*16 + lane15;
            float bb = bhh[col];
#pragma unroll
            for (int v=0; v<4; ++v){
                ghs[lhi*4 + v][col] = acc[v] + bb;
            }
        }
        __syncthreads();
        for (int u = tid; u < 2048; u += 512){
            int s=u>>7, k=u&127; int f = fLoc[t][s];
            if (f >= 0 && f < F){
                const float* gp = giF + (size_t)f*384;
                float r  = sigf(gp[k]     + ghs[s][k]);
                float zz = sigf(gp[128+k] + ghs[s][128+k]);
                float n  = tanhf(gp[256+k] + r*ghs[s][256+k]);
                float hn = (1.f-zz)*n + zz*hs[s][k];
                hs[s][k] = hn;
                unsigned short hb = f2b(hn);
                int ksw = k ^ ((s & 7) << 3);
                hsHi[s*128 + ksw] = hb;
                hsLo[s*128 + ksw] = f2b(hn - us2f(hb));
                out_f[(size_t)f*128+k] = hn;
                out_f_bf[(size_t)f*128+k] = hb;
            }
        }
        __syncthreads();
    }
    for (int u = tid; u < 2048; u += 512){ int s=u>>7,k=u&127; h_srv[(size_t)(s0+s)*128+k] = hs[s][k]; }
}

__global__ void k_count(const int* __restrict__ row, int* __restrict__ counts, int F, int Dn)
{ int f = blockIdx.x*blockDim.x + threadIdx.x; if (f < F) atomicAdd(&counts[clampi(row[f],0,Dn-1)], 1); }

__global__ void k_scan(const int* __restrict__ counts, int* __restrict__ offs, int D)
{
    __shared__ int part[257];
    int tid = threadIdx.x;
    int per = (D + 255) / 256;
    int s = 0;
    for (int i=0;i<per;i++){ int idx = tid*per+i; if (idx < D) s += counts[idx]; }
    part[tid] = s;
    __syncthreads();
    if (tid == 0){
        int acc = 0;
        for (int i=0;i<256;i++){ int v = part[i]; part[i] = acc; acc += v; }
        part[256] = acc;
    }
    __syncthreads();
    int acc = part[tid];
    for (int i=0;i<per;i++){ int idx = tid*per+i; if (idx < D){ offs[idx] = acc; acc += counts[idx]; } }
    if (tid == 0) offs[D] = part[256];
}

__global__ void k_fill(const int* __restrict__ row, const int* __restrict__ offs,
                       int* __restrict__ cursor, int* __restrict__ list, int F, int Dn)
{
    int f = blockIdx.x*blockDim.x + threadIdx.x;
    if (f >= F) return;
    int r = clampi(row[f],0,Dn-1);
    int p = atomicAdd(&cursor[r], 1);
    int pos = offs[r]+p;
    if (pos >= 0 && pos < F) list[pos] = f;
}

__global__ void k_build_inv(const int* __restrict__ fs, const int* __restrict__ fp,
                            int* __restrict__ inv, int F, int L, int S)
{
    int f = blockIdx.x*blockDim.x + threadIdx.x;
    if (f >= F) return;
    inv[clampi(fs[f],0,S-1)*L + clampi(fp[f],0,L-1)] = f;
}

__global__ void k_pool_add(const float* __restrict__ frag, const int* __restrict__ fs,
                           float* __restrict__ pooled, int F, int S)
{
    int t = blockIdx.x*blockDim.x + threadIdx.x;
    int i = t >> 7, j = t & 127;
    if (i >= F) return;
    atomicAdd(&pooled[(size_t)clampi(fs[i],0,S-1)*128 + j], frag[(size_t)i*128 + j]);
}

__global__ void k_pool_div(float* __restrict__ pooled, const int* __restrict__ lengths, int S)
{
    int t = blockIdx.x*blockDim.x + threadIdx.x;
    int i = t >> 7, j = t & 127;
    if (i >= S) return;
    int l = lengths[i]; if (l < 1) l = 1;
    pooled[(size_t)i*128 + j] /= (float)l;
}

__global__ void k_dot_out(const float* __restrict__ H, const float* __restrict__ W3,
                          const float* __restrict__ b3, float* __restrict__ outv, int off)
{
    __shared__ float red[256];
    int s = blockIdx.x, tid = threadIdx.x;
    red[tid] = H[(size_t)s*256 + tid] * W3[tid];
    __syncthreads();
    for (int st=128; st; st>>=1){ if (tid < st) red[tid] += red[tid+st]; __syncthreads(); }
    if (tid == 0) outv[off + s] = red[0] + b3[0];
}

// =====================================================================================
extern "C" void kernel_launch(void* const* d_in, const int* in_sizes, int n_in,
                              void* d_out, int out_size, void* d_ws, size_t ws_size,
                              hipStream_t stream)
{
    (void)n_in; (void)out_size; (void)ws_size;
    const float* realnode = (const float*)d_in[0];
    const float* arr      = (const float*)d_in[1];
    const int* r_exe   = (const int*)d_in[2];
    const int* r_idev  = (const int*)d_in[3];
    const int* r_ifrag = (const int*)d_in[4];
    const int* r_fdn   = (const int*)d_in[5];
    const int* r_fdr   = (const int*)d_in[6];
    const int* r_len   = (const int*)d_in[7];
    const int* r_fsvc  = (const int*)d_in[8];
    const int* r_fpos  = (const int*)d_in[9];
    const float *W_dev=(const float*)d_in[10], *b_dev=(const float*)d_in[11];
    const float *W_frg=(const float*)d_in[12], *b_frg=(const float*)d_in[13];
    const float *W_srv=(const float*)d_in[14], *b_srv=(const float*)d_in[15];
    const float *C_Wih=(const float*)d_in[16], *C_Whh=(const float*)d_in[17], *C_bih=(const float*)d_in[18], *C_bhh=(const float*)d_in[19];
    const float *F_Wih=(const float*)d_in[20], *F_Whh=(const float*)d_in[21], *F_bih=(const float*)d_in[22], *F_bhh=(const float*)d_in[23];
    const float *D_Wih=(const float*)d_in[24], *D_Whh=(const float*)d_in[25], *D_bih=(const float*)d_in[26], *D_bhh=(const float*)d_in[27];
    const float *W_src=(const float*)d_in[28], *b_src=(const float*)d_in[29];
    const float *W_tgt=(const float*)d_in[30], *b_tgt=(const float*)d_in[31];
    const float *att=(const float*)d_in[32], *bias_att=(const float*)d_in[33];
    const float *Wt1=(const float*)d_in[34], *bt1=(const float*)d_in[35], *Wt2=(const float*)d_in[36], *bt2=(const float*)d_in[37], *Wt3=(const float*)d_in[38], *bt3=(const float*)d_in[39];
    const float *Wl1=(const float*)d_in[40], *bl1=(const float*)d_in[41], *Wl2=(const float*)d_in[42], *bl2=(const float*)d_in[43], *Wl3=(const float*)d_in[44], *bl3=(const float*)d_in[45];
    float* outp = (float*)d_out;

    const int S  = in_sizes[7];
    const int Dn = in_sizes[3];
    const int F  = in_sizes[4];
    const int L  = in_sizes[2] / (2*S);
    const int nreal = in_sizes[0]/5;
    const int nodes = nreal + 1;
    const int NIT = 3;

    char* wp = (char*)d_ws;
    auto alloc = [&](size_t nelem)->float*{
        float* p = (float*)wp;
        wp += ((nelem*4 + 255)/256)*256;
        return p;
    };
    float* state  = alloc((size_t)nodes*128);
    float* h_srv  = alloc((size_t)S*128);
    float* out_f  = alloc((size_t)F*128);
    float* fragA  = alloc((size_t)F*128);
    float* devA   = alloc((size_t)Dn*128);
    float* alphaB = alloc((size_t)F*4);
    float* msgDm  = alloc((size_t)Dn*256);
    float* UNION  = alloc((size_t)F*512);
    float* giF    = UNION;
    unsigned short* SRC = (unsigned short*)UNION;
    float* TGT    = alloc((size_t)Dn*1024);
    float* Z      = alloc((size_t)Dn*1024);
    float* pooled = alloc((size_t)S*128);
    unsigned short* state_bf = (unsigned short*)alloc((size_t)nodes*64);
    unsigned short* out_f_bf = (unsigned short*)alloc((size_t)F*64);
    unsigned short* fragA_bf = (unsigned short*)alloc((size_t)F*64);
    unsigned short* devA_bf  = (unsigned short*)alloc((size_t)Dn*64);
    unsigned short* msgD_bf  = (unsigned short*)alloc((size_t)Dn*128);
    unsigned short* tCWih   = (unsigned short*)alloc(384*256/2);
    unsigned short* tCWhhHi = (unsigned short*)alloc(384*128/2);
    unsigned short* tCWhhLo = (unsigned short*)alloc(384*128/2);
    unsigned short* tFWih   = (unsigned short*)alloc(384*256/2);
    unsigned short* tFWhh   = (unsigned short*)alloc(384*128/2);
    unsigned short* tDWih   = (unsigned short*)alloc(384*256/2);
    unsigned short* tDWhh   = (unsigned short*)alloc(384*128/2);
    unsigned short* tWtgt   = (unsigned short*)alloc(1024*128/2);
    unsigned short* tWsrc   = (unsigned short*)alloc(1024*256/2);
    int* cExe   = (int*)alloc((size_t)S*2*L);
    int* cIdev  = (int*)alloc((size_t)Dn);
    int* cIfrag = (int*)alloc((size_t)F);
    int* cFdn   = (int*)alloc((size_t)F);
    int* cFdr   = (int*)alloc((size_t)F);
    int* cLen   = (int*)alloc((size_t)S);
    int* cFsvc  = (int*)alloc((size_t)F);
    int* cFpos  = (int*)alloc((size_t)F);
    int* inv    = (int*)alloc((size_t)S*L);
    int* counts = (int*)alloc((size_t)Dn);
    int* offs   = (int*)alloc((size_t)Dn+1);
    int* cursor = (int*)alloc((size_t)Dn);
    int* list   = (int*)alloc((size_t)F);

    const int* det = r_idev;
    auto cvt = [&](const int* src, int* dst, int n){
        k_cvt<<<dim3((n+255)/256),256,0,stream>>>(src, dst, n, det);
    };
    cvt(r_exe,  cExe,  S*2*L);
    cvt(r_idev, cIdev, Dn);
    cvt(r_ifrag,cIfrag,F);
    cvt(r_fdn,  cFdn,  F);
    cvt(r_fdr,  cFdr,  F);
    cvt(r_len,  cLen,  S);
    cvt(r_fsvc, cFsvc, F);
    cvt(r_fpos, cFpos, F);

    k_wt<<<dim3((98304+255)/256),256,0,stream>>>(C_Wih, tCWih, 384, 8, 255, 98304);
    k_wt2<<<dim3((49152+255)/256),256,0,stream>>>(C_Whh, tCWhhHi, tCWhhLo, 384, 7, 127, 49152);
    k_wt<<<dim3((98304+255)/256),256,0,stream>>>(F_Wih, tFWih, 384, 8, 255, 98304);
    k_wt<<<dim3((49152+255)/256),256,0,stream>>>(F_Whh, tFWhh, 384, 7, 127, 49152);
    k_wt<<<dim3((98304+255)/256),256,0,stream>>>(D_Wih, tDWih, 384, 8, 255, 98304);
    k_wt<<<dim3((49152+255)/256),256,0,stream>>>(D_Whh, tDWhh, 384, 7, 127, 49152);
    k_wt<<<dim3((131072+255)/256),256,0,stream>>>(W_tgt, tWtgt, 1024, 7, 127, 131072);
    k_wt<<<dim3((262144+255)/256),256,0,stream>>>(W_src, tWsrc, 1024, 8, 255, 262144);

    hipMemsetAsync(state, 0, (size_t)nodes*128*4, stream);
    hipMemsetAsync(state_bf, 0, (size_t)nodes*128*2, stream);
    hipMemsetAsync(inv, 0xFF, (size_t)S*L*4, stream);
    hipMemsetAsync(counts, 0, (size_t)Dn*4, stream);
    hipMemsetAsync(cursor, 0, (size_t)Dn*4, stream);

    k_proj5<<<dim3((Dn*128+255)/256),256,0,stream>>>(realnode, W_dev, b_dev, cIdev, cIdev,
        state, state_bf, devA, devA_bf, Dn, nreal, nodes);
    k_proj5<<<dim3(((size_t)F*128+255)/256),256,0,stream>>>(realnode, W_frg, b_frg, cIfrag, cIfrag,
        state, state_bf, fragA, fragA_bf, F, nreal, nodes);
    k_proj5<<<dim3((S*128+255)/256),256,0,stream>>>(arr, W_srv, b_srv, nullptr, nullptr,
        h_srv, nullptr, nullptr, nullptr, S, S, nodes);
    k_build_inv<<<dim3((F+255)/256),256,0,stream>>>(cFsvc, cFpos, inv, F, L, S);
    k_count<<<dim3((F+255)/256),256,0,stream>>>(cFdr, counts, F, Dn);
    k_scan<<<1,256,0,stream>>>(counts, offs, Dn);
    k_fill<<<dim3((F+255)/256),256,0,stream>>>(cFdr, offs, cursor, list, F, Dn);

    const int nrF = F/128, nrD = Dn/128;
    for (int it=0; it<NIT; ++it){
        mm2<<<dim3(3*nrF),256,0,stream>>>(state_bf, state_bf, cIfrag, cFdn,
            tCWih, C_bih, giF, F, 384, 256, 0, 1.f, nrF);
        k_recur<<<dim3(S/16),512,0,stream>>>(h_srv, giF, tCWhhHi, tCWhhLo, C_bhh, inv,
            out_f, out_f_bf, S, L, F);
        mm2<<<dim3(8*nrD),256,0,stream>>>(devA_bf, devA_bf, nullptr, nullptr,
            tWtgt, b_tgt, TGT, Dn, 1024, 128, 0, 1.f, nrD);
        mm2<<<dim3(8*nrF),256,0,stream>>>(out_f_bf, fragA_bf, nullptr, nullptr,
            tWsrc, b_src, SRC, F, 1024, 256, 2, 1.f, nrF);
        k_attn<<<dim3(Dn),256,0,stream>>>(SRC, TGT, att, list, offs, bias_att,
            msgDm, msgD_bf, alphaB, Dn, F);
        // F-GRU (pipelined; reads out_f_bf + state_bf[cFdn], in-place fragA)
        k_grufuse<<<dim3(nrF),512,0,stream>>>(out_f_bf, state_bf, nullptr, cFdn, 128,
            tFWih, tFWhh, F_bih, F_bhh, fragA, fragA_bf, state, state_bf, cIfrag, F, nodes);
        // D-GRU (pipelined; A = msgD_bf lda=256, in-place devA)
        k_grufuse<<<dim3(nrD),512,0,stream>>>(msgD_bf, nullptr, nullptr, nullptr, 256,
            tDWih, tDWhh, D_bih, D_bhh, devA, devA_bf, state, state_bf, cIdev, Dn, nodes);
    }

    // readout
    hipMemsetAsync(pooled, 0, (size_t)S*128*4, stream);
    k_pool_add<<<dim3(((size_t)F*128+255)/256),256,0,stream>>>(fragA, cFsvc, pooled, F, S);
    k_pool_div<<<dim3((S*128+255)/256),256,0,stream>>>(pooled, cLen, S);
    k_mm<<<dim3(256/128, S/128),256,0,stream>>>(pooled, 128, Wl1, 256, bl1, TGT, S, 256, 128, 1, 1.f, 0);
    k_mm<<<dim3(256/128, S/128),256,0,stream>>>(TGT, 256, Wl2, 256, bl2, Z, S, 256, 256, 1, 1.f, 0);
    k_dot_out<<<dim3(S),256,0,stream>>>(Z, Wl3, bl3, outp, 0);
    k_mm<<<dim3(256/128, S/128),256,0,stream>>>(h_srv, 128, Wt1, 256, bt1, TGT, S, 256, 128, 1, 1.f, 0);
    k_mm<<<dim3(256/128, S/128),256,0,stream>>>(TGT, 256, Wt2, 256, bt2, Z, S, 256, 256, 1, 1.f, 0);
    k_dot_out<<<dim3(S),256,0,stream>>>(Z, Wt3, bt3, outp, S);
}

// Round 13
// 859.617 us; speedup vs baseline: 1.8371x; 1.1263x over previous
//
#include <hip/hip_runtime.h>
#include <hip/hip_bf16.h>

typedef __attribute__((ext_vector_type(8))) short bf16x8;
typedef __attribute__((ext_vector_type(4))) float f32x4;

__device__ __forceinline__ float sigf(float x){ return 1.0f/(1.0f+expf(-x)); }
__device__ __forceinline__ int clampi(int v, int lo, int hi){ return v<lo?lo:(v>hi?hi:v); }
__device__ __forceinline__ unsigned short f2b(float f){
    __hip_bfloat16 h = __float2bfloat16(f);
    return *reinterpret_cast<unsigned short*>(&h);
}
__device__ __forceinline__ float us2f(unsigned short u){ return __uint_as_float(((unsigned)u)<<16); }

__device__ __forceinline__ void gload16(const void* g, void* l){
    __builtin_amdgcn_global_load_lds((const __attribute__((address_space(1))) void*)g,
                                     (__attribute__((address_space(3))) void*)l, 16, 0, 0);
}

// ---- int64/int32 tolerant index conversion ----
__global__ void k_cvt(const int* __restrict__ src, int* __restrict__ dst, int n,
                      const int* __restrict__ det)
{
    int i = blockIdx.x*blockDim.x + threadIdx.x;
    if (i >= n) return;
    int stride = (det[1] == 0) ? 2 : 1;
    dst[i] = src[(size_t)i*stride];
}

__global__ void k_wt(const float* __restrict__ W, unsigned short* __restrict__ Wt,
                     int N, int kshift, int kmask, int total)
{
    int idx = blockIdx.x*blockDim.x + threadIdx.x;
    if (idx >= total) return;
    int n = idx >> kshift, k = idx & kmask;
    Wt[idx] = f2b(W[(size_t)k*N + n]);
}

__global__ void k_wt2(const float* __restrict__ W, unsigned short* __restrict__ Whi,
                      unsigned short* __restrict__ Wlo, int N, int kshift, int kmask, int total)
{
    int idx = blockIdx.x*blockDim.x + threadIdx.x;
    if (idx >= total) return;
    int n = idx >> kshift, k = idx & kmask;
    float v = W[(size_t)k*N + n];
    unsigned short hi = f2b(v);
    Whi[idx] = hi;
    Wlo[idx] = f2b(v - us2f(hi));
}

// ---------------- init projections ----------------
__global__ void k_proj5(const float* __restrict__ X, const float* __restrict__ W,
                        const float* __restrict__ bias,
                        const int* __restrict__ gidx, const int* __restrict__ sidx,
                        float* __restrict__ out, unsigned short* __restrict__ outBf,
                        float* __restrict__ out2, unsigned short* __restrict__ out2Bf,
                        int M, int nrows, int nodes)
{
    int t = blockIdx.x*blockDim.x + threadIdx.x;
    int i = t >> 7, j = t & 127;
    if (i >= M) return;
    int src = gidx ? clampi(gidx[i]-1, 0, nrows-1) : i;
    const float* xp = X + (size_t)src*5;
    float acc = bias[j];
#pragma unroll
    for (int k=0;k<5;k++) acc += xp[k] * W[k*128+j];
    int dr = sidx ? clampi(sidx[i], 0, nodes-1) : i;
    if (out)   out[(size_t)dr*128 + j] = acc;
    if (outBf) outBf[(size_t)dr*128 + j] = f2b(acc);
    if (out2)  out2[(size_t)i*128 + j] = acc;
    if (out2Bf) out2Bf[(size_t)i*128 + j] = f2b(acc);
}

// ---------------- f32 tiled GEMM (readout heads only) ----------------
__launch_bounds__(256)
__global__ void k_mm(const float* __restrict__ A0, int lda,
                     const float* __restrict__ B, int ldb,
                     const float* __restrict__ bias, float* __restrict__ C,
                     int M, int N, int K, int relu, float scale, int accum)
{
    __shared__ float As[16][132];
    __shared__ float Bs[16][132];
    int tid = threadIdx.x;
    int tx = tid & 15, ty = tid >> 4;
    int row0 = blockIdx.y * 128, col0 = blockIdx.x * 128;
    float acc[8][8] = {};
    for (int k0 = 0; k0 < K; k0 += 16){
#pragma unroll
        for (int q = 0; q < 2; ++q){
            int idx = tid + q*256;
            int r = idx >> 2, k4 = (idx & 3) * 4;
            const float* src = A0 + (size_t)(row0+r)*lda + k0 + k4;
            float4 v = *reinterpret_cast<const float4*>(src);
            As[k4+0][r]=v.x; As[k4+1][r]=v.y; As[k4+2][r]=v.z; As[k4+3][r]=v.w;
        }
#pragma unroll
        for (int q = 0; q < 2; ++q){
            int idx = tid + q*256;
            int kb = idx >> 5, n4 = (idx & 31) * 4;
            float4 v = *reinterpret_cast<const float4*>(B + (size_t)(k0+kb)*ldb + col0 + n4);
            *reinterpret_cast<float4*>(&Bs[kb][n4]) = v;
        }
        __syncthreads();
#pragma unroll
        for (int k = 0; k < 16; ++k){
            float a[8], b[8];
            *(float4*)&a[0] = *(const float4*)&As[k][ty*8];
            *(float4*)&a[4] = *(const float4*)&As[k][ty*8+4];
            *(float4*)&b[0] = *(const float4*)&Bs[k][tx*8];
            *(float4*)&b[4] = *(const float4*)&Bs[k][tx*8+4];
#pragma unroll
            for (int i=0;i<8;i++)
#pragma unroll
                for (int j=0;j<8;j++) acc[i][j] += a[i]*b[j];
        }
        __syncthreads();
    }
    float bb[8];
#pragma unroll
    for (int j=0;j<8;j++) bb[j] = bias ? bias[col0+tx*8+j] : 0.f;
#pragma unroll
    for (int i=0;i<8;i++){
        float* cp = C + (size_t)(row0+ty*8+i)*N + col0 + tx*8;
#pragma unroll
        for (int jq=0;jq<2;jq++){
            float4 prev = accum ? *(const float4*)(cp+jq*4) : make_float4(0,0,0,0);
            float o[4];
#pragma unroll
            for (int c=0;c<4;c++){
                float u = acc[i][jq*4+c] + bb[jq*4+c];
                if (relu) u = fmaxf(u,0.f);
                o[c] = (&prev.x)[c] + scale*u;
            }
            *(float4*)(cp+jq*4) = make_float4(o[0],o[1],o[2],o[3]);
        }
    }
}

// ---------------- pipelined bf16 MFMA GEMM body ----------------
struct MJob {
    const unsigned short *A0, *A1;
    const int *i0, *i1;
    const unsigned short *Wt;
    const float *bias;
    void *C;
    int N, K, epi, nrow;   // epi: 0 f32 out, 2 bf16 out
    float scale;
};

#define MM2_SMEM 67840

__device__ __forceinline__ void mm2_body(const MJob J, int bid, char* smem)
{
    unsigned short* AsB = (unsigned short*)smem;     // 2 x 8192 ushort (32 KB)
    unsigned short* BsB = AsB + 16384;               // 2 x 8192 ushort (32 KB)
    int tid = threadIdx.x;
    int l = tid & 63, w = tid >> 6;
    int wr = w >> 1, wc = w & 1;
    int row0 = (bid % J.nrow) * 128, col0 = (bid / J.nrow) * 128;
    int nK = J.K >> 6;

    f32x4 acc[4][4];
#pragma unroll
    for (int m=0;m<4;m++)
#pragma unroll
        for (int n=0;n<4;n++) acc[m][n] = (f32x4){0.f,0.f,0.f,0.f};

    auto stage = [&](int buf, int k0){
        unsigned short* As = AsB + buf*8192;
        unsigned short* Bs = BsB + buf*8192;
#pragma unroll
        for (int q=0;q<4;q++){
            int slot = q*256 + w*64 + l;
            int r = slot >> 3, c8 = slot & 7;
            int g8 = c8 ^ (r & 7);
            int row; const unsigned short* base; int kl;
            if (k0 < 128){ row = J.i0 ? J.i0[row0+r] : (row0+r); base = J.A0; kl = k0; }
            else         { row = J.i1 ? J.i1[row0+r] : (row0+r); base = J.A1; kl = k0-128; }
            const char* g = (const char*)(base + (size_t)row*128 + kl) + g8*16;
            gload16(g, (void*)&As[(size_t)(q*256 + w*64)*8]);
        }
#pragma unroll
        for (int q=0;q<4;q++){
            int slot = q*256 + w*64 + l;
            int n = slot >> 3, kc = slot & 7;
            int g8 = kc ^ (n & 7);
            const char* g = (const char*)(J.Wt + (size_t)(col0+n)*J.K + k0) + g8*16;
            gload16(g, (void*)&Bs[(size_t)(q*256 + w*64)*8]);
        }
    };

    stage(0, 0);
    __syncthreads();
    for (int ks=0; ks<nK; ++ks){
        int cur = ks & 1;
        if (ks+1 < nK) stage(cur^1, (ks+1)*64);
        unsigned short* As = AsB + cur*8192;
        unsigned short* Bs = BsB + cur*8192;
#pragma unroll
        for (int kk = 0; kk < 2; ++kk){
            int ek = kk*32 + (l >> 4) * 8;
            bf16x8 af[4], bf[4];
#pragma unroll
            for (int m=0;m<4;m++){
                int r = wr*64 + m*16 + (l & 15);
                af[m] = *reinterpret_cast<const bf16x8*>(&As[r*64 + (ek ^ ((r & 7) << 3))]);
            }
#pragma unroll
            for (int n=0;n<4;n++){
                int c = wc*64 + n*16 + (l & 15);
                bf[n] = *reinterpret_cast<const bf16x8*>(&Bs[c*64 + (ek ^ ((c & 7) << 3))]);
            }
#pragma unroll
            for (int m=0;m<4;m++)
#pragma unroll
                for (int n=0;n<4;n++)
                    acc[m][n] = __builtin_amdgcn_mfma_f32_16x16x32_bf16(af[m], bf[n], acc[m][n], 0, 0, 0);
        }
        __syncthreads();
    }

    // epilogue via LDS tile -> coalesced stores
    if (J.epi == 0){
        float* Ct = (float*)smem;   // [128][132]
#pragma unroll
        for (int m=0;m<4;m++){
#pragma unroll
            for (int v=0;v<4;v++){
                int rl = wr*64 + m*16 + (l >> 4)*4 + v;
#pragma unroll
                for (int n=0;n<4;n++){
                    int c = wc*64 + n*16 + (l & 15);
                    Ct[rl*132 + c] = J.scale*acc[m][n][v] + (J.bias ? J.bias[col0+c] : 0.f);
                }
            }
        }
        __syncthreads();
#pragma unroll
        for (int q=0;q<16;q++){
            int idx = tid + q*256;
            int r = idx >> 5, c4 = (idx & 31)*4;
            float4 v = *reinterpret_cast<const float4*>(&Ct[r*132 + c4]);
            *reinterpret_cast<float4*>((float*)J.C + (size_t)(row0+r)*J.N + col0 + c4) = v;
        }
    } else {
        unsigned short* Cb = (unsigned short*)smem;  // [128][136]
#pragma unroll
        for (int m=0;m<4;m++){
#pragma unroll
            for (int v=0;v<4;v++){
                int rl = wr*64 + m*16 + (l >> 4)*4 + v;
#pragma unroll
                for (int n=0;n<4;n++){
                    int c = wc*64 + n*16 + (l & 15);
                    Cb[rl*136 + c] = f2b(J.scale*acc[m][n][v] + (J.bias ? J.bias[col0+c] : 0.f));
                }
            }
        }
        __syncthreads();
#pragma unroll
        for (int q=0;q<8;q++){
            int idx = tid + q*256;
            int r = idx >> 4, c8 = (idx & 15)*8;
            uint4 v = *reinterpret_cast<const uint4*>(&Cb[r*136 + c8]);
            *reinterpret_cast<uint4*>((unsigned short*)J.C + (size_t)(row0+r)*J.N + col0 + c8) = v;
        }
    }
}

__launch_bounds__(256)
__global__ void mm2one(MJob a)
{
    __shared__ alignas(16) char smem[MM2_SMEM];
    mm2_body(a, blockIdx.x, smem);
}

__launch_bounds__(256)
__global__ void mm2two(MJob a, MJob b, int asplit)
{
    __shared__ alignas(16) char smem[MM2_SMEM];
    int bid = blockIdx.x;
    if (bid < asplit) mm2_body(a, bid, smem);
    else              mm2_body(b, bid - asplit, smem);
}

// ---------------- fully fused GRU body ----------------
struct GJob {
    const unsigned short *A0, *A1;
    const int *i0, *i1;
    int lda;
    const unsigned short *Wih, *Whh;
    const float *bih, *bhh;
    float *H;
    unsigned short *Hbf, *stateBf;
    const int *sidx;
    int M, nodes;
};

__device__ __forceinline__ void gru_body(const GJob J, int bid, unsigned short* AsB, unsigned short* BsB)
{
    int tid = threadIdx.x;
    int l = tid & 63, w = tid >> 6;
    int row0 = bid * 128;
    f32x4 acc[24], accN[8];
#pragma unroll
    for (int n=0;n<24;n++) acc[n] = (f32x4){0.f,0.f,0.f,0.f};
#pragma unroll
    for (int n=0;n<8;n++) accN[n] = (f32x4){0.f,0.f,0.f,0.f};

    auto stage = [&](int buf, int st){
        int k0 = st*64;
        unsigned short* As = AsB + buf*8192;
        unsigned short* Bs = BsB + buf*24576;
#pragma unroll
        for (int q=0;q<2;q++){
            int slot = q*512 + w*64 + l;
            int r = slot >> 3, c8 = slot & 7;
            int g8 = c8 ^ (r & 7);
            const unsigned short* src;
            if (st < 4){
                if (J.i1){
                    if (k0 < 128){ int ri = J.i0 ? J.i0[row0+r] : (row0+r); src = J.A0 + (size_t)ri*128 + k0; }
                    else         { int ri = J.i1[row0+r]; src = J.A1 + (size_t)ri*128 + (k0-128); }
                } else {
                    src = J.A0 + (size_t)(row0+r)*J.lda + k0;
                }
            } else {
                src = J.Hbf + (size_t)(row0+r)*128 + (k0-256);
            }
            gload16((const char*)src + g8*16, (void*)&As[(size_t)(q*512 + w*64)*8]);
        }
#pragma unroll
        for (int q=0;q<6;q++){
            int slot = q*512 + w*64 + l;
            int n = slot >> 3, kc = slot & 7;
            int g8 = kc ^ (n & 7);
            const unsigned short* src = (st < 4) ? (J.Wih + (size_t)n*256 + k0)
                                                 : (J.Whh + (size_t)n*128 + (k0-256));
            gload16((const char*)src + g8*16, (void*)&Bs[(size_t)(q*512 + w*64)*8]);
        }
    };

    stage(0, 0);
    __syncthreads();
    for (int st=0; st<4; ++st){
        int cur = st & 1;
        stage(cur^1, st+1);
        unsigned short* As = AsB + cur*8192;
        unsigned short* Bs = BsB + cur*24576;
#pragma unroll
        for (int kk=0; kk<2; ++kk){
            int ek = kk*32 + (l >> 4)*8;
            int r = w*16 + (l & 15);
            bf16x8 af = *reinterpret_cast<const bf16x8*>(&As[r*64 + (ek ^ ((r & 7) << 3))]);
#pragma unroll
            for (int n=0;n<24;n++){
                int c = n*16 + (l & 15);
                bf16x8 bf = *reinterpret_cast<const bf16x8*>(&Bs[c*64 + (ek ^ ((c & 7) << 3))]);
                acc[n] = __builtin_amdgcn_mfma_f32_16x16x32_bf16(af, bf, acc[n], 0, 0, 0);
            }
        }
        __syncthreads();
    }
    for (int st=4; st<6; ++st){
        int cur = st & 1;
        if (st+1 < 6) stage(cur^1, st+1);
        unsigned short* As = AsB + cur*8192;
        unsigned short* Bs = BsB + cur*24576;
#pragma unroll
        for (int kk=0; kk<2; ++kk){
            int ek = kk*32 + (l >> 4)*8;
            int r = w*16 + (l & 15);
            bf16x8 af = *reinterpret_cast<const bf16x8*>(&As[r*64 + (ek ^ ((r & 7) << 3))]);
#pragma unroll
            for (int n=0;n<24;n++){
                int c = n*16 + (l & 15);
                bf16x8 bf = *reinterpret_cast<const bf16x8*>(&Bs[c*64 + (ek ^ ((c & 7) << 3))]);
                if (n < 16) acc[n]     = __builtin_amdgcn_mfma_f32_16x16x32_bf16(af, bf, acc[n], 0, 0, 0);
                else        accN[n-16] = __builtin_amdgcn_mfma_f32_16x16x32_bf16(af, bf, accN[n-16], 0, 0, 0);
            }
        }
        __syncthreads();
    }
#pragma unroll
    for (int v=0;v<4;v++){
        int row = row0 + w*16 + (l >> 4)*4 + v;
        int st = clampi(J.sidx[row],0,J.nodes-1);
#pragma unroll
        for (int c=0;c<8;c++){
            int col = c*16 + (l & 15);
            float rr = sigf(acc[c][v]    + J.bih[col]     + J.bhh[col]);
            float zz = sigf(acc[c+8][v]  + J.bih[col+128] + J.bhh[col+128]);
            float nn = tanhf(acc[c+16][v] + J.bih[col+256] + rr*(accN[c][v] + J.bhh[col+256]));
            float hv = J.H[(size_t)row*128 + col];
            float hn = (1.f-zz)*nn + zz*hv;
            unsigned short hb = f2b(hn);
            J.H[(size_t)row*128 + col] = hn;
            J.Hbf[(size_t)row*128 + col] = hb;
            J.stateBf[(size_t)st*128 + col] = hb;
        }
    }
}

__launch_bounds__(512)
__global__ void gru2(GJob a, GJob b, int asplit)
{
    __shared__ alignas(16) unsigned short AsB[2*8192];
    __shared__ alignas(16) unsigned short BsB[2*24576];
    int bid = blockIdx.x;
    if (bid < asplit) gru_body(a, bid, AsB, BsB);
    else              gru_body(b, bid - asplit, AsB, BsB);
}

// ---------------- fused GAT attention (bf16 tgt, bf16 msgD out) ----------------
__launch_bounds__(256)
__global__ void k_attn(const unsigned short* __restrict__ SRC, const unsigned short* __restrict__ tgtbf,
                       const float* __restrict__ att, const int* __restrict__ list,
                       const int* __restrict__ offs, const float* __restrict__ batt,
                       unsigned short* __restrict__ msgDbf,
                       float* __restrict__ alphaG, int Dn, int F)
{
    __shared__ float tg[1024];
    __shared__ float alds[128*4];
    __shared__ float accs[4][256];
    int d = blockIdx.x;
    int tid = threadIdx.x;
    int w = tid >> 6, lane = tid & 63;
    for (int u = tid; u < 1024; u += 256) tg[u] = us2f(tgtbf[(size_t)d*1024 + u]);
    __syncthreads();
    int beg = offs[d], end = offs[d+1];
    if (beg < 0) beg = 0; if (end > F) end = F; if (end < beg) end = beg;
    int c0 = w*256 + lane*4;
    float t0 = tg[c0], t1 = tg[c0+1], t2 = tg[c0+2], t3 = tg[c0+3];
    float a0 = att[c0], a1 = att[c0+1], a2 = att[c0+2], a3 = att[c0+3];
    float amax = -3.4e38f;
    for (int i=beg;i<end;i++){
        int f = list[i];
        ushort4 sv = *reinterpret_cast<const ushort4*>(SRC + (size_t)f*1024 + c0);
        float e0 = us2f(sv.x)+t0, e1 = us2f(sv.y)+t1, e2 = us2f(sv.z)+t2, e3 = us2f(sv.w)+t3;
        e0 = e0>0.f?e0:0.2f*e0; e1 = e1>0.f?e1:0.2f*e1;
        e2 = e2>0.f?e2:0.2f*e2; e3 = e3>0.f?e3:0.2f*e3;
        float s = e0*a0 + e1*a1 + e2*a2 + e3*a3;
#pragma unroll
        for (int msk=1; msk<64; msk<<=1) s += __shfl_xor(s, msk);
        int li = i - beg;
        if (li < 128){ if (lane == 0) alds[li*4+w] = s; }
        else         { if (lane == 0) alphaG[(size_t)f*4+w] = s; }
        amax = fmaxf(amax, s);
    }
    __syncthreads();
    float wsum = 0.f;
    for (int i=beg;i<end;i++){
        int li = i - beg;
        float a = (li < 128) ? alds[li*4+w] : alphaG[(size_t)list[i]*4+w];
        wsum += expf(a - amax);
    }
    float iws = 1.f/(wsum + 1e-16f);
    float acc[4] = {0,0,0,0};
    for (int i=beg;i<end;i++){
        int f = list[i];
        int li = i - beg;
        float a = (li < 128) ? alds[li*4+w] : alphaG[(size_t)f*4+w];
        float p = expf(a - amax)*iws;
        ushort4 sv = *reinterpret_cast<const ushort4*>(SRC + (size_t)f*1024 + c0);
        acc[0] += p*us2f(sv.x); acc[1] += p*us2f(sv.y);
        acc[2] += p*us2f(sv.z); acc[3] += p*us2f(sv.w);
    }
#pragma unroll
    for (int j=0;j<4;j++) accs[w][lane*4+j] = acc[j];
    __syncthreads();
    if (tid < 256){
        float m = (accs[0][tid]+accs[1][tid]+accs[2][tid]+accs[3][tid])*0.25f + batt[tid];
        msgDbf[(size_t)d*256 + tid] = f2b(m);
    }
}

// ---------------- fused phiC recurrence ----------------
__launch_bounds__(512)
__global__ void k_recur(float* __restrict__ h_srv, const float* __restrict__ giF,
                        const unsigned short* __restrict__ Whi,
                        const unsigned short* __restrict__ Wlo,
                        const float* __restrict__ bhh,
                        const int* __restrict__ inv,
                        unsigned short* __restrict__ out_f_bf,
                        int S, int L, int F)
{
    __shared__ float hs[16][129];
    __shared__ alignas(16) unsigned short hsHi[16*128];
    __shared__ alignas(16) unsigned short hsLo[16*128];
    __shared__ float ghs[16][385];
    __shared__ int fLoc[16][16];
    int tid = threadIdx.x;
    int l = tid & 63, w = tid >> 6;
    int lane15 = l & 15, lhi = l >> 4;
    int s0 = blockIdx.x * 16;
    for (int u = tid; u < 2048; u += 512){
        int s=u>>7,k=u&127;
        float v = h_srv[(size_t)(s0+s)*128+k];
        hs[s][k] = v;
        unsigned short hb = f2b(v);
        int ksw = k ^ ((s & 7) << 3);
        hsHi[s*128 + ksw] = hb;
        hsLo[s*128 + ksw] = f2b(v - us2f(hb));
    }
    if (tid < 256) fLoc[tid>>4][tid&15] = inv[(size_t)(s0+(tid&15))*L + (tid>>4)];
    bf16x8 wHi[3][4], wLo[3][4];
#pragma unroll
    for (int ct=0; ct<3; ++ct){
        int col = w*48 + ct*16 + lane15;
#pragma unroll
        for (int ks=0; ks<4; ++ks){
            size_t off = (size_t)col*128 + ks*32 + lhi*8;
            wHi[ct][ks] = *reinterpret_cast<const bf16x8*>(Whi + off);
            wLo[ct][ks] = *reinterpret_cast<const bf16x8*>(Wlo + off);
        }
    }
    __syncthreads();
    for (int t=0;t<L;++t){
        bf16x8 hHi[4], hLo[4];
#pragma unroll
        for (int ks=0; ks<4; ++ks){
            int ek = ks*32 + lhi*8;
            int off = lane15*128 + (ek ^ ((lane15 & 7) << 3));
            hHi[ks] = *reinterpret_cast<const bf16x8*>(&hsHi[off]);
            hLo[ks] = *reinterpret_cast<const bf16x8*>(&hsLo[off]);
        }
#pragma unroll
        for (int ct=0; ct<3; ++ct){
            f32x4 acc = (f32x4){0.f,0.f,0.f,0.f};
#pragma unroll
            for (int ks=0; ks<4; ++ks){
                acc = __builtin_amdgcn_mfma_f32_16x16x32_bf16(hHi[ks], wHi[ct][ks], acc, 0,0,0);
                acc = __builtin_amdgcn_mfma_f32_16x16x32_bf16(hLo[ks], wHi[ct][ks], acc, 0,0,0);
                acc = __builtin_amdgcn_mfma_f32_16x16x32_bf16(hHi[ks], wLo[ct][ks], acc, 0,0,0);
            }
            int col = w*48 + ct*16 + lane15;
            float bb = bhh[col];
#pragma unroll
            for (int v=0; v<4; ++v){
                ghs[lhi*4 + v][col] = acc[v] + bb;
            }
        }
        __syncthreads();
        for (int u = tid; u < 2048; u += 512){
            int s=u>>7, k=u&127; int f = fLoc[t][s];
            if (f >= 0 && f < F){
                const float* gp = giF + (size_t)f*384;
                float r  = sigf(gp[k]     + ghs[s][k]);
                float zz = sigf(gp[128+k] + ghs[s][128+k]);
                float n  = tanhf(gp[256+k] + r*ghs[s][256+k]);
                float hn = (1.f-zz)*n + zz*hs[s][k];
                hs[s][k] = hn;
                unsigned short hb = f2b(hn);
                int ksw = k ^ ((s & 7) << 3);
                hsHi[s*128 + ksw] = hb;
                hsLo[s*128 + ksw] = f2b(hn - us2f(hb));
                out_f_bf[(size_t)f*128+k] = hb;
            }
        }
        __syncthreads();
    }
    for (int u = tid; u < 2048; u += 512){ int s=u>>7,k=u&127; h_srv[(size_t)(s0+s)*128+k] = hs[s][k]; }
}

__global__ void k_count(const int* __restrict__ row, int* __restrict__ counts, int F, int Dn)
{ int f = blockIdx.x*blockDim.x + threadIdx.x; if (f < F) atomicAdd(&counts[clampi(row[f],0,Dn-1)], 1); }

__global__ void k_scan(const int* __restrict__ counts, int* __restrict__ offs, int D)
{
    __shared__ int part[257];
    int tid = threadIdx.x;
    int per = (D + 255) / 256;
    int s = 0;
    for (int i=0;i<per;i++){ int idx = tid*per+i; if (idx < D) s += counts[idx]; }
    part[tid] = s;
    __syncthreads();
    if (tid == 0){
        int acc = 0;
        for (int i=0;i<256;i++){ int v = part[i]; part[i] = acc; acc += v; }
        part[256] = acc;
    }
    __syncthreads();
    int acc = part[tid];
    for (int i=0;i<per;i++){ int idx = tid*per+i; if (idx < D){ offs[idx] = acc; acc += counts[idx]; } }
    if (tid == 0) offs[D] = part[256];
}

__global__ void k_fill(const int* __restrict__ row, const int* __restrict__ offs,
                       int* __restrict__ cursor, int* __restrict__ list, int F, int Dn)
{
    int f = blockIdx.x*blockDim.x + threadIdx.x;
    if (f >= F) return;
    int r = clampi(row[f],0,Dn-1);
    int p = atomicAdd(&cursor[r], 1);
    int pos = offs[r]+p;
    if (pos >= 0 && pos < F) list[pos] = f;
}

__global__ void k_build_inv(const int* __restrict__ fs, const int* __restrict__ fp,
                            int* __restrict__ inv, int F, int L, int S)
{
    int f = blockIdx.x*blockDim.x + threadIdx.x;
    if (f >= F) return;
    inv[clampi(fs[f],0,S-1)*L + clampi(fp[f],0,L-1)] = f;
}

__global__ void k_pool_add(const float* __restrict__ frag, const int* __restrict__ fs,
                           float* __restrict__ pooled, int F, int S)
{
    int t = blockIdx.x*blockDim.x + threadIdx.x;
    int i = t >> 7, j = t & 127;
    if (i >= F) return;
    atomicAdd(&pooled[(size_t)clampi(fs[i],0,S-1)*128 + j], frag[(size_t)i*128 + j]);
}

__global__ void k_pool_div(float* __restrict__ pooled, const int* __restrict__ lengths, int S)
{
    int t = blockIdx.x*blockDim.x + threadIdx.x;
    int i = t >> 7, j = t & 127;
    if (i >= S) return;
    int l = lengths[i]; if (l < 1) l = 1;
    pooled[(size_t)i*128 + j] /= (float)l;
}

__global__ void k_dot_out(const float* __restrict__ H, const float* __restrict__ W3,
                          const float* __restrict__ b3, float* __restrict__ outv, int off)
{
    __shared__ float red[256];
    int s = blockIdx.x, tid = threadIdx.x;
    red[tid] = H[(size_t)s*256 + tid] * W3[tid];
    __syncthreads();
    for (int st=128; st; st>>=1){ if (tid < st) red[tid] += red[tid+st]; __syncthreads(); }
    if (tid == 0) outv[off + s] = red[0] + b3[0];
}

// =====================================================================================
extern "C" void kernel_launch(void* const* d_in, const int* in_sizes, int n_in,
                              void* d_out, int out_size, void* d_ws, size_t ws_size,
                              hipStream_t stream)
{
    (void)n_in; (void)out_size; (void)ws_size;
    const float* realnode = (const float*)d_in[0];
    const float* arr      = (const float*)d_in[1];
    const int* r_exe   = (const int*)d_in[2];
    const int* r_idev  = (const int*)d_in[3];
    const int* r_ifrag = (const int*)d_in[4];
    const int* r_fdn   = (const int*)d_in[5];
    const int* r_fdr   = (const int*)d_in[6];
    const int* r_len   = (const int*)d_in[7];
    const int* r_fsvc  = (const int*)d_in[8];
    const int* r_fpos  = (const int*)d_in[9];
    const float *W_dev=(const float*)d_in[10], *b_dev=(const float*)d_in[11];
    const float *W_frg=(const float*)d_in[12], *b_frg=(const float*)d_in[13];
    const float *W_srv=(const float*)d_in[14], *b_srv=(const float*)d_in[15];
    const float *C_Wih=(const float*)d_in[16], *C_Whh=(const float*)d_in[17], *C_bih=(const float*)d_in[18], *C_bhh=(const float*)d_in[19];
    const float *F_Wih=(const float*)d_in[20], *F_Whh=(const float*)d_in[21], *F_bih=(const float*)d_in[22], *F_bhh=(const float*)d_in[23];
    const float *D_Wih=(const float*)d_in[24], *D_Whh=(const float*)d_in[25], *D_bih=(const float*)d_in[26], *D_bhh=(const float*)d_in[27];
    const float *W_src=(const float*)d_in[28], *b_src=(const float*)d_in[29];
    const float *W_tgt=(const float*)d_in[30], *b_tgt=(const float*)d_in[31];
    const float *att=(const float*)d_in[32], *bias_att=(const float*)d_in[33];
    const float *Wt1=(const float*)d_in[34], *bt1=(const float*)d_in[35], *Wt2=(const float*)d_in[36], *bt2=(const float*)d_in[37], *Wt3=(const float*)d_in[38], *bt3=(const float*)d_in[39];
    const float *Wl1=(const float*)d_in[40], *bl1=(const float*)d_in[41], *Wl2=(const float*)d_in[42], *bl2=(const float*)d_in[43], *Wl3=(const float*)d_in[44], *bl3=(const float*)d_in[45];
    float* outp = (float*)d_out;

    const int S  = in_sizes[7];
    const int Dn = in_sizes[3];
    const int F  = in_sizes[4];
    const int L  = in_sizes[2] / (2*S);
    const int nreal = in_sizes[0]/5;
    const int nodes = nreal + 1;
    const int NIT = 3;

    char* wp = (char*)d_ws;
    auto alloc = [&](size_t nelem)->float*{
        float* p = (float*)wp;
        wp += ((nelem*4 + 255)/256)*256;
        return p;
    };
    float* h_srv  = alloc((size_t)S*128);
    float* fragA  = alloc((size_t)F*128);
    float* devA   = alloc((size_t)Dn*128);
    float* alphaB = alloc((size_t)F*4);
    float* UNION  = alloc((size_t)F*512);     // giF f32 / SRC bf16
    float* giF    = UNION;
    unsigned short* SRC = (unsigned short*)UNION;
    float* Z      = alloc((size_t)Dn*1024);   // readout h2
    float* TGTf   = alloc((size_t)Dn*512);    // TGT bf16 region
    unsigned short* TGT = (unsigned short*)TGTf;
    float* pooled = alloc((size_t)S*128);
    unsigned short* state_bf = (unsigned short*)alloc((size_t)nodes*64);
    unsigned short* out_f_bf = (unsigned short*)alloc((size_t)F*64);
    unsigned short* fragA_bf = (unsigned short*)alloc((size_t)F*64);
    unsigned short* devA_bf  = (unsigned short*)alloc((size_t)Dn*64);
    unsigned short* msgD_bf  = (unsigned short*)alloc((size_t)Dn*128);
    unsigned short* tCWih   = (unsigned short*)alloc(384*256/2);
    unsigned short* tCWhhHi = (unsigned short*)alloc(384*128/2);
    unsigned short* tCWhhLo = (unsigned short*)alloc(384*128/2);
    unsigned short* tFWih   = (unsigned short*)alloc(384*256/2);
    unsigned short* tFWhh   = (unsigned short*)alloc(384*128/2);
    unsigned short* tDWih   = (unsigned short*)alloc(384*256/2);
    unsigned short* tDWhh   = (unsigned short*)alloc(384*128/2);
    unsigned short* tWtgt   = (unsigned short*)alloc(1024*128/2);
    unsigned short* tWsrc   = (unsigned short*)alloc(1024*256/2);
    int* cExe   = (int*)alloc((size_t)S*2*L);
    int* cIdev  = (int*)alloc((size_t)Dn);
    int* cIfrag = (int*)alloc((size_t)F);
    int* cFdn   = (int*)alloc((size_t)F);
    int* cFdr   = (int*)alloc((size_t)F);
    int* cLen   = (int*)alloc((size_t)S);
    int* cFsvc  = (int*)alloc((size_t)F);
    int* cFpos  = (int*)alloc((size_t)F);
    int* inv    = (int*)alloc((size_t)S*L);
    int* counts = (int*)alloc((size_t)Dn);
    int* offs   = (int*)alloc((size_t)Dn+1);
    int* cursor = (int*)alloc((size_t)Dn);
    int* list   = (int*)alloc((size_t)F);

    const int* det = r_idev;
    auto cvt = [&](const int* src, int* dst, int n){
        k_cvt<<<dim3((n+255)/256),256,0,stream>>>(src, dst, n, det);
    };
    cvt(r_exe,  cExe,  S*2*L);
    cvt(r_idev, cIdev, Dn);
    cvt(r_ifrag,cIfrag,F);
    cvt(r_fdn,  cFdn,  F);
    cvt(r_fdr,  cFdr,  F);
    cvt(r_len,  cLen,  S);
    cvt(r_fsvc, cFsvc, F);
    cvt(r_fpos, cFpos, F);

    k_wt<<<dim3((98304+255)/256),256,0,stream>>>(C_Wih, tCWih, 384, 8, 255, 98304);
    k_wt2<<<dim3((49152+255)/256),256,0,stream>>>(C_Whh, tCWhhHi, tCWhhLo, 384, 7, 127, 49152);
    k_wt<<<dim3((98304+255)/256),256,0,stream>>>(F_Wih, tFWih, 384, 8, 255, 98304);
    k_wt<<<dim3((49152+255)/256),256,0,stream>>>(F_Whh, tFWhh, 384, 7, 127, 49152);
    k_wt<<<dim3((98304+255)/256),256,0,stream>>>(D_Wih, tDWih, 384, 8, 255, 98304);
    k_wt<<<dim3((49152+255)/256),256,0,stream>>>(D_Whh, tDWhh, 384, 7, 127, 49152);
    k_wt<<<dim3((131072+255)/256),256,0,stream>>>(W_tgt, tWtgt, 1024, 7, 127, 131072);
    k_wt<<<dim3((262144+255)/256),256,0,stream>>>(W_src, tWsrc, 1024, 8, 255, 262144);

    hipMemsetAsync(state_bf, 0, (size_t)nodes*128*2, stream);
    hipMemsetAsync(inv, 0xFF, (size_t)S*L*4, stream);
    hipMemsetAsync(counts, 0, (size_t)Dn*4, stream);
    hipMemsetAsync(cursor, 0, (size_t)Dn*4, stream);

    k_proj5<<<dim3((Dn*128+255)/256),256,0,stream>>>(realnode, W_dev, b_dev, cIdev, cIdev,
        nullptr, state_bf, devA, devA_bf, Dn, nreal, nodes);
    k_proj5<<<dim3(((size_t)F*128+255)/256),256,0,stream>>>(realnode, W_frg, b_frg, cIfrag, cIfrag,
        nullptr, state_bf, fragA, fragA_bf, F, nreal, nodes);
    k_proj5<<<dim3((S*128+255)/256),256,0,stream>>>(arr, W_srv, b_srv, nullptr, nullptr,
        h_srv, nullptr, nullptr, nullptr, S, S, nodes);
    k_build_inv<<<dim3((F+255)/256),256,0,stream>>>(cFsvc, cFpos, inv, F, L, S);
    k_count<<<dim3((F+255)/256),256,0,stream>>>(cFdr, counts, F, Dn);
    k_scan<<<1,256,0,stream>>>(counts, offs, Dn);
    k_fill<<<dim3((F+255)/256),256,0,stream>>>(cFdr, offs, cursor, list, F, Dn);

    const int nrF = F/128, nrD = Dn/128;
    MJob jGi  = { state_bf, state_bf, cIfrag, cFdn, tCWih, C_bih, giF, 384, 256, 0, nrF, 1.f };
    MJob jTgt = { devA_bf, devA_bf, nullptr, nullptr, tWtgt, b_tgt, TGT, 1024, 128, 2, nrD, 1.f };
    MJob jSrc = { out_f_bf, fragA_bf, nullptr, nullptr, tWsrc, b_src, SRC, 1024, 256, 2, nrF, 1.f };
    GJob jF = { out_f_bf, state_bf, nullptr, cFdn, 128, tFWih, tFWhh, F_bih, F_bhh,
                fragA, fragA_bf, state_bf, cIfrag, F, nodes };
    GJob jD = { msgD_bf, nullptr, nullptr, nullptr, 256, tDWih, tDWhh, D_bih, D_bhh,
                devA, devA_bf, state_bf, cIdev, Dn, nodes };

    for (int it=0; it<NIT; ++it){
        mm2two<<<dim3(3*nrF + 8*nrD),256,0,stream>>>(jGi, jTgt, 3*nrF);
        k_recur<<<dim3(S/16),512,0,stream>>>(h_srv, giF, tCWhhHi, tCWhhLo, C_bhh, inv,
            out_f_bf, S, L, F);
        mm2one<<<dim3(8*nrF),256,0,stream>>>(jSrc);
        k_attn<<<dim3(Dn),256,0,stream>>>(SRC, TGT, att, list, offs, bias_att,
            msgD_bf, alphaB, Dn, F);
        gru2<<<dim3(nrF + nrD),512,0,stream>>>(jF, jD, nrF);
    }

    // readout
    hipMemsetAsync(pooled, 0, (size_t)S*128*4, stream);
    k_pool_add<<<dim3(((size_t)F*128+255)/256),256,0,stream>>>(fragA, cFsvc, pooled, F, S);
    k_pool_div<<<dim3((S*128+255)/256),256,0,stream>>>(pooled, cLen, S);
    float* h1 = (float*)TGTf;   // reuse TGT region post-loop (Dn*512 floats >= S*256)
    k_mm<<<dim3(256/128, S/128),256,0,stream>>>(pooled, 128, Wl1, 256, bl1, h1, S, 256, 128, 1, 1.f, 0);
    k_mm<<<dim3(256/128, S/128),256,0,stream>>>(h1, 256, Wl2, 256, bl2, Z, S, 256, 256, 1, 1.f, 0);
    k_dot_out<<<dim3(S),256,0,stream>>>(Z, Wl3, bl3, outp, 0);
    k_mm<<<dim3(256/128, S/128),256,0,stream>>>(h_srv, 128, Wt1, 256, bt1, h1, S, 256, 128, 1, 1.f, 0);
    k_mm<<<dim3(256/128, S/128),256,0,stream>>>(h1, 256, Wt2, 256, bt2, Z, S, 256, 256, 1, 1.f, 0);
    k_dot_out<<<dim3(S),256,0,stream>>>(Z, Wt3, bt3, outp, S);
}

// Round 14
// 801.793 us; speedup vs baseline: 1.9696x; 1.0721x over previous
//
#include <hip/hip_runtime.h>
#include <hip/hip_bf16.h>

typedef __attribute__((ext_vector_type(8))) short bf16x8;
typedef __attribute__((ext_vector_type(4))) float f32x4;

__device__ __forceinline__ float sigf(float x){ return 1.0f/(1.0f+expf(-x)); }
__device__ __forceinline__ int clampi(int v, int lo, int hi){ return v<lo?lo:(v>hi?hi:v); }
__device__ __forceinline__ unsigned short f2b(float f){
    __hip_bfloat16 h = __float2bfloat16(f);
    return *reinterpret_cast<unsigned short*>(&h);
}
__device__ __forceinline__ float us2f(unsigned short u){ return __uint_as_float(((unsigned)u)<<16); }

__device__ __forceinline__ void gload16(const void* g, void* l){
    __builtin_amdgcn_global_load_lds((const __attribute__((address_space(1))) void*)g,
                                     (__attribute__((address_space(3))) void*)l, 16, 0, 0);
}

// ---- int64/int32 tolerant index conversion ----
__global__ void k_cvt(const int* __restrict__ src, int* __restrict__ dst, int n,
                      const int* __restrict__ det)
{
    int i = blockIdx.x*blockDim.x + threadIdx.x;
    if (i >= n) return;
    int stride = (det[1] == 0) ? 2 : 1;
    dst[i] = src[(size_t)i*stride];
}

__global__ void k_wt(const float* __restrict__ W, unsigned short* __restrict__ Wt,
                     int N, int kshift, int kmask, int total)
{
    int idx = blockIdx.x*blockDim.x + threadIdx.x;
    if (idx >= total) return;
    int n = idx >> kshift, k = idx & kmask;
    Wt[idx] = f2b(W[(size_t)k*N + n]);
}

__global__ void k_wt2(const float* __restrict__ W, unsigned short* __restrict__ Whi,
                      unsigned short* __restrict__ Wlo, int N, int kshift, int kmask, int total)
{
    int idx = blockIdx.x*blockDim.x + threadIdx.x;
    if (idx >= total) return;
    int n = idx >> kshift, k = idx & kmask;
    float v = W[(size_t)k*N + n];
    unsigned short hi = f2b(v);
    Whi[idx] = hi;
    Wlo[idx] = f2b(v - us2f(hi));
}

// ---------------- init projections ----------------
__global__ void k_proj5(const float* __restrict__ X, const float* __restrict__ W,
                        const float* __restrict__ bias,
                        const int* __restrict__ gidx, const int* __restrict__ sidx,
                        float* __restrict__ out, unsigned short* __restrict__ outBf,
                        float* __restrict__ out2, unsigned short* __restrict__ out2Bf,
                        int M, int nrows, int nodes)
{
    int t = blockIdx.x*blockDim.x + threadIdx.x;
    int i = t >> 7, j = t & 127;
    if (i >= M) return;
    int src = gidx ? clampi(gidx[i]-1, 0, nrows-1) : i;
    const float* xp = X + (size_t)src*5;
    float acc = bias[j];
#pragma unroll
    for (int k=0;k<5;k++) acc += xp[k] * W[k*128+j];
    int dr = sidx ? clampi(sidx[i], 0, nodes-1) : i;
    if (out)   out[(size_t)dr*128 + j] = acc;
    if (outBf) outBf[(size_t)dr*128 + j] = f2b(acc);
    if (out2)  out2[(size_t)i*128 + j] = acc;
    if (out2Bf) out2Bf[(size_t)i*128 + j] = f2b(acc);
}

// ---------------- f32 tiled GEMM (readout heads only) ----------------
__launch_bounds__(256)
__global__ void k_mm(const float* __restrict__ A0, int lda,
                     const float* __restrict__ B, int ldb,
                     const float* __restrict__ bias, float* __restrict__ C,
                     int M, int N, int K, int relu, float scale, int accum)
{
    __shared__ float As[16][132];
    __shared__ float Bs[16][132];
    int tid = threadIdx.x;
    int tx = tid & 15, ty = tid >> 4;
    int row0 = blockIdx.y * 128, col0 = blockIdx.x * 128;
    float acc[8][8] = {};
    for (int k0 = 0; k0 < K; k0 += 16){
#pragma unroll
        for (int q = 0; q < 2; ++q){
            int idx = tid + q*256;
            int r = idx >> 2, k4 = (idx & 3) * 4;
            const float* src = A0 + (size_t)(row0+r)*lda + k0 + k4;
            float4 v = *reinterpret_cast<const float4*>(src);
            As[k4+0][r]=v.x; As[k4+1][r]=v.y; As[k4+2][r]=v.z; As[k4+3][r]=v.w;
        }
#pragma unroll
        for (int q = 0; q < 2; ++q){
            int idx = tid + q*256;
            int kb = idx >> 5, n4 = (idx & 31) * 4;
            float4 v = *reinterpret_cast<const float4*>(B + (size_t)(k0+kb)*ldb + col0 + n4);
            *reinterpret_cast<float4*>(&Bs[kb][n4]) = v;
        }
        __syncthreads();
#pragma unroll
        for (int k = 0; k < 16; ++k){
            float a[8], b[8];
            *(float4*)&a[0] = *(const float4*)&As[k][ty*8];
            *(float4*)&a[4] = *(const float4*)&As[k][ty*8+4];
            *(float4*)&b[0] = *(const float4*)&Bs[k][tx*8];
            *(float4*)&b[4] = *(const float4*)&Bs[k][tx*8+4];
#pragma unroll
            for (int i=0;i<8;i++)
#pragma unroll
                for (int j=0;j<8;j++) acc[i][j] += a[i]*b[j];
        }
        __syncthreads();
    }
    float bb[8];
#pragma unroll
    for (int j=0;j<8;j++) bb[j] = bias ? bias[col0+tx*8+j] : 0.f;
#pragma unroll
    for (int i=0;i<8;i++){
        float* cp = C + (size_t)(row0+ty*8+i)*N + col0 + tx*8;
#pragma unroll
        for (int jq=0;jq<2;jq++){
            float4 prev = accum ? *(const float4*)(cp+jq*4) : make_float4(0,0,0,0);
            float o[4];
#pragma unroll
            for (int c=0;c<4;c++){
                float u = acc[i][jq*4+c] + bb[jq*4+c];
                if (relu) u = fmaxf(u,0.f);
                o[c] = (&prev.x)[c] + scale*u;
            }
            *(float4*)(cp+jq*4) = make_float4(o[0],o[1],o[2],o[3]);
        }
    }
}

// ---------------- pipelined bf16 MFMA GEMM body (counted vmcnt, 2-barrier) ----------------
struct MJob {
    const unsigned short *A0, *A1;
    const int *i0, *i1;
    const unsigned short *Wt;
    const float *bias;
    void *C;
    int N, K, epi, nrow;   // epi: 0 f32 out, 2 bf16 out
    float scale;
};

#define MM2_SMEM 67840

__device__ __forceinline__ void mm2_body(const MJob J, int bid, char* smem)
{
    unsigned short* AsB = (unsigned short*)smem;
    unsigned short* BsB = AsB + 16384;
    int tid = threadIdx.x;
    int l = tid & 63, w = tid >> 6;
    int wr = w >> 1, wc = w & 1;
    int row0 = (bid % J.nrow) * 128, col0 = (bid / J.nrow) * 128;
    int nK = J.K >> 6;

    f32x4 acc[4][4];
#pragma unroll
    for (int m=0;m<4;m++)
#pragma unroll
        for (int n=0;n<4;n++) acc[m][n] = (f32x4){0.f,0.f,0.f,0.f};

    auto stage = [&](int buf, int k0){
        unsigned short* As = AsB + buf*8192;
        unsigned short* Bs = BsB + buf*8192;
#pragma unroll
        for (int q=0;q<4;q++){
            int slot = q*256 + w*64 + l;
            int r = slot >> 3, c8 = slot & 7;
            int g8 = c8 ^ (r & 7);
            int row; const unsigned short* base; int kl;
            if (k0 < 128){ row = J.i0 ? J.i0[row0+r] : (row0+r); base = J.A0; kl = k0; }
            else         { row = J.i1 ? J.i1[row0+r] : (row0+r); base = J.A1; kl = k0-128; }
            const char* g = (const char*)(base + (size_t)row*128 + kl) + g8*16;
            gload16(g, (void*)&As[(size_t)(q*256 + w*64)*8]);
        }
#pragma unroll
        for (int q=0;q<4;q++){
            int slot = q*256 + w*64 + l;
            int n = slot >> 3, kc = slot & 7;
            int g8 = kc ^ (n & 7);
            const char* g = (const char*)(J.Wt + (size_t)(col0+n)*J.K + k0) + g8*16;
            gload16(g, (void*)&Bs[(size_t)(q*256 + w*64)*8]);
        }
    };

    stage(0, 0);
    for (int ks=0; ks<nK; ++ks){
        int cur = ks & 1;
        if (ks+1 < nK){
            stage(cur^1, (ks+1)*64);
            asm volatile("s_waitcnt vmcnt(8)" ::: "memory");
        } else {
            asm volatile("s_waitcnt vmcnt(0)" ::: "memory");
        }
        __builtin_amdgcn_s_barrier();
        __builtin_amdgcn_sched_barrier(0);
        unsigned short* As = AsB + cur*8192;
        unsigned short* Bs = BsB + cur*8192;
#pragma unroll
        for (int kk = 0; kk < 2; ++kk){
            int ek = kk*32 + (l >> 4) * 8;
            bf16x8 af[4], bf[4];
#pragma unroll
            for (int m=0;m<4;m++){
                int r = wr*64 + m*16 + (l & 15);
                af[m] = *reinterpret_cast<const bf16x8*>(&As[r*64 + (ek ^ ((r & 7) << 3))]);
            }
#pragma unroll
            for (int n=0;n<4;n++){
                int c = wc*64 + n*16 + (l & 15);
                bf[n] = *reinterpret_cast<const bf16x8*>(&Bs[c*64 + (ek ^ ((c & 7) << 3))]);
            }
#pragma unroll
            for (int m=0;m<4;m++)
#pragma unroll
                for (int n=0;n<4;n++)
                    acc[m][n] = __builtin_amdgcn_mfma_f32_16x16x32_bf16(af[m], bf[n], acc[m][n], 0, 0, 0);
        }
        __builtin_amdgcn_sched_barrier(0);
        __builtin_amdgcn_s_barrier();
    }

    if (J.epi == 0){
        float* Ct = (float*)smem;
#pragma unroll
        for (int m=0;m<4;m++){
#pragma unroll
            for (int v=0;v<4;v++){
                int rl = wr*64 + m*16 + (l >> 4)*4 + v;
#pragma unroll
                for (int n=0;n<4;n++){
                    int c = wc*64 + n*16 + (l & 15);
                    Ct[rl*132 + c] = J.scale*acc[m][n][v] + (J.bias ? J.bias[col0+c] : 0.f);
                }
            }
        }
        __syncthreads();
#pragma unroll
        for (int q=0;q<16;q++){
            int idx = tid + q*256;
            int r = idx >> 5, c4 = (idx & 31)*4;
            float4 v = *reinterpret_cast<const float4*>(&Ct[r*132 + c4]);
            *reinterpret_cast<float4*>((float*)J.C + (size_t)(row0+r)*J.N + col0 + c4) = v;
        }
    } else {
        unsigned short* Cb = (unsigned short*)smem;
#pragma unroll
        for (int m=0;m<4;m++){
#pragma unroll
            for (int v=0;v<4;v++){
                int rl = wr*64 + m*16 + (l >> 4)*4 + v;
#pragma unroll
                for (int n=0;n<4;n++){
                    int c = wc*64 + n*16 + (l & 15);
                    Cb[rl*136 + c] = f2b(J.scale*acc[m][n][v] + (J.bias ? J.bias[col0+c] : 0.f));
                }
            }
        }
        __syncthreads();
#pragma unroll
        for (int q=0;q<8;q++){
            int idx = tid + q*256;
            int r = idx >> 4, c8 = (idx & 15)*8;
            uint4 v = *reinterpret_cast<const uint4*>(&Cb[r*136 + c8]);
            *reinterpret_cast<uint4*>((unsigned short*)J.C + (size_t)(row0+r)*J.N + col0 + c8) = v;
        }
    }
}

__launch_bounds__(256)
__global__ void mm2one(MJob a)
{
    __shared__ alignas(16) char smem[MM2_SMEM];
    mm2_body(a, blockIdx.x, smem);
}

__launch_bounds__(256)
__global__ void mm2two(MJob a, MJob b, int asplit)
{
    __shared__ alignas(16) char smem[MM2_SMEM];
    int bid = blockIdx.x;
    if (bid < asplit) mm2_body(a, bid, smem);
    else              mm2_body(b, bid - asplit, smem);
}

// ---------------- fully fused GRU body (counted vmcnt, 2-barrier) ----------------
struct GJob {
    const unsigned short *A0, *A1;
    const int *i0, *i1;
    int lda;
    const unsigned short *Wih, *Whh;
    const float *bih, *bhh;
    float *H;
    unsigned short *Hbf, *stateBf;
    const int *sidx;
    int M, nodes;
};

__device__ __forceinline__ void gru_body(const GJob J, int bid, unsigned short* AsB, unsigned short* BsB)
{
    int tid = threadIdx.x;
    int l = tid & 63, w = tid >> 6;
    int row0 = bid * 128;
    f32x4 acc[24], accN[8];
#pragma unroll
    for (int n=0;n<24;n++) acc[n] = (f32x4){0.f,0.f,0.f,0.f};
#pragma unroll
    for (int n=0;n<8;n++) accN[n] = (f32x4){0.f,0.f,0.f,0.f};

    auto stage = [&](int buf, int st){
        int k0 = st*64;
        unsigned short* As = AsB + buf*8192;
        unsigned short* Bs = BsB + buf*24576;
#pragma unroll
        for (int q=0;q<2;q++){
            int slot = q*512 + w*64 + l;
            int r = slot >> 3, c8 = slot & 7;
            int g8 = c8 ^ (r & 7);
            const unsigned short* src;
            if (st < 4){
                if (J.i1){
                    if (k0 < 128){ int ri = J.i0 ? J.i0[row0+r] : (row0+r); src = J.A0 + (size_t)ri*128 + k0; }
                    else         { int ri = J.i1[row0+r]; src = J.A1 + (size_t)ri*128 + (k0-128); }
                } else {
                    src = J.A0 + (size_t)(row0+r)*J.lda + k0;
                }
            } else {
                src = J.Hbf + (size_t)(row0+r)*128 + (k0-256);
            }
            gload16((const char*)src + g8*16, (void*)&As[(size_t)(q*512 + w*64)*8]);
        }
#pragma unroll
        for (int q=0;q<6;q++){
            int slot = q*512 + w*64 + l;
            int n = slot >> 3, kc = slot & 7;
            int g8 = kc ^ (n & 7);
            const unsigned short* src = (st < 4) ? (J.Wih + (size_t)n*256 + k0)
                                                 : (J.Whh + (size_t)n*128 + (k0-256));
            gload16((const char*)src + g8*16, (void*)&Bs[(size_t)(q*512 + w*64)*8]);
        }
    };

    stage(0, 0);
    for (int st=0; st<6; ++st){
        int cur = st & 1;
        if (st+1 < 6){
            stage(cur^1, st+1);
            asm volatile("s_waitcnt vmcnt(8)" ::: "memory");
        } else {
            asm volatile("s_waitcnt vmcnt(0)" ::: "memory");
        }
        __builtin_amdgcn_s_barrier();
        __builtin_amdgcn_sched_barrier(0);
        unsigned short* As = AsB + cur*8192;
        unsigned short* Bs = BsB + cur*24576;
        if (st < 4){
#pragma unroll
            for (int kk=0; kk<2; ++kk){
                int ek = kk*32 + (l >> 4)*8;
                int r = w*16 + (l & 15);
                bf16x8 af = *reinterpret_cast<const bf16x8*>(&As[r*64 + (ek ^ ((r & 7) << 3))]);
#pragma unroll
                for (int n=0;n<24;n++){
                    int c = n*16 + (l & 15);
                    bf16x8 bf = *reinterpret_cast<const bf16x8*>(&Bs[c*64 + (ek ^ ((c & 7) << 3))]);
                    acc[n] = __builtin_amdgcn_mfma_f32_16x16x32_bf16(af, bf, acc[n], 0, 0, 0);
                }
            }
        } else {
#pragma unroll
            for (int kk=0; kk<2; ++kk){
                int ek = kk*32 + (l >> 4)*8;
                int r = w*16 + (l & 15);
                bf16x8 af = *reinterpret_cast<const bf16x8*>(&As[r*64 + (ek ^ ((r & 7) << 3))]);
#pragma unroll
                for (int n=0;n<24;n++){
                    int c = n*16 + (l & 15);
                    bf16x8 bf = *reinterpret_cast<const bf16x8*>(&Bs[c*64 + (ek ^ ((c & 7) << 3))]);
                    if (n < 16) acc[n]     = __builtin_amdgcn_mfma_f32_16x16x32_bf16(af, bf, acc[n], 0, 0, 0);
                    else        accN[n-16] = __builtin_amdgcn_mfma_f32_16x16x32_bf16(af, bf, accN[n-16], 0, 0, 0);
                }
            }
        }
        __builtin_amdgcn_sched_barrier(0);
        __builtin_amdgcn_s_barrier();
    }
#pragma unroll
    for (int v=0;v<4;v++){
        int row = row0 + w*16 + (l >> 4)*4 + v;
        int st = clampi(J.sidx[row],0,J.nodes-1);
#pragma unroll
        for (int c=0;c<8;c++){
            int col = c*16 + (l & 15);
            float rr = sigf(acc[c][v]    + J.bih[col]     + J.bhh[col]);
            float zz = sigf(acc[c+8][v]  + J.bih[col+128] + J.bhh[col+128]);
            float nn = tanhf(acc[c+16][v] + J.bih[col+256] + rr*(accN[c][v] + J.bhh[col+256]));
            float hv = J.H[(size_t)row*128 + col];
            float hn = (1.f-zz)*nn + zz*hv;
            unsigned short hb = f2b(hn);
            J.H[(size_t)row*128 + col] = hn;
            J.Hbf[(size_t)row*128 + col] = hb;
            J.stateBf[(size_t)st*128 + col] = hb;
        }
    }
}

__launch_bounds__(512)
__global__ void gru2(GJob a, GJob b, int asplit)
{
    __shared__ alignas(16) unsigned short AsB[2*8192];
    __shared__ alignas(16) unsigned short BsB[2*24576];
    int bid = blockIdx.x;
    if (bid < asplit) gru_body(a, bid, AsB, BsB);
    else              gru_body(b, bid - asplit, AsB, BsB);
}

// ---------------- fused GAT attention ----------------
__launch_bounds__(256)
__global__ void k_attn(const unsigned short* __restrict__ SRC, const unsigned short* __restrict__ tgtbf,
                       const float* __restrict__ att, const int* __restrict__ list,
                       const int* __restrict__ offs, const float* __restrict__ batt,
                       unsigned short* __restrict__ msgDbf,
                       float* __restrict__ alphaG, int Dn, int F)
{
    __shared__ float tg[1024];
    __shared__ float alds[128*4];
    __shared__ float accs[4][256];
    int d = blockIdx.x;
    int tid = threadIdx.x;
    int w = tid >> 6, lane = tid & 63;
    for (int u = tid; u < 1024; u += 256) tg[u] = us2f(tgtbf[(size_t)d*1024 + u]);
    __syncthreads();
    int beg = offs[d], end = offs[d+1];
    if (beg < 0) beg = 0; if (end > F) end = F; if (end < beg) end = beg;
    int c0 = w*256 + lane*4;
    float t0 = tg[c0], t1 = tg[c0+1], t2 = tg[c0+2], t3 = tg[c0+3];
    float a0 = att[c0], a1 = att[c0+1], a2 = att[c0+2], a3 = att[c0+3];
    float amax = -3.4e38f;
    for (int i=beg;i<end;i++){
        int f = list[i];
        ushort4 sv = *reinterpret_cast<const ushort4*>(SRC + (size_t)f*1024 + c0);
        float e0 = us2f(sv.x)+t0, e1 = us2f(sv.y)+t1, e2 = us2f(sv.z)+t2, e3 = us2f(sv.w)+t3;
        e0 = e0>0.f?e0:0.2f*e0; e1 = e1>0.f?e1:0.2f*e1;
        e2 = e2>0.f?e2:0.2f*e2; e3 = e3>0.f?e3:0.2f*e3;
        float s = e0*a0 + e1*a1 + e2*a2 + e3*a3;
#pragma unroll
        for (int msk=1; msk<64; msk<<=1) s += __shfl_xor(s, msk);
        int li = i - beg;
        if (li < 128){ if (lane == 0) alds[li*4+w] = s; }
        else         { if (lane == 0) alphaG[(size_t)f*4+w] = s; }
        amax = fmaxf(amax, s);
    }
    __syncthreads();
    float wsum = 0.f;
    for (int i=beg;i<end;i++){
        int li = i - beg;
        float a = (li < 128) ? alds[li*4+w] : alphaG[(size_t)list[i]*4+w];
        wsum += expf(a - amax);
    }
    float iws = 1.f/(wsum + 1e-16f);
    float acc[4] = {0,0,0,0};
    for (int i=beg;i<end;i++){
        int f = list[i];
        int li = i - beg;
        float a = (li < 128) ? alds[li*4+w] : alphaG[(size_t)f*4+w];
        float p = expf(a - amax)*iws;
        ushort4 sv = *reinterpret_cast<const ushort4*>(SRC + (size_t)f*1024 + c0);
        acc[0] += p*us2f(sv.x); acc[1] += p*us2f(sv.y);
        acc[2] += p*us2f(sv.z); acc[3] += p*us2f(sv.w);
    }
#pragma unroll
    for (int j=0;j<4;j++) accs[w][lane*4+j] = acc[j];
    __syncthreads();
    if (tid < 256){
        float m = (accs[0][tid]+accs[1][tid]+accs[2][tid]+accs[3][tid])*0.25f + batt[tid];
        msgDbf[(size_t)d*256 + tid] = f2b(m);
    }
}

// ---------------- fused phiC recurrence: 8 services/block, bf16 gi ----------------
__launch_bounds__(512)
__global__ void k_recur(float* __restrict__ h_srv, const unsigned short* __restrict__ giFb,
                        const unsigned short* __restrict__ Whi,
                        const unsigned short* __restrict__ Wlo,
                        const float* __restrict__ bhh,
                        const int* __restrict__ inv,
                        unsigned short* __restrict__ out_f_bf,
                        int S, int L, int F)
{
    __shared__ float hs[8][129];
    __shared__ alignas(16) unsigned short hsHi[16*128];
    __shared__ alignas(16) unsigned short hsLo[16*128];
    __shared__ float ghs[16][385];
    __shared__ int fLoc[16][8];
    int tid = threadIdx.x;
    int l = tid & 63, w = tid >> 6;
    int lane15 = l & 15, lhi = l >> 4;
    int s0 = blockIdx.x * 8;
    for (int u = tid; u < 2048; u += 512){
        int s=u>>7,k=u&127;
        int ksw = k ^ ((s & 7) << 3);
        if (s < 8){
            float v = h_srv[(size_t)(s0+s)*128+k];
            hs[s][k] = v;
            unsigned short hb = f2b(v);
            hsHi[s*128 + ksw] = hb;
            hsLo[s*128 + ksw] = f2b(v - us2f(hb));
        } else {
            hsHi[s*128 + ksw] = 0;
            hsLo[s*128 + ksw] = 0;
        }
    }
    if (tid < 128) fLoc[tid>>3][tid&7] = inv[(size_t)(s0+(tid&7))*L + (tid>>3)];
    bf16x8 wHi[3][4], wLo[3][4];
#pragma unroll
    for (int ct=0; ct<3; ++ct){
        int col = w*48 + ct*16 + lane15;
#pragma unroll
        for (int ks=0; ks<4; ++ks){
            size_t off = (size_t)col*128 + ks*32 + lhi*8;
            wHi[ct][ks] = *reinterpret_cast<const bf16x8*>(Whi + off);
            wLo[ct][ks] = *reinterpret_cast<const bf16x8*>(Wlo + off);
        }
    }
    __syncthreads();
    for (int t=0;t<L;++t){
        bf16x8 hHi[4], hLo[4];
#pragma unroll
        for (int ks=0; ks<4; ++ks){
            int ek = ks*32 + lhi*8;
            int off = lane15*128 + (ek ^ ((lane15 & 7) << 3));
            hHi[ks] = *reinterpret_cast<const bf16x8*>(&hsHi[off]);
            hLo[ks] = *reinterpret_cast<const bf16x8*>(&hsLo[off]);
        }
#pragma unroll
        for (int ct=0; ct<3; ++ct){
            f32x4 acc = (f32x4){0.f,0.f,0.f,0.f};
#pragma unroll
            for (int ks=0; ks<4; ++ks){
                acc = __builtin_amdgcn_mfma_f32_16x16x32_bf16(hHi[ks], wHi[ct][ks], acc, 0,0,0);
                acc = __builtin_amdgcn_mfma_f32_16x16x32_bf16(hLo[ks], wHi[ct][ks], acc, 0,0,0);
                acc = __builtin_amdgcn_mfma_f32_16x16x32_bf16(hHi[ks], wLo[ct][ks], acc, 0,0,0);
            }
            int col = w*48 + ct*16 + lane15;
            float bb = bhh[col];
#pragma unroll
            for (int v=0; v<4; ++v){
                ghs[lhi*4 + v][col] = acc[v] + bb;
            }
        }
        __syncthreads();
        for (int u = tid; u < 1024; u += 512){
            int s=u>>7, k=u&127; int f = fLoc[t][s];
            if (f >= 0 && f < F){
                const unsigned short* gp = giFb + (size_t)f*384;
                float r  = sigf(us2f(gp[k])     + ghs[s][k]);
                float zz = sigf(us2f(gp[128+k]) + ghs[s][128+k]);
                float n  = tanhf(us2f(gp[256+k]) + r*ghs[s][256+k]);
                float hn = (1.f-zz)*n + zz*hs[s][k];
                hs[s][k] = hn;
                unsigned short hb = f2b(hn);
                int ksw = k ^ ((s & 7) << 3);
                hsHi[s*128 + ksw] = hb;
                hsLo[s*128 + ksw] = f2b(hn - us2f(hb));
                out_f_bf[(size_t)f*128+k] = hb;
            }
        }
        __syncthreads();
    }
    for (int u = tid; u < 1024; u += 512){ int s=u>>7,k=u&127; h_srv[(size_t)(s0+s)*128+k] = hs[s][k]; }
}

__global__ void k_count(const int* __restrict__ row, int* __restrict__ counts, int F, int Dn)
{ int f = blockIdx.x*blockDim.x + threadIdx.x; if (f < F) atomicAdd(&counts[clampi(row[f],0,Dn-1)], 1); }

__global__ void k_scan(const int* __restrict__ counts, int* __restrict__ offs, int D)
{
    __shared__ int part[257];
    int tid = threadIdx.x;
    int per = (D + 255) / 256;
    int s = 0;
    for (int i=0;i<per;i++){ int idx = tid*per+i; if (idx < D) s += counts[idx]; }
    part[tid] = s;
    __syncthreads();
    if (tid == 0){
        int acc = 0;
        for (int i=0;i<256;i++){ int v = part[i]; part[i] = acc; acc += v; }
        part[256] = acc;
    }
    __syncthreads();
    int acc = part[tid];
    for (int i=0;i<per;i++){ int idx = tid*per+i; if (idx < D){ offs[idx] = acc; acc += counts[idx]; } }
    if (tid == 0) offs[D] = part[256];
}

__global__ void k_fill(const int* __restrict__ row, const int* __restrict__ offs,
                       int* __restrict__ cursor, int* __restrict__ list, int F, int Dn)
{
    int f = blockIdx.x*blockDim.x + threadIdx.x;
    if (f >= F) return;
    int r = clampi(row[f],0,Dn-1);
    int p = atomicAdd(&cursor[r], 1);
    int pos = offs[r]+p;
    if (pos >= 0 && pos < F) list[pos] = f;
}

__global__ void k_build_inv(const int* __restrict__ fs, const int* __restrict__ fp,
                            int* __restrict__ inv, int F, int L, int S)
{
    int f = blockIdx.x*blockDim.x + threadIdx.x;
    if (f >= F) return;
    inv[clampi(fs[f],0,S-1)*L + clampi(fp[f],0,L-1)] = f;
}

__global__ void k_pool_add(const float* __restrict__ frag, const int* __restrict__ fs,
                           float* __restrict__ pooled, int F, int S)
{
    int t = blockIdx.x*blockDim.x + threadIdx.x;
    int i = t >> 7, j = t & 127;
    if (i >= F) return;
    atomicAdd(&pooled[(size_t)clampi(fs[i],0,S-1)*128 + j], frag[(size_t)i*128 + j]);
}

__global__ void k_pool_div(float* __restrict__ pooled, const int* __restrict__ lengths, int S)
{
    int t = blockIdx.x*blockDim.x + threadIdx.x;
    int i = t >> 7, j = t & 127;
    if (i >= S) return;
    int l = lengths[i]; if (l < 1) l = 1;
    pooled[(size_t)i*128 + j] /= (float)l;
}

__global__ void k_dot_out(const float* __restrict__ H, const float* __restrict__ W3,
                          const float* __restrict__ b3, float* __restrict__ outv, int off)
{
    __shared__ float red[256];
    int s = blockIdx.x, tid = threadIdx.x;
    red[tid] = H[(size_t)s*256 + tid] * W3[tid];
    __syncthreads();
    for (int st=128; st; st>>=1){ if (tid < st) red[tid] += red[tid+st]; __syncthreads(); }
    if (tid == 0) outv[off + s] = red[0] + b3[0];
}

// =====================================================================================
extern "C" void kernel_launch(void* const* d_in, const int* in_sizes, int n_in,
                              void* d_out, int out_size, void* d_ws, size_t ws_size,
                              hipStream_t stream)
{
    (void)n_in; (void)out_size; (void)ws_size;
    const float* realnode = (const float*)d_in[0];
    const float* arr      = (const float*)d_in[1];
    const int* r_exe   = (const int*)d_in[2];
    const int* r_idev  = (const int*)d_in[3];
    const int* r_ifrag = (const int*)d_in[4];
    const int* r_fdn   = (const int*)d_in[5];
    const int* r_fdr   = (const int*)d_in[6];
    const int* r_len   = (const int*)d_in[7];
    const int* r_fsvc  = (const int*)d_in[8];
    const int* r_fpos  = (const int*)d_in[9];
    const float *W_dev=(const float*)d_in[10], *b_dev=(const float*)d_in[11];
    const float *W_frg=(const float*)d_in[12], *b_frg=(const float*)d_in[13];
    const float *W_srv=(const float*)d_in[14], *b_srv=(const float*)d_in[15];
    const float *C_Wih=(const float*)d_in[16], *C_Whh=(const float*)d_in[17], *C_bih=(const float*)d_in[18], *C_bhh=(const float*)d_in[19];
    const float *F_Wih=(const float*)d_in[20], *F_Whh=(const float*)d_in[21], *F_bih=(const float*)d_in[22], *F_bhh=(const float*)d_in[23];
    const float *D_Wih=(const float*)d_in[24], *D_Whh=(const float*)d_in[25], *D_bih=(const float*)d_in[26], *D_bhh=(const float*)d_in[27];
    const float *W_src=(const float*)d_in[28], *b_src=(const float*)d_in[29];
    const float *W_tgt=(const float*)d_in[30], *b_tgt=(const float*)d_in[31];
    const float *att=(const float*)d_in[32], *bias_att=(const float*)d_in[33];
    const float *Wt1=(const float*)d_in[34], *bt1=(const float*)d_in[35], *Wt2=(const float*)d_in[36], *bt2=(const float*)d_in[37], *Wt3=(const float*)d_in[38], *bt3=(const float*)d_in[39];
    const float *Wl1=(const float*)d_in[40], *bl1=(const float*)d_in[41], *Wl2=(const float*)d_in[42], *bl2=(const float*)d_in[43], *Wl3=(const float*)d_in[44], *bl3=(const float*)d_in[45];
    float* outp = (float*)d_out;

    const int S  = in_sizes[7];
    const int Dn = in_sizes[3];
    const int F  = in_sizes[4];
    const int L  = in_sizes[2] / (2*S);
    const int nreal = in_sizes[0]/5;
    const int nodes = nreal + 1;
    const int NIT = 3;

    char* wp = (char*)d_ws;
    auto alloc = [&](size_t nelem)->float*{
        float* p = (float*)wp;
        wp += ((nelem*4 + 255)/256)*256;
        return p;
    };
    float* h_srv  = alloc((size_t)S*128);
    float* fragA  = alloc((size_t)F*128);
    float* devA   = alloc((size_t)Dn*128);
    float* alphaB = alloc((size_t)F*4);
    float* UNION  = alloc((size_t)F*512);     // giFb bf16 / SRC bf16
    unsigned short* giFb = (unsigned short*)UNION;
    unsigned short* SRC  = (unsigned short*)UNION;
    float* Z      = alloc((size_t)Dn*1024);
    float* TGTf   = alloc((size_t)Dn*512);
    unsigned short* TGT = (unsigned short*)TGTf;
    float* pooled = alloc((size_t)S*128);
    unsigned short* state_bf = (unsigned short*)alloc((size_t)nodes*64);
    unsigned short* out_f_bf = (unsigned short*)alloc((size_t)F*64);
    unsigned short* fragA_bf = (unsigned short*)alloc((size_t)F*64);
    unsigned short* devA_bf  = (unsigned short*)alloc((size_t)Dn*64);
    unsigned short* msgD_bf  = (unsigned short*)alloc((size_t)Dn*128);
    unsigned short* tCWih   = (unsigned short*)alloc(384*256/2);
    unsigned short* tCWhhHi = (unsigned short*)alloc(384*128/2);
    unsigned short* tCWhhLo = (unsigned short*)alloc(384*128/2);
    unsigned short* tFWih   = (unsigned short*)alloc(384*256/2);
    unsigned short* tFWhh   = (unsigned short*)alloc(384*128/2);
    unsigned short* tDWih   = (unsigned short*)alloc(384*256/2);
    unsigned short* tDWhh   = (unsigned short*)alloc(384*128/2);
    unsigned short* tWtgt   = (unsigned short*)alloc(1024*128/2);
    unsigned short* tWsrc   = (unsigned short*)alloc(1024*256/2);
    int* cExe   = (int*)alloc((size_t)S*2*L);
    int* cIdev  = (int*)alloc((size_t)Dn);
    int* cIfrag = (int*)alloc((size_t)F);
    int* cFdn   = (int*)alloc((size_t)F);
    int* cFdr   = (int*)alloc((size_t)F);
    int* cLen   = (int*)alloc((size_t)S);
    int* cFsvc  = (int*)alloc((size_t)F);
    int* cFpos  = (int*)alloc((size_t)F);
    int* inv    = (int*)alloc((size_t)S*L);
    int* counts = (int*)alloc((size_t)Dn);
    int* offs   = (int*)alloc((size_t)Dn+1);
    int* cursor = (int*)alloc((size_t)Dn);
    int* list   = (int*)alloc((size_t)F);

    const int* det = r_idev;
    auto cvt = [&](const int* src, int* dst, int n){
        k_cvt<<<dim3((n+255)/256),256,0,stream>>>(src, dst, n, det);
    };
    cvt(r_exe,  cExe,  S*2*L);
    cvt(r_idev, cIdev, Dn);
    cvt(r_ifrag,cIfrag,F);
    cvt(r_fdn,  cFdn,  F);
    cvt(r_fdr,  cFdr,  F);
    cvt(r_len,  cLen,  S);
    cvt(r_fsvc, cFsvc, F);
    cvt(r_fpos, cFpos, F);

    k_wt<<<dim3((98304+255)/256),256,0,stream>>>(C_Wih, tCWih, 384, 8, 255, 98304);
    k_wt2<<<dim3((49152+255)/256),256,0,stream>>>(C_Whh, tCWhhHi, tCWhhLo, 384, 7, 127, 49152);
    k_wt<<<dim3((98304+255)/256),256,0,stream>>>(F_Wih, tFWih, 384, 8, 255, 98304);
    k_wt<<<dim3((49152+255)/256),256,0,stream>>>(F_Whh, tFWhh, 384, 7, 127, 49152);
    k_wt<<<dim3((98304+255)/256),256,0,stream>>>(D_Wih, tDWih, 384, 8, 255, 98304);
    k_wt<<<dim3((49152+255)/256),256,0,stream>>>(D_Whh, tDWhh, 384, 7, 127, 49152);
    k_wt<<<dim3((131072+255)/256),256,0,stream>>>(W_tgt, tWtgt, 1024, 7, 127, 131072);
    k_wt<<<dim3((262144+255)/256),256,0,stream>>>(W_src, tWsrc, 1024, 8, 255, 262144);

    hipMemsetAsync(state_bf, 0, (size_t)nodes*128*2, stream);
    hipMemsetAsync(inv, 0xFF, (size_t)S*L*4, stream);
    hipMemsetAsync(counts, 0, (size_t)Dn*4, stream);
    hipMemsetAsync(cursor, 0, (size_t)Dn*4, stream);

    k_proj5<<<dim3((Dn*128+255)/256),256,0,stream>>>(realnode, W_dev, b_dev, cIdev, cIdev,
        nullptr, state_bf, devA, devA_bf, Dn, nreal, nodes);
    k_proj5<<<dim3(((size_t)F*128+255)/256),256,0,stream>>>(realnode, W_frg, b_frg, cIfrag, cIfrag,
        nullptr, state_bf, fragA, fragA_bf, F, nreal, nodes);
    k_proj5<<<dim3((S*128+255)/256),256,0,stream>>>(arr, W_srv, b_srv, nullptr, nullptr,
        h_srv, nullptr, nullptr, nullptr, S, S, nodes);
    k_build_inv<<<dim3((F+255)/256),256,0,stream>>>(cFsvc, cFpos, inv, F, L, S);
    k_count<<<dim3((F+255)/256),256,0,stream>>>(cFdr, counts, F, Dn);
    k_scan<<<1,256,0,stream>>>(counts, offs, Dn);
    k_fill<<<dim3((F+255)/256),256,0,stream>>>(cFdr, offs, cursor, list, F, Dn);

    const int nrF = F/128, nrD = Dn/128;
    MJob jGi  = { state_bf, state_bf, cIfrag, cFdn, tCWih, C_bih, giFb, 384, 256, 2, nrF, 1.f };
    MJob jTgt = { devA_bf, devA_bf, nullptr, nullptr, tWtgt, b_tgt, TGT, 1024, 128, 2, nrD, 1.f };
    MJob jSrc = { out_f_bf, fragA_bf, nullptr, nullptr, tWsrc, b_src, SRC, 1024, 256, 2, nrF, 1.f };
    GJob jF = { out_f_bf, state_bf, nullptr, cFdn, 128, tFWih, tFWhh, F_bih, F_bhh,
                fragA, fragA_bf, state_bf, cIfrag, F, nodes };
    GJob jD = { msgD_bf, nullptr, nullptr, nullptr, 256, tDWih, tDWhh, D_bih, D_bhh,
                devA, devA_bf, state_bf, cIdev, Dn, nodes };

    for (int it=0; it<NIT; ++it){
        mm2two<<<dim3(3*nrF + 8*nrD),256,0,stream>>>(jGi, jTgt, 3*nrF);
        k_recur<<<dim3(S/8),512,0,stream>>>(h_srv, giFb, tCWhhHi, tCWhhLo, C_bhh, inv,
            out_f_bf, S, L, F);
        mm2one<<<dim3(8*nrF),256,0,stream>>>(jSrc);
        k_attn<<<dim3(Dn),256,0,stream>>>(SRC, TGT, att, list, offs, bias_att,
            msgD_bf, alphaB, Dn, F);
        gru2<<<dim3(nrF + nrD),512,0,stream>>>(jF, jD, nrF);
    }

    // readout
    hipMemsetAsync(pooled, 0, (size_t)S*128*4, stream);
    k_pool_add<<<dim3(((size_t)F*128+255)/256),256,0,stream>>>(fragA, cFsvc, pooled, F, S);
    k_pool_div<<<dim3((S*128+255)/256),256,0,stream>>>(pooled, cLen, S);
    float* h1 = (float*)TGTf;
    k_mm<<<dim3(256/128, S/128),256,0,stream>>>(pooled, 128, Wl1, 256, bl1, h1, S, 256, 128, 1, 1.f, 0);
    k_mm<<<dim3(256/128, S/128),256,0,stream>>>(h1, 256, Wl2, 256, bl2, Z, S, 256, 256, 1, 1.f, 0);
    k_dot_out<<<dim3(S),256,0,stream>>>(Z, Wl3, bl3, outp, 0);
    k_mm<<<dim3(256/128, S/128),256,0,stream>>>(h_srv, 128, Wt1, 256, bt1, h1, S, 256, 128, 1, 1.f, 0);
    k_mm<<<dim3(256/128, S/128),256,0,stream>>>(h1, 256, Wt2, 256, bt2, Z, S, 256, 256, 1, 1.f, 0);
    k_dot_out<<<dim3(S),256,0,stream>>>(Z, Wt3, bt3, outp, S);
}

// Round 15
// 800.865 us; speedup vs baseline: 1.9719x; 1.0012x over previous
//
#include <hip/hip_runtime.h>
#include <hip/hip_bf16.h>

typedef __attribute__((ext_vector_type(8))) short bf16x8;
typedef __attribute__((ext_vector_type(4))) float f32x4;

__device__ __forceinline__ float sigf(float x){ return 1.0f/(1.0f+expf(-x)); }
__device__ __forceinline__ int clampi(int v, int lo, int hi){ return v<lo?lo:(v>hi?hi:v); }
__device__ __forceinline__ unsigned short f2b(float f){
    __hip_bfloat16 h = __float2bfloat16(f);
    return *reinterpret_cast<unsigned short*>(&h);
}
__device__ __forceinline__ float us2f(unsigned short u){ return __uint_as_float(((unsigned)u)<<16); }

__device__ __forceinline__ void gload16(const void* g, void* l){
    __builtin_amdgcn_global_load_lds((const __attribute__((address_space(1))) void*)g,
                                     (__attribute__((address_space(3))) void*)l, 16, 0, 0);
}

// ---- int64/int32 tolerant index conversion ----
__global__ void k_cvt(const int* __restrict__ src, int* __restrict__ dst, int n,
                      const int* __restrict__ det)
{
    int i = blockIdx.x*blockDim.x + threadIdx.x;
    if (i >= n) return;
    int stride = (det[1] == 0) ? 2 : 1;
    dst[i] = src[(size_t)i*stride];
}

__global__ void k_wt(const float* __restrict__ W, unsigned short* __restrict__ Wt,
                     int N, int kshift, int kmask, int total)
{
    int idx = blockIdx.x*blockDim.x + threadIdx.x;
    if (idx >= total) return;
    int n = idx >> kshift, k = idx & kmask;
    Wt[idx] = f2b(W[(size_t)k*N + n]);
}

__global__ void k_wt2(const float* __restrict__ W, unsigned short* __restrict__ Whi,
                      unsigned short* __restrict__ Wlo, int N, int kshift, int kmask, int total)
{
    int idx = blockIdx.x*blockDim.x + threadIdx.x;
    if (idx >= total) return;
    int n = idx >> kshift, k = idx & kmask;
    float v = W[(size_t)k*N + n];
    unsigned short hi = f2b(v);
    Whi[idx] = hi;
    Wlo[idx] = f2b(v - us2f(hi));
}

// ---------------- init projections ----------------
__global__ void k_proj5(const float* __restrict__ X, const float* __restrict__ W,
                        const float* __restrict__ bias,
                        const int* __restrict__ gidx, const int* __restrict__ sidx,
                        float* __restrict__ out, unsigned short* __restrict__ outBf,
                        float* __restrict__ out2, unsigned short* __restrict__ out2Bf,
                        int M, int nrows, int nodes)
{
    int t = blockIdx.x*blockDim.x + threadIdx.x;
    int i = t >> 7, j = t & 127;
    if (i >= M) return;
    int src = gidx ? clampi(gidx[i]-1, 0, nrows-1) : i;
    const float* xp = X + (size_t)src*5;
    float acc = bias[j];
#pragma unroll
    for (int k=0;k<5;k++) acc += xp[k] * W[k*128+j];
    int dr = sidx ? clampi(sidx[i], 0, nodes-1) : i;
    if (out)   out[(size_t)dr*128 + j] = acc;
    if (outBf) outBf[(size_t)dr*128 + j] = f2b(acc);
    if (out2)  out2[(size_t)i*128 + j] = acc;
    if (out2Bf) out2Bf[(size_t)i*128 + j] = f2b(acc);
}

// ---------------- f32 tiled GEMM (readout heads only) ----------------
__launch_bounds__(256)
__global__ void k_mm(const float* __restrict__ A0, int lda,
                     const float* __restrict__ B, int ldb,
                     const float* __restrict__ bias, float* __restrict__ C,
                     int M, int N, int K, int relu, float scale, int accum)
{
    __shared__ float As[16][132];
    __shared__ float Bs[16][132];
    int tid = threadIdx.x;
    int tx = tid & 15, ty = tid >> 4;
    int row0 = blockIdx.y * 128, col0 = blockIdx.x * 128;
    float acc[8][8] = {};
    for (int k0 = 0; k0 < K; k0 += 16){
#pragma unroll
        for (int q = 0; q < 2; ++q){
            int idx = tid + q*256;
            int r = idx >> 2, k4 = (idx & 3) * 4;
            const float* src = A0 + (size_t)(row0+r)*lda + k0 + k4;
            float4 v = *reinterpret_cast<const float4*>(src);
            As[k4+0][r]=v.x; As[k4+1][r]=v.y; As[k4+2][r]=v.z; As[k4+3][r]=v.w;
        }
#pragma unroll
        for (int q = 0; q < 2; ++q){
            int idx = tid + q*256;
            int kb = idx >> 5, n4 = (idx & 31) * 4;
            float4 v = *reinterpret_cast<const float4*>(B + (size_t)(k0+kb)*ldb + col0 + n4);
            *reinterpret_cast<float4*>(&Bs[kb][n4]) = v;
        }
        __syncthreads();
#pragma unroll
        for (int k = 0; k < 16; ++k){
            float a[8], b[8];
            *(float4*)&a[0] = *(const float4*)&As[k][ty*8];
            *(float4*)&a[4] = *(const float4*)&As[k][ty*8+4];
            *(float4*)&b[0] = *(const float4*)&Bs[k][tx*8];
            *(float4*)&b[4] = *(const float4*)&Bs[k][tx*8+4];
#pragma unroll
            for (int i=0;i<8;i++)
#pragma unroll
                for (int j=0;j<8;j++) acc[i][j] += a[i]*b[j];
        }
        __syncthreads();
    }
    float bb[8];
#pragma unroll
    for (int j=0;j<8;j++) bb[j] = bias ? bias[col0+tx*8+j] : 0.f;
#pragma unroll
    for (int i=0;i<8;i++){
        float* cp = C + (size_t)(row0+ty*8+i)*N + col0 + tx*8;
#pragma unroll
        for (int jq=0;jq<2;jq++){
            float4 prev = accum ? *(const float4*)(cp+jq*4) : make_float4(0,0,0,0);
            float o[4];
#pragma unroll
            for (int c=0;c<4;c++){
                float u = acc[i][jq*4+c] + bb[jq*4+c];
                if (relu) u = fmaxf(u,0.f);
                o[c] = (&prev.x)[c] + scale*u;
            }
            *(float4*)(cp+jq*4) = make_float4(o[0],o[1],o[2],o[3]);
        }
    }
}

// ---------------- pipelined bf16 MFMA GEMM body (counted vmcnt, 2-barrier) ----------------
struct MJob {
    const unsigned short *A0, *A1;
    const int *i0, *i1;
    const unsigned short *Wt;
    const float *bias;
    void *C;
    int N, K, epi, nrow;   // epi: 0 f32 out, 2 bf16 out
    float scale;
};

#define MM2_SMEM 67840

__device__ __forceinline__ void mm2_body(const MJob J, int bid, char* smem)
{
    unsigned short* AsB = (unsigned short*)smem;
    unsigned short* BsB = AsB + 16384;
    int tid = threadIdx.x;
    int l = tid & 63, w = tid >> 6;
    int wr = w >> 1, wc = w & 1;
    int row0 = (bid % J.nrow) * 128, col0 = (bid / J.nrow) * 128;
    int nK = J.K >> 6;

    f32x4 acc[4][4];
#pragma unroll
    for (int m=0;m<4;m++)
#pragma unroll
        for (int n=0;n<4;n++) acc[m][n] = (f32x4){0.f,0.f,0.f,0.f};

    auto stage = [&](int buf, int k0){
        unsigned short* As = AsB + buf*8192;
        unsigned short* Bs = BsB + buf*8192;
#pragma unroll
        for (int q=0;q<4;q++){
            int slot = q*256 + w*64 + l;
            int r = slot >> 3, c8 = slot & 7;
            int g8 = c8 ^ (r & 7);
            int row; const unsigned short* base; int kl;
            if (k0 < 128){ row = J.i0 ? J.i0[row0+r] : (row0+r); base = J.A0; kl = k0; }
            else         { row = J.i1 ? J.i1[row0+r] : (row0+r); base = J.A1; kl = k0-128; }
            const char* g = (const char*)(base + (size_t)row*128 + kl) + g8*16;
            gload16(g, (void*)&As[(size_t)(q*256 + w*64)*8]);
        }
#pragma unroll
        for (int q=0;q<4;q++){
            int slot = q*256 + w*64 + l;
            int n = slot >> 3, kc = slot & 7;
            int g8 = kc ^ (n & 7);
            const char* g = (const char*)(J.Wt + (size_t)(col0+n)*J.K + k0) + g8*16;
            gload16(g, (void*)&Bs[(size_t)(q*256 + w*64)*8]);
        }
    };

    stage(0, 0);
    for (int ks=0; ks<nK; ++ks){
        int cur = ks & 1;
        if (ks+1 < nK){
            stage(cur^1, (ks+1)*64);
            asm volatile("s_waitcnt vmcnt(8)" ::: "memory");
        } else {
            asm volatile("s_waitcnt vmcnt(0)" ::: "memory");
        }
        __builtin_amdgcn_s_barrier();
        __builtin_amdgcn_sched_barrier(0);
        unsigned short* As = AsB + cur*8192;
        unsigned short* Bs = BsB + cur*8192;
#pragma unroll
        for (int kk = 0; kk < 2; ++kk){
            int ek = kk*32 + (l >> 4) * 8;
            bf16x8 af[4], bf[4];
#pragma unroll
            for (int m=0;m<4;m++){
                int r = wr*64 + m*16 + (l & 15);
                af[m] = *reinterpret_cast<const bf16x8*>(&As[r*64 + (ek ^ ((r & 7) << 3))]);
            }
#pragma unroll
            for (int n=0;n<4;n++){
                int c = wc*64 + n*16 + (l & 15);
                bf[n] = *reinterpret_cast<const bf16x8*>(&Bs[c*64 + (ek ^ ((c & 7) << 3))]);
            }
#pragma unroll
            for (int m=0;m<4;m++)
#pragma unroll
                for (int n=0;n<4;n++)
                    acc[m][n] = __builtin_amdgcn_mfma_f32_16x16x32_bf16(af[m], bf[n], acc[m][n], 0, 0, 0);
        }
        __builtin_amdgcn_sched_barrier(0);
        __builtin_amdgcn_s_barrier();
    }

    if (J.epi == 0){
        float* Ct = (float*)smem;
#pragma unroll
        for (int m=0;m<4;m++){
#pragma unroll
            for (int v=0;v<4;v++){
                int rl = wr*64 + m*16 + (l >> 4)*4 + v;
#pragma unroll
                for (int n=0;n<4;n++){
                    int c = wc*64 + n*16 + (l & 15);
                    Ct[rl*132 + c] = J.scale*acc[m][n][v] + (J.bias ? J.bias[col0+c] : 0.f);
                }
            }
        }
        __syncthreads();
#pragma unroll
        for (int q=0;q<16;q++){
            int idx = tid + q*256;
            int r = idx >> 5, c4 = (idx & 31)*4;
            float4 v = *reinterpret_cast<const float4*>(&Ct[r*132 + c4]);
            *reinterpret_cast<float4*>((float*)J.C + (size_t)(row0+r)*J.N + col0 + c4) = v;
        }
    } else {
        unsigned short* Cb = (unsigned short*)smem;
#pragma unroll
        for (int m=0;m<4;m++){
#pragma unroll
            for (int v=0;v<4;v++){
                int rl = wr*64 + m*16 + (l >> 4)*4 + v;
#pragma unroll
                for (int n=0;n<4;n++){
                    int c = wc*64 + n*16 + (l & 15);
                    Cb[rl*136 + c] = f2b(J.scale*acc[m][n][v] + (J.bias ? J.bias[col0+c] : 0.f));
                }
            }
        }
        __syncthreads();
#pragma unroll
        for (int q=0;q<8;q++){
            int idx = tid + q*256;
            int r = idx >> 4, c8 = (idx & 15)*8;
            uint4 v = *reinterpret_cast<const uint4*>(&Cb[r*136 + c8]);
            *reinterpret_cast<uint4*>((unsigned short*)J.C + (size_t)(row0+r)*J.N + col0 + c8) = v;
        }
    }
}

__launch_bounds__(256)
__global__ void mm2one(MJob a)
{
    __shared__ alignas(16) char smem[MM2_SMEM];
    mm2_body(a, blockIdx.x, smem);
}

__launch_bounds__(256)
__global__ void mm2two(MJob a, MJob b, int asplit)
{
    __shared__ alignas(16) char smem[MM2_SMEM];
    int bid = blockIdx.x;
    if (bid < asplit) mm2_body(a, bid, smem);
    else              mm2_body(b, bid - asplit, smem);
}

// ---------------- fully fused GRU body (counted vmcnt + LDS-staged epilogue) ----------------
struct GJob {
    const unsigned short *A0, *A1;
    const int *i0, *i1;
    int lda;
    const unsigned short *Wih, *Whh;
    const float *bih, *bhh;
    float *H;
    unsigned short *Hbf, *stateBf;
    const int *sidx;
    int M, nodes;
};

__device__ __forceinline__ void gru_body(const GJob J, int bid, char* smem)
{
    unsigned short* AsB = (unsigned short*)smem;          // 2 x 8192 ushort (32 KB)
    unsigned short* BsB = AsB + 2*8192;                   // 2 x 24576 ushort (96 KB)
    int tid = threadIdx.x;
    int l = tid & 63, w = tid >> 6;
    int row0 = bid * 128;
    f32x4 acc[24], accN[8];
#pragma unroll
    for (int n=0;n<24;n++) acc[n] = (f32x4){0.f,0.f,0.f,0.f};
#pragma unroll
    for (int n=0;n<8;n++) accN[n] = (f32x4){0.f,0.f,0.f,0.f};

    auto stage = [&](int buf, int st){
        int k0 = st*64;
        unsigned short* As = AsB + buf*8192;
        unsigned short* Bs = BsB + buf*24576;
#pragma unroll
        for (int q=0;q<2;q++){
            int slot = q*512 + w*64 + l;
            int r = slot >> 3, c8 = slot & 7;
            int g8 = c8 ^ (r & 7);
            const unsigned short* src;
            if (st < 4){
                if (J.i1){
                    if (k0 < 128){ int ri = J.i0 ? J.i0[row0+r] : (row0+r); src = J.A0 + (size_t)ri*128 + k0; }
                    else         { int ri = J.i1[row0+r]; src = J.A1 + (size_t)ri*128 + (k0-128); }
                } else {
                    src = J.A0 + (size_t)(row0+r)*J.lda + k0;
                }
            } else {
                src = J.Hbf + (size_t)(row0+r)*128 + (k0-256);
            }
            gload16((const char*)src + g8*16, (void*)&As[(size_t)(q*512 + w*64)*8]);
        }
#pragma unroll
        for (int q=0;q<6;q++){
            int slot = q*512 + w*64 + l;
            int n = slot >> 3, kc = slot & 7;
            int g8 = kc ^ (n & 7);
            const unsigned short* src = (st < 4) ? (J.Wih + (size_t)n*256 + k0)
                                                 : (J.Whh + (size_t)n*128 + (k0-256));
            gload16((const char*)src + g8*16, (void*)&Bs[(size_t)(q*512 + w*64)*8]);
        }
    };

    stage(0, 0);
    for (int st=0; st<6; ++st){
        int cur = st & 1;
        if (st+1 < 6){
            stage(cur^1, st+1);
            asm volatile("s_waitcnt vmcnt(8)" ::: "memory");
        } else {
            asm volatile("s_waitcnt vmcnt(0)" ::: "memory");
        }
        __builtin_amdgcn_s_barrier();
        __builtin_amdgcn_sched_barrier(0);
        unsigned short* As = AsB + cur*8192;
        unsigned short* Bs = BsB + cur*24576;
        if (st < 4){
#pragma unroll
            for (int kk=0; kk<2; ++kk){
                int ek = kk*32 + (l >> 4)*8;
                int r = w*16 + (l & 15);
                bf16x8 af = *reinterpret_cast<const bf16x8*>(&As[r*64 + (ek ^ ((r & 7) << 3))]);
#pragma unroll
                for (int n=0;n<24;n++){
                    int c = n*16 + (l & 15);
                    bf16x8 bf = *reinterpret_cast<const bf16x8*>(&Bs[c*64 + (ek ^ ((c & 7) << 3))]);
                    acc[n] = __builtin_amdgcn_mfma_f32_16x16x32_bf16(af, bf, acc[n], 0, 0, 0);
                }
            }
        } else {
#pragma unroll
            for (int kk=0; kk<2; ++kk){
                int ek = kk*32 + (l >> 4)*8;
                int r = w*16 + (l & 15);
                bf16x8 af = *reinterpret_cast<const bf16x8*>(&As[r*64 + (ek ^ ((r & 7) << 3))]);
#pragma unroll
                for (int n=0;n<24;n++){
                    int c = n*16 + (l & 15);
                    bf16x8 bf = *reinterpret_cast<const bf16x8*>(&Bs[c*64 + (ek ^ ((c & 7) << 3))]);
                    if (n < 16) acc[n]     = __builtin_amdgcn_mfma_f32_16x16x32_bf16(af, bf, acc[n], 0, 0, 0);
                    else        accN[n-16] = __builtin_amdgcn_mfma_f32_16x16x32_bf16(af, bf, accN[n-16], 0, 0, 0);
                }
            }
        }
        __builtin_amdgcn_sched_barrier(0);
        __builtin_amdgcn_s_barrier();
    }

    // ---- LDS-staged epilogue: coalesced H load, pointwise, coalesced stores ----
    __syncthreads();
    float* Hld = (float*)smem;                                   // [128][132] f32 (67584 B)
    unsigned short* Hb = (unsigned short*)(smem + 67584);        // [128][136] bf16 (34816 B)
#pragma unroll
    for (int q=0;q<8;q++){
        int idx = tid + q*512;
        int r = idx >> 5, c4 = (idx & 31)*4;
        float4 v = *reinterpret_cast<const float4*>(J.H + (size_t)(row0+r)*128 + c4);
        *reinterpret_cast<float4*>(&Hld[r*132 + c4]) = v;
    }
    __syncthreads();
#pragma unroll
    for (int v=0;v<4;v++){
        int rl = w*16 + (l >> 4)*4 + v;
#pragma unroll
        for (int c=0;c<8;c++){
            int col = c*16 + (l & 15);
            float rr = sigf(acc[c][v]    + J.bih[col]     + J.bhh[col]);
            float zz = sigf(acc[c+8][v]  + J.bih[col+128] + J.bhh[col+128]);
            float nn = tanhf(acc[c+16][v] + J.bih[col+256] + rr*(accN[c][v] + J.bhh[col+256]));
            float hv = Hld[rl*132 + col];
            float hn = (1.f-zz)*nn + zz*hv;
            Hld[rl*132 + col] = hn;
            Hb[rl*136 + col] = f2b(hn);
        }
    }
    __syncthreads();
#pragma unroll
    for (int q=0;q<8;q++){
        int idx = tid + q*512;
        int r = idx >> 5, c4 = (idx & 31)*4;
        float4 v = *reinterpret_cast<const float4*>(&Hld[r*132 + c4]);
        *reinterpret_cast<float4*>(J.H + (size_t)(row0+r)*128 + c4) = v;
    }
#pragma unroll
    for (int q=0;q<4;q++){
        int idx = tid + q*512;
        int r = idx >> 4, c8 = (idx & 15)*8;
        uint4 v = *reinterpret_cast<const uint4*>(&Hb[r*136 + c8]);
        *reinterpret_cast<uint4*>(J.Hbf + (size_t)(row0+r)*128 + c8) = v;
        int st = clampi(J.sidx[row0+r],0,J.nodes-1);
        *reinterpret_cast<uint4*>(J.stateBf + (size_t)st*128 + c8) = v;
    }
}

__launch_bounds__(512)
__global__ void gru2(GJob a, GJob b, int asplit)
{
    __shared__ alignas(16) char smem[131072];
    int bid = blockIdx.x;
    if (bid < asplit) gru_body(a, bid, smem);
    else              gru_body(b, bid - asplit, smem);
}

// ---------------- fused GAT attention ----------------
__launch_bounds__(256)
__global__ void k_attn(const unsigned short* __restrict__ SRC, const unsigned short* __restrict__ tgtbf,
                       const float* __restrict__ att, const int* __restrict__ list,
                       const int* __restrict__ offs, const float* __restrict__ batt,
                       unsigned short* __restrict__ msgDbf,
                       float* __restrict__ alphaG, int Dn, int F)
{
    __shared__ float tg[1024];
    __shared__ float alds[128*4];
    __shared__ float accs[4][256];
    int d = blockIdx.x;
    int tid = threadIdx.x;
    int w = tid >> 6, lane = tid & 63;
    for (int u = tid; u < 1024; u += 256) tg[u] = us2f(tgtbf[(size_t)d*1024 + u]);
    __syncthreads();
    int beg = offs[d], end = offs[d+1];
    if (beg < 0) beg = 0; if (end > F) end = F; if (end < beg) end = beg;
    int c0 = w*256 + lane*4;
    float t0 = tg[c0], t1 = tg[c0+1], t2 = tg[c0+2], t3 = tg[c0+3];
    float a0 = att[c0], a1 = att[c0+1], a2 = att[c0+2], a3 = att[c0+3];
    float amax = -3.4e38f;
    for (int i=beg;i<end;i++){
        int f = list[i];
        ushort4 sv = *reinterpret_cast<const ushort4*>(SRC + (size_t)f*1024 + c0);
        float e0 = us2f(sv.x)+t0, e1 = us2f(sv.y)+t1, e2 = us2f(sv.z)+t2, e3 = us2f(sv.w)+t3;
        e0 = e0>0.f?e0:0.2f*e0; e1 = e1>0.f?e1:0.2f*e1;
        e2 = e2>0.f?e2:0.2f*e2; e3 = e3>0.f?e3:0.2f*e3;
        float s = e0*a0 + e1*a1 + e2*a2 + e3*a3;
#pragma unroll
        for (int msk=1; msk<64; msk<<=1) s += __shfl_xor(s, msk);
        int li = i - beg;
        if (li < 128){ if (lane == 0) alds[li*4+w] = s; }
        else         { if (lane == 0) alphaG[(size_t)f*4+w] = s; }
        amax = fmaxf(amax, s);
    }
    __syncthreads();
    float wsum = 0.f;
    for (int i=beg;i<end;i++){
        int li = i - beg;
        float a = (li < 128) ? alds[li*4+w] : alphaG[(size_t)list[i]*4+w];
        wsum += expf(a - amax);
    }
    float iws = 1.f/(wsum + 1e-16f);
    float acc[4] = {0,0,0,0};
    for (int i=beg;i<end;i++){
        int f = list[i];
        int li = i - beg;
        float a = (li < 128) ? alds[li*4+w] : alphaG[(size_t)f*4+w];
        float p = expf(a - amax)*iws;
        ushort4 sv = *reinterpret_cast<const ushort4*>(SRC + (size_t)f*1024 + c0);
        acc[0] += p*us2f(sv.x); acc[1] += p*us2f(sv.y);
        acc[2] += p*us2f(sv.z); acc[3] += p*us2f(sv.w);
    }
#pragma unroll
    for (int j=0;j<4;j++) accs[w][lane*4+j] = acc[j];
    __syncthreads();
    if (tid < 256){
        float m = (accs[0][tid]+accs[1][tid]+accs[2][tid]+accs[3][tid])*0.25f + batt[tid];
        msgDbf[(size_t)d*256 + tid] = f2b(m);
    }
}

// ---------------- fused phiC recurrence: 8 services/block, bf16 gi ----------------
__launch_bounds__(512)
__global__ void k_recur(float* __restrict__ h_srv, const unsigned short* __restrict__ giFb,
                        const unsigned short* __restrict__ Whi,
                        const unsigned short* __restrict__ Wlo,
                        const float* __restrict__ bhh,
                        const int* __restrict__ inv,
                        unsigned short* __restrict__ out_f_bf,
                        int S, int L, int F)
{
    __shared__ float hs[8][129];
    __shared__ alignas(16) unsigned short hsHi[16*128];
    __shared__ alignas(16) unsigned short hsLo[16*128];
    __shared__ float ghs[16][385];
    __shared__ int fLoc[16][8];
    int tid = threadIdx.x;
    int l = tid & 63, w = tid >> 6;
    int lane15 = l & 15, lhi = l >> 4;
    int s0 = blockIdx.x * 8;
    for (int u = tid; u < 2048; u += 512){
        int s=u>>7,k=u&127;
        int ksw = k ^ ((s & 7) << 3);
        if (s < 8){
            float v = h_srv[(size_t)(s0+s)*128+k];
            hs[s][k] = v;
            unsigned short hb = f2b(v);
            hsHi[s*128 + ksw] = hb;
            hsLo[s*128 + ksw] = f2b(v - us2f(hb));
        } else {
            hsHi[s*128 + ksw] = 0;
            hsLo[s*128 + ksw] = 0;
        }
    }
    if (tid < 128) fLoc[tid>>3][tid&7] = inv[(size_t)(s0+(tid&7))*L + (tid>>3)];
    bf16x8 wHi[3][4], wLo[3][4];
#pragma unroll
    for (int ct=0; ct<3; ++ct){
        int col = w*48 + ct*16 + lane15;
#pragma unroll
        for (int ks=0; ks<4; ++ks){
            size_t off = (size_t)col*128 + ks*32 + lhi*8;
            wHi[ct][ks] = *reinterpret_cast<const bf16x8*>(Whi + off);
            wLo[ct][ks] = *reinterpret_cast<const bf16x8*>(Wlo + off);
        }
    }
    __syncthreads();
    for (int t=0;t<L;++t){
        bf16x8 hHi[4], hLo[4];
#pragma unroll
        for (int ks=0; ks<4; ++ks){
            int ek = ks*32 + lhi*8;
            int off = lane15*128 + (ek ^ ((lane15 & 7) << 3));
            hHi[ks] = *reinterpret_cast<const bf16x8*>(&hsHi[off]);
            hLo[ks] = *reinterpret_cast<const bf16x8*>(&hsLo[off]);
        }
#pragma unroll
        for (int ct=0; ct<3; ++ct){
            f32x4 acc = (f32x4){0.f,0.f,0.f,0.f};
#pragma unroll
            for (int ks=0; ks<4; ++ks){
                acc = __builtin_amdgcn_mfma_f32_16x16x32_bf16(hHi[ks], wHi[ct][ks], acc, 0,0,0);
                acc = __builtin_amdgcn_mfma_f32_16x16x32_bf16(hLo[ks], wHi[ct][ks], acc, 0,0,0);
                acc = __builtin_amdgcn_mfma_f32_16x16x32_bf16(hHi[ks], wLo[ct][ks], acc, 0,0,0);
            }
            int col = w*48 + ct*16 + lane15;
            float bb = bhh[col];
#pragma unroll
            for (int v=0; v<4; ++v){
                ghs[lhi*4 + v][col] = acc[v] + bb;
            }
        }
        __syncthreads();
        for (int u = tid; u < 1024; u += 512){
            int s=u>>7, k=u&127; int f = fLoc[t][s];
            if (f >= 0 && f < F){
                const unsigned short* gp = giFb + (size_t)f*384;
                float r  = sigf(us2f(gp[k])     + ghs[s][k]);
                float zz = sigf(us2f(gp[128+k]) + ghs[s][128+k]);
                float n  = tanhf(us2f(gp[256+k]) + r*ghs[s][256+k]);
                float hn = (1.f-zz)*n + zz*hs[s][k];
                hs[s][k] = hn;
                unsigned short hb = f2b(hn);
                int ksw = k ^ ((s & 7) << 3);
                hsHi[s*128 + ksw] = hb;
                hsLo[s*128 + ksw] = f2b(hn - us2f(hb));
                out_f_bf[(size_t)f*128+k] = hb;
            }
        }
        __syncthreads();
    }
    for (int u = tid; u < 1024; u += 512){ int s=u>>7,k=u&127; h_srv[(size_t)(s0+s)*128+k] = hs[s][k]; }
}

__global__ void k_count(const int* __restrict__ row, int* __restrict__ counts, int F, int Dn)
{ int f = blockIdx.x*blockDim.x + threadIdx.x; if (f < F) atomicAdd(&counts[clampi(row[f],0,Dn-1)], 1); }

__global__ void k_scan(const int* __restrict__ counts, int* __restrict__ offs, int D)
{
    __shared__ int part[257];
    int tid = threadIdx.x;
    int per = (D + 255) / 256;
    int s = 0;
    for (int i=0;i<per;i++){ int idx = tid*per+i; if (idx < D) s += counts[idx]; }
    part[tid] = s;
    __syncthreads();
    if (tid == 0){
        int acc = 0;
        for (int i=0;i<256;i++){ int v = part[i]; part[i] = acc; acc += v; }
        part[256] = acc;
    }
    __syncthreads();
    int acc = part[tid];
    for (int i=0;i<per;i++){ int idx = tid*per+i; if (idx < D){ offs[idx] = acc; acc += counts[idx]; } }
    if (tid == 0) offs[D] = part[256];
}

__global__ void k_fill(const int* __restrict__ row, const int* __restrict__ offs,
                       int* __restrict__ cursor, int* __restrict__ list, int F, int Dn)
{
    int f = blockIdx.x*blockDim.x + threadIdx.x;
    if (f >= F) return;
    int r = clampi(row[f],0,Dn-1);
    int p = atomicAdd(&cursor[r], 1);
    int pos = offs[r]+p;
    if (pos >= 0 && pos < F) list[pos] = f;
}

__global__ void k_build_inv(const int* __restrict__ fs, const int* __restrict__ fp,
                            int* __restrict__ inv, int F, int L, int S)
{
    int f = blockIdx.x*blockDim.x + threadIdx.x;
    if (f >= F) return;
    inv[clampi(fs[f],0,S-1)*L + clampi(fp[f],0,L-1)] = f;
}

__global__ void k_pool_add(const float* __restrict__ frag, const int* __restrict__ fs,
                           float* __restrict__ pooled, int F, int S)
{
    int t = blockIdx.x*blockDim.x + threadIdx.x;
    int i = t >> 7, j = t & 127;
    if (i >= F) return;
    atomicAdd(&pooled[(size_t)clampi(fs[i],0,S-1)*128 + j], frag[(size_t)i*128 + j]);
}

__global__ void k_pool_div(float* __restrict__ pooled, const int* __restrict__ lengths, int S)
{
    int t = blockIdx.x*blockDim.x + threadIdx.x;
    int i = t >> 7, j = t & 127;
    if (i >= S) return;
    int l = lengths[i]; if (l < 1) l = 1;
    pooled[(size_t)i*128 + j] /= (float)l;
}

__global__ void k_dot_out(const float* __restrict__ H, const float* __restrict__ W3,
                          const float* __restrict__ b3, float* __restrict__ outv, int off)
{
    __shared__ float red[256];
    int s = blockIdx.x, tid = threadIdx.x;
    red[tid] = H[(size_t)s*256 + tid] * W3[tid];
    __syncthreads();
    for (int st=128; st; st>>=1){ if (tid < st) red[tid] += red[tid+st]; __syncthreads(); }
    if (tid == 0) outv[off + s] = red[0] + b3[0];
}

// =====================================================================================
extern "C" void kernel_launch(void* const* d_in, const int* in_sizes, int n_in,
                              void* d_out, int out_size, void* d_ws, size_t ws_size,
                              hipStream_t stream)
{
    (void)n_in; (void)out_size; (void)ws_size;
    const float* realnode = (const float*)d_in[0];
    const float* arr      = (const float*)d_in[1];
    const int* r_exe   = (const int*)d_in[2];
    const int* r_idev  = (const int*)d_in[3];
    const int* r_ifrag = (const int*)d_in[4];
    const int* r_fdn   = (const int*)d_in[5];
    const int* r_fdr   = (const int*)d_in[6];
    const int* r_len   = (const int*)d_in[7];
    const int* r_fsvc  = (const int*)d_in[8];
    const int* r_fpos  = (const int*)d_in[9];
    const float *W_dev=(const float*)d_in[10], *b_dev=(const float*)d_in[11];
    const float *W_frg=(const float*)d_in[12], *b_frg=(const float*)d_in[13];
    const float *W_srv=(const float*)d_in[14], *b_srv=(const float*)d_in[15];
    const float *C_Wih=(const float*)d_in[16], *C_Whh=(const float*)d_in[17], *C_bih=(const float*)d_in[18], *C_bhh=(const float*)d_in[19];
    const float *F_Wih=(const float*)d_in[20], *F_Whh=(const float*)d_in[21], *F_bih=(const float*)d_in[22], *F_bhh=(const float*)d_in[23];
    const float *D_Wih=(const float*)d_in[24], *D_Whh=(const float*)d_in[25], *D_bih=(const float*)d_in[26], *D_bhh=(const float*)d_in[27];
    const float *W_src=(const float*)d_in[28], *b_src=(const float*)d_in[29];
    const float *W_tgt=(const float*)d_in[30], *b_tgt=(const float*)d_in[31];
    const float *att=(const float*)d_in[32], *bias_att=(const float*)d_in[33];
    const float *Wt1=(const float*)d_in[34], *bt1=(const float*)d_in[35], *Wt2=(const float*)d_in[36], *bt2=(const float*)d_in[37], *Wt3=(const float*)d_in[38], *bt3=(const float*)d_in[39];
    const float *Wl1=(const float*)d_in[40], *bl1=(const float*)d_in[41], *Wl2=(const float*)d_in[42], *bl2=(const float*)d_in[43], *Wl3=(const float*)d_in[44], *bl3=(const float*)d_in[45];
    float* outp = (float*)d_out;

    const int S  = in_sizes[7];
    const int Dn = in_sizes[3];
    const int F  = in_sizes[4];
    const int L  = in_sizes[2] / (2*S);
    const int nreal = in_sizes[0]/5;
    const int nodes = nreal + 1;
    const int NIT = 3;

    char* wp = (char*)d_ws;
    auto alloc = [&](size_t nelem)->float*{
        float* p = (float*)wp;
        wp += ((nelem*4 + 255)/256)*256;
        return p;
    };
    float* h_srv  = alloc((size_t)S*128);
    float* fragA  = alloc((size_t)F*128);
    float* devA   = alloc((size_t)Dn*128);
    float* alphaB = alloc((size_t)F*4);
    float* UNION  = alloc((size_t)F*512);
    unsigned short* giFb = (unsigned short*)UNION;
    unsigned short* SRC  = (unsigned short*)UNION;
    float* Z      = alloc((size_t)Dn*1024);
    float* TGTf   = alloc((size_t)Dn*512);
    unsigned short* TGT = (unsigned short*)TGTf;
    float* pooled = alloc((size_t)S*128);
    unsigned short* state_bf = (unsigned short*)alloc((size_t)nodes*64);
    unsigned short* out_f_bf = (unsigned short*)alloc((size_t)F*64);
    unsigned short* fragA_bf = (unsigned short*)alloc((size_t)F*64);
    unsigned short* devA_bf  = (unsigned short*)alloc((size_t)Dn*64);
    unsigned short* msgD_bf  = (unsigned short*)alloc((size_t)Dn*128);
    unsigned short* tCWih   = (unsigned short*)alloc(384*256/2);
    unsigned short* tCWhhHi = (unsigned short*)alloc(384*128/2);
    unsigned short* tCWhhLo = (unsigned short*)alloc(384*128/2);
    unsigned short* tFWih   = (unsigned short*)alloc(384*256/2);
    unsigned short* tFWhh   = (unsigned short*)alloc(384*128/2);
    unsigned short* tDWih   = (unsigned short*)alloc(384*256/2);
    unsigned short* tDWhh   = (unsigned short*)alloc(384*128/2);
    unsigned short* tWtgt   = (unsigned short*)alloc(1024*128/2);
    unsigned short* tWsrc   = (unsigned short*)alloc(1024*256/2);
    int* cExe   = (int*)alloc((size_t)S*2*L);
    int* cIdev  = (int*)alloc((size_t)Dn);
    int* cIfrag = (int*)alloc((size_t)F);
    int* cFdn   = (int*)alloc((size_t)F);
    int* cFdr   = (int*)alloc((size_t)F);
    int* cLen   = (int*)alloc((size_t)S);
    int* cFsvc  = (int*)alloc((size_t)F);
    int* cFpos  = (int*)alloc((size_t)F);
    int* inv    = (int*)alloc((size_t)S*L);
    int* counts = (int*)alloc((size_t)Dn);
    int* offs   = (int*)alloc((size_t)Dn+1);
    int* cursor = (int*)alloc((size_t)Dn);
    int* list   = (int*)alloc((size_t)F);

    const int* det = r_idev;
    auto cvt = [&](const int* src, int* dst, int n){
        k_cvt<<<dim3((n+255)/256),256,0,stream>>>(src, dst, n, det);
    };
    cvt(r_exe,  cExe,  S*2*L);
    cvt(r_idev, cIdev, Dn);
    cvt(r_ifrag,cIfrag,F);
    cvt(r_fdn,  cFdn,  F);
    cvt(r_fdr,  cFdr,  F);
    cvt(r_len,  cLen,  S);
    cvt(r_fsvc, cFsvc, F);
    cvt(r_fpos, cFpos, F);

    k_wt<<<dim3((98304+255)/256),256,0,stream>>>(C_Wih, tCWih, 384, 8, 255, 98304);
    k_wt2<<<dim3((49152+255)/256),256,0,stream>>>(C_Whh, tCWhhHi, tCWhhLo, 384, 7, 127, 49152);
    k_wt<<<dim3((98304+255)/256),256,0,stream>>>(F_Wih, tFWih, 384, 8, 255, 98304);
    k_wt<<<dim3((49152+255)/256),256,0,stream>>>(F_Whh, tFWhh, 384, 7, 127, 49152);
    k_wt<<<dim3((98304+255)/256),256,0,stream>>>(D_Wih, tDWih, 384, 8, 255, 98304);
    k_wt<<<dim3((49152+255)/256),256,0,stream>>>(D_Whh, tDWhh, 384, 7, 127, 49152);
    k_wt<<<dim3((131072+255)/256),256,0,stream>>>(W_tgt, tWtgt, 1024, 7, 127, 131072);
    k_wt<<<dim3((262144+255)/256),256,0,stream>>>(W_src, tWsrc, 1024, 8, 255, 262144);

    hipMemsetAsync(state_bf, 0, (size_t)nodes*128*2, stream);
    hipMemsetAsync(inv, 0xFF, (size_t)S*L*4, stream);
    hipMemsetAsync(counts, 0, (size_t)Dn*4, stream);
    hipMemsetAsync(cursor, 0, (size_t)Dn*4, stream);

    k_proj5<<<dim3((Dn*128+255)/256),256,0,stream>>>(realnode, W_dev, b_dev, cIdev, cIdev,
        nullptr, state_bf, devA, devA_bf, Dn, nreal, nodes);
    k_proj5<<<dim3(((size_t)F*128+255)/256),256,0,stream>>>(realnode, W_frg, b_frg, cIfrag, cIfrag,
        nullptr, state_bf, fragA, fragA_bf, F, nreal, nodes);
    k_proj5<<<dim3((S*128+255)/256),256,0,stream>>>(arr, W_srv, b_srv, nullptr, nullptr,
        h_srv, nullptr, nullptr, nullptr, S, S, nodes);
    k_build_inv<<<dim3((F+255)/256),256,0,stream>>>(cFsvc, cFpos, inv, F, L, S);
    k_count<<<dim3((F+255)/256),256,0,stream>>>(cFdr, counts, F, Dn);
    k_scan<<<1,256,0,stream>>>(counts, offs, Dn);
    k_fill<<<dim3((F+255)/256),256,0,stream>>>(cFdr, offs, cursor, list, F, Dn);

    const int nrF = F/128, nrD = Dn/128;
    MJob jGi  = { state_bf, state_bf, cIfrag, cFdn, tCWih, C_bih, giFb, 384, 256, 2, nrF, 1.f };
    MJob jTgt = { devA_bf, devA_bf, nullptr, nullptr, tWtgt, b_tgt, TGT, 1024, 128, 2, nrD, 1.f };
    MJob jSrc = { out_f_bf, fragA_bf, nullptr, nullptr, tWsrc, b_src, SRC, 1024, 256, 2, nrF, 1.f };
    GJob jF = { out_f_bf, state_bf, nullptr, cFdn, 128, tFWih, tFWhh, F_bih, F_bhh,
                fragA, fragA_bf, state_bf, cIfrag, F, nodes };
    GJob jD = { msgD_bf, nullptr, nullptr, nullptr, 256, tDWih, tDWhh, D_bih, D_bhh,
                devA, devA_bf, state_bf, cIdev, Dn, nodes };

    for (int it=0; it<NIT; ++it){
        mm2two<<<dim3(3*nrF + 8*nrD),256,0,stream>>>(jGi, jTgt, 3*nrF);
        k_recur<<<dim3(S/8),512,0,stream>>>(h_srv, giFb, tCWhhHi, tCWhhLo, C_bhh, inv,
            out_f_bf, S, L, F);
        mm2one<<<dim3(8*nrF),256,0,stream>>>(jSrc);
        k_attn<<<dim3(Dn),256,0,stream>>>(SRC, TGT, att, list, offs, bias_att,
            msgD_bf, alphaB, Dn, F);
        gru2<<<dim3(nrF + nrD),512,0,stream>>>(jF, jD, nrF);
    }

    // readout
    hipMemsetAsync(pooled, 0, (size_t)S*128*4, stream);
    k_pool_add<<<dim3(((size_t)F*128+255)/256),256,0,stream>>>(fragA, cFsvc, pooled, F, S);
    k_pool_div<<<dim3((S*128+255)/256),256,0,stream>>>(pooled, cLen, S);
    float* h1 = (float*)TGTf;
    k_mm<<<dim3(256/128, S/128),256,0,stream>>>(pooled, 128, Wl1, 256, bl1, h1, S, 256, 128, 1, 1.f, 0);
    k_mm<<<dim3(256/128, S/128),256,0,stream>>>(h1, 256, Wl2, 256, bl2, Z, S, 256, 256, 1, 1.f, 0);
    k_dot_out<<<dim3(S),256,0,stream>>>(Z, Wl3, bl3, outp, 0);
    k_mm<<<dim3(256/128, S/128),256,0,stream>>>(h_srv, 128, Wt1, 256, bt1, h1, S, 256, 128, 1, 1.f, 0);
    k_mm<<<dim3(256/128, S/128),256,0,stream>>>(h1, 256, Wt2, 256, bt2, Z, S, 256, 256, 1, 1.f, 0);
    k_dot_out<<<dim3(S),256,0,stream>>>(Z, Wt3, bt3, outp, S);
}